// Round 6
// baseline (469.908 us; speedup 1.0000x reference)
//
#include <hip/hip_runtime.h>
#include <hip/hip_bf16.h>

#define N_NODES 20000
#define KADJ 4
#define NEDGE 320000
#define ETOTAL (KADJ * NEDGE)               // 1,280,000
#define IN_DIM_ 1024
#define H_IN_ 256
#define DDIM 128
#define GATE_H_ 128
#define TEMP_ 0.6f
#define M_CLAMP_ 20.0f
#define CSR_TOTAL (KADJ * N_NODES)          // 80000
#define NCOARSE 128
#define QPER (CSR_TOTAL / NCOARSE)          // 625
#define ESTRIDE 12288                       // bucket slot stride (exp fill 10000, sigma~100)
#define TILE_A 4096
#define BINA_NB ((ETOTAL + TILE_A - 1) / TILE_A)  // 313
#define NB_CAST (N_NODES * IN_DIM_ / 8 / 256)     // 10000
#define NB_TRANS 2560                              // 8 x 32 x 10

typedef __attribute__((ext_vector_type(8))) short frag_ab;      // 8 bf16
typedef __attribute__((ext_vector_type(4))) float frag_cd;      // 4 fp32
typedef __attribute__((ext_vector_type(8))) unsigned short us8;

__device__ inline unsigned short f2bf(float f) {
    unsigned int u = __float_as_uint(f);
    u += 0x7FFFu + ((u >> 16) & 1);   // RNE
    return (unsigned short)(u >> 16);
}
__device__ inline float bflo(unsigned int p) { return __uint_as_float(p << 16); }
__device__ inline float bfhi(unsigned int p) { return __uint_as_float(p & 0xffff0000u); }

// async 16B global->LDS (wave-uniform LDS base + lane*16)
__device__ __forceinline__ void gld16(const unsigned short* g, unsigned short* l) {
    __builtin_amdgcn_global_load_lds(
        (const __attribute__((address_space(1))) void*)g,
        (__attribute__((address_space(3))) void*)l, 16, 0, 0);
}

// ---- pipelined K-loop building blocks: per wave per stage exactly 5 gld16 ----
#define PIPE_WAIT_NEXT()  asm volatile("s_waitcnt vmcnt(5)" ::: "memory")
#define PIPE_WAIT_LAST()  asm volatile("s_waitcnt vmcnt(0)" ::: "memory")
#define PIPE_BAR()        __builtin_amdgcn_s_barrier()
#define PIPE_FENCE()      __builtin_amdgcn_sched_barrier(0)

// BM=32 / BN=128 geometry, 4 waves in 2x2 layout:
//   wave w: rows wr=(w&1)*16 .. +16, cols wc=(w>>1)*64 .. +64
//   per K-step per wave: 1 A-chunk + 4 B-chunks staged (5 gld16), 8 MFMA.

struct TD { const float* src; unsigned short* dst; int K; int N; };
struct TD10 { TD d[10]; };

// ============== prep mega-kernel: binA2 FIRST (latency-bound) ++ transposes ++ X cast =======
__global__ __launch_bounds__(256) void prep_kernel(
    const float* __restrict__ X, unsigned short* __restrict__ Xb,
    TD10 descs,
    const int* __restrict__ rows, const int* __restrict__ cols,
    int* __restrict__ bcnt, uint2* __restrict__ staging)
{
    __shared__ __align__(16) char sraw[2048 + TILE_A * 8];   // 34 KB
    int bid = blockIdx.x;
    int tid = threadIdx.x;

    if (bid >= BINA_NB + NB_TRANS) {
        // ---- X fp32 -> bf16 streaming cast (scheduled last; BW-bound) ----
        int i = ((bid - BINA_NB - NB_TRANS) * 256 + tid) * 8;
        float4 a = *(const float4*)(X + i), b = *(const float4*)(X + i + 4);
        us8 o;
        o[0] = f2bf(a.x); o[1] = f2bf(a.y); o[2] = f2bf(a.z); o[3] = f2bf(a.w);
        o[4] = f2bf(b.x); o[5] = f2bf(b.y); o[6] = f2bf(b.z); o[7] = f2bf(b.w);
        *(us8*)(Xb + i) = o;
        return;
    }
    if (bid >= BINA_NB) {
        // ---- weight transpose ----
        int b2 = bid - BINA_NB;
        TD t = descs.d[b2 >> 8];
        int rem = b2 & 255;
        int n0 = (rem & 7) * 32, k0 = (rem >> 3) * 32;
        if (n0 >= t.N || k0 >= t.K) return;
        float (*tile)[33] = (float(*)[33])sraw;
        int tx = tid & 31, ty4 = (tid >> 5) * 4;
#pragma unroll
        for (int i = 0; i < 4; i++)
            tile[ty4 + i][tx] = t.src[(size_t)(k0 + ty4 + i) * t.N + n0 + tx];
        __syncthreads();
#pragma unroll
        for (int i = 0; i < 4; i++)
            t.dst[(size_t)(n0 + ty4 + i) * t.K + k0 + tx] = f2bf(tile[tx][ty4 + i]);
        return;
    }
    // ---- binA2: CSR coarse binning (dispatched FIRST, overlaps with cast) ----
    int* hist  = (int*)sraw;
    int* hscan = hist + NCOARSE;
    int* lcur  = hscan + NCOARSE;
    int* gbase = lcur + NCOARSE;
    uint2* pairs = (uint2*)(sraw + 2048);

    int base = bid * TILE_A;
    int cnt_t = min(TILE_A, ETOTAL - base);

    for (int i = tid; i < NCOARSE; i += 256) hist[i] = 0;
    __syncthreads();

    unsigned int q[16], c[16];
    bool valid[16];
#pragma unroll
    for (int i = 0; i < 16; i++) {
        int loc = i * 256 + tid;
        valid[i] = loc < cnt_t;
        if (valid[i]) {
            int e = base + loc;
            int k = e / NEDGE;
            unsigned int qq = (unsigned int)(k * N_NODES + rows[e]);
            q[i] = qq;
            c[i] = (unsigned int)cols[e];
            atomicAdd(&hist[qq / QPER], 1);
        }
    }
    __syncthreads();
    if (tid < NCOARSE) hscan[tid] = hist[tid];
    __syncthreads();
    for (int d = 1; d < NCOARSE; d <<= 1) {
        int v = (tid >= d && tid < NCOARSE) ? hscan[tid - d] : 0;
        __syncthreads();
        if (tid < NCOARSE) hscan[tid] += v;
        __syncthreads();
    }
    if (tid < NCOARSE) {
        int ex = hscan[tid] - hist[tid];
        hscan[tid] = ex;
        lcur[tid] = ex;
        gbase[tid] = hist[tid] ? (tid * ESTRIDE + atomicAdd(&bcnt[tid], hist[tid])) : 0;
    }
    __syncthreads();
#pragma unroll
    for (int i = 0; i < 16; i++) {
        if (valid[i]) {
            int b = q[i] / QPER;
            int p = atomicAdd(&lcur[b], 1);
            pairs[p] = make_uint2(q[i], c[i]);
        }
    }
    __syncthreads();
    for (int i = tid; i < cnt_t; i += 256) {
        uint2 pr = pairs[i];
        int b = pr.x / QPER;
        staging[gbase[b] + (i - hscan[b])] = pr;
    }
}

// ============== gemm1 ++ binB2 in one launch (independent; staging must NOT alias H0b!) ======
__global__ __launch_bounds__(256) void gemm1_binb_kernel(
    const unsigned short* __restrict__ A, const unsigned short* __restrict__ Bt,
    const float* __restrict__ bias, unsigned short* __restrict__ Cb,
    int M, int N, int K,
    const uint2* __restrict__ staging, const int* __restrict__ bcnt,
    int* __restrict__ offs, int* __restrict__ ends, int* __restrict__ edst)
{
    __shared__ __align__(16) char smem[40960];
    int tid = threadIdx.x;
    int bid = blockIdx.x;
    const int GEMM_NB = 2 * 625;

    if (bid < GEMM_NB) {
        unsigned short* sA0 = (unsigned short*)smem;           // 2 x 2048 shorts
        unsigned short* sB0 = (unsigned short*)(smem + 8192);  // 2 x 8192 shorts
        int tileM = (bid >> 1) * 32, tileN = (bid & 1) * 128;
        int w = tid >> 6, lane = tid & 63;
        int wr = (w & 1) * 16, wc = (w >> 1) * 64;
        int fm = lane & 15, fq = lane >> 4;
        int crow = lane >> 3;
        int gsw = (lane & 7) ^ crow;

        frag_cd acc[4] = {};

        auto stage = [&](int buf, int k0) {
            {
                int row = w * 8 + crow;
                int ar = min(tileM + row, M - 1);
                gld16(A + (size_t)ar * K + k0 + gsw * 8, sA0 + buf * 2048 + w * 512);
            }
#pragma unroll
            for (int t = 0; t < 4; t++) {
                int chunk = w * 4 + t;
                int row = chunk * 8 + crow;
                gld16(Bt + (size_t)(tileN + row) * K + k0 + gsw * 8, sB0 + buf * 8192 + chunk * 512);
            }
        };

        int nt = K >> 6;
        stage(0, 0);
        for (int t = 0; t < nt; t++) {
            int cur = t & 1;
            if (t + 1 < nt) { stage(cur ^ 1, (t + 1) << 6); PIPE_WAIT_NEXT(); }
            else            { PIPE_WAIT_LAST(); }
            PIPE_BAR();
            PIPE_FENCE();
#pragma unroll
            for (int s = 0; s < 2; s++) {
                int sw = ((s * 4 + fq) ^ (fm & 7)) * 8;
                frag_ab af = *(const frag_ab*)(sA0 + cur * 2048 + (wr + fm) * 64 + sw);
#pragma unroll
                for (int j = 0; j < 4; j++) {
                    frag_ab bf = *(const frag_ab*)(sB0 + cur * 8192 + (wc + j * 16 + fm) * 64 + sw);
                    acc[j] = __builtin_amdgcn_mfma_f32_16x16x32_bf16(af, bf, acc[j], 0, 0, 0);
                }
            }
            PIPE_FENCE();
            PIPE_BAR();
        }
        int row = tileM + wr + fq * 4;
#pragma unroll
        for (int r = 0; r < 4; r++) {
            if (row + r < M) {
#pragma unroll
                for (int j = 0; j < 4; j++) {
                    int col = tileN + wc + j * 16 + fm;
                    float v = fmaxf(acc[j][r] + bias[col], 0.f);
                    Cb[(size_t)(row + r) * N + col] = f2bf(v);
                }
            }
        }
        return;
    }
    // ---- binB2 ----
    int* cntS = (int*)smem;
    int* sofs = cntS + QPER;
    int* lcur = sofs + QPER;
    int* psum = lcur + QPER;
    int b = bid - GEMM_NB;
    int q0 = b * QPER, base = b * ESTRIDE;
    int fill = bcnt[b];
    for (int i = tid; i < QPER; i += 256) cntS[i] = 0;
    __syncthreads();
    for (int i = tid; i < fill; i += 256)
        atomicAdd(&cntS[staging[base + i].x - q0], 1);
    __syncthreads();
    const int CH = 3;
    int lo = tid * CH, hi = min(lo + CH, QPER);
    int s = 0;
    for (int i = lo; i < hi; i++) s += cntS[i];
    psum[tid] = s;
    __syncthreads();
    for (int d = 1; d < 256; d <<= 1) {
        int v = (tid >= d) ? psum[tid - d] : 0;
        __syncthreads();
        psum[tid] += v;
        __syncthreads();
    }
    int run = (tid == 0) ? 0 : psum[tid - 1];
    for (int i = lo; i < hi; i++) {
        sofs[i] = run;
        lcur[i] = run;
        run += cntS[i];
    }
    __syncthreads();
    for (int i = tid; i < QPER; i += 256) {
        offs[q0 + i] = base + sofs[i];
        ends[q0 + i] = base + sofs[i] + cntS[i];
    }
    for (int i = tid; i < fill; i += 256) {
        uint2 p = staging[base + i];
        int pos = atomicAdd(&lcur[p.x - q0], 1);
        edst[base + pos] = (int)p.y;
    }
}

// ============== async bf16 MFMA GEMM: C = [relu](A[M,K]_bf16 @ (Bt[N,K]_bf16)^T + bias) =========
__global__ __launch_bounds__(256) void gemm_async_kernel(
    const unsigned short* __restrict__ A, const unsigned short* __restrict__ Bt,
    const float* __restrict__ bias, float* __restrict__ Cf, unsigned short* __restrict__ Cb,
    int M, int N, int K, int do_relu)
{
    __shared__ unsigned short sA[2][32 * 64];
    __shared__ unsigned short sB[2][128 * 64];
    int tid = threadIdx.x;
    int tileM = blockIdx.y * 32, tileN = blockIdx.x * 128;
    int w = tid >> 6, lane = tid & 63;
    int wr = (w & 1) * 16, wc = (w >> 1) * 64;
    int fm = lane & 15, fq = lane >> 4;
    int crow = lane >> 3;
    int gsw = (lane & 7) ^ crow;

    frag_cd acc[4] = {};

    auto stage = [&](int buf, int k0) {
        {
            int row = w * 8 + crow;
            int ar = min(tileM + row, M - 1);
            gld16(A + (size_t)ar * K + k0 + gsw * 8, &sA[buf][w * 512]);
        }
#pragma unroll
        for (int t = 0; t < 4; t++) {
            int chunk = w * 4 + t;
            int row = chunk * 8 + crow;
            gld16(Bt + (size_t)(tileN + row) * K + k0 + gsw * 8, &sB[buf][chunk * 512]);
        }
    };

    int nt = K >> 6;
    stage(0, 0);
    for (int t = 0; t < nt; t++) {
        int cur = t & 1;
        if (t + 1 < nt) { stage(cur ^ 1, (t + 1) << 6); PIPE_WAIT_NEXT(); }
        else            { PIPE_WAIT_LAST(); }
        PIPE_BAR();
        PIPE_FENCE();
#pragma unroll
        for (int s = 0; s < 2; s++) {
            int sw = ((s * 4 + fq) ^ (fm & 7)) * 8;
            frag_ab af = *(const frag_ab*)&sA[cur][(wr + fm) * 64 + sw];
#pragma unroll
            for (int j = 0; j < 4; j++) {
                frag_ab bf = *(const frag_ab*)&sB[cur][(wc + j * 16 + fm) * 64 + sw];
                acc[j] = __builtin_amdgcn_mfma_f32_16x16x32_bf16(af, bf, acc[j], 0, 0, 0);
            }
        }
        PIPE_FENCE();
        PIPE_BAR();
    }
    int row = tileM + wr + fq * 4;
#pragma unroll
    for (int r = 0; r < 4; r++) {
        if (row + r < M) {
#pragma unroll
            for (int j = 0; j < 4; j++) {
                int col = tileN + wc + j * 16 + fm;
                float v = acc[j][r];
                if (bias) v += bias[col];
                if (do_relu) v = fmaxf(v, 0.f);
                if (Cf) Cf[(size_t)(row + r) * N + col] = v;
                if (Cb) Cb[(size_t)(row + r) * N + col] = f2bf(v);
            }
        }
    }
}

// ============== fused Z+GH GEMM: A=Hb[M,128], Bt=wzg[256][128] ==============
__global__ __launch_bounds__(256) void zg_gemm_kernel(
    const unsigned short* __restrict__ A, const unsigned short* __restrict__ Bt,
    const float* __restrict__ bg1, unsigned short* __restrict__ Zb,
    float* __restrict__ GH, int M)
{
    __shared__ unsigned short sA[2][32 * 64];
    __shared__ unsigned short sB[2][128 * 64];
    int tid = threadIdx.x;
    int tileM = blockIdx.y * 32, tileN = blockIdx.x * 128;
    int w = tid >> 6, lane = tid & 63;
    int wr = (w & 1) * 16, wc = (w >> 1) * 64;
    int fm = lane & 15, fq = lane >> 4;
    int crow = lane >> 3;
    int gsw = (lane & 7) ^ crow;

    frag_cd acc[4] = {};

    auto stage = [&](int buf, int k0) {
        {
            int row = w * 8 + crow;
            int ar = min(tileM + row, M - 1);
            gld16(A + (size_t)ar * DDIM + k0 + gsw * 8, &sA[buf][w * 512]);
        }
#pragma unroll
        for (int t = 0; t < 4; t++) {
            int chunk = w * 4 + t;
            int row = chunk * 8 + crow;
            gld16(Bt + (size_t)(tileN + row) * DDIM + k0 + gsw * 8, &sB[buf][chunk * 512]);
        }
    };

    stage(0, 0);
#pragma unroll
    for (int t = 0; t < 2; t++) {
        int cur = t & 1;
        if (t == 0) { stage(1, 64); PIPE_WAIT_NEXT(); }
        else        { PIPE_WAIT_LAST(); }
        PIPE_BAR();
        PIPE_FENCE();
#pragma unroll
        for (int s = 0; s < 2; s++) {
            int sw = ((s * 4 + fq) ^ (fm & 7)) * 8;
            frag_ab af = *(const frag_ab*)&sA[cur][(wr + fm) * 64 + sw];
#pragma unroll
            for (int j = 0; j < 4; j++) {
                frag_ab bf = *(const frag_ab*)&sB[cur][(wc + j * 16 + fm) * 64 + sw];
                acc[j] = __builtin_amdgcn_mfma_f32_16x16x32_bf16(af, bf, acc[j], 0, 0, 0);
            }
        }
        PIPE_FENCE();
        PIPE_BAR();
    }
    int isZ = (blockIdx.x == 0);
    int row = tileM + wr + fq * 4;
#pragma unroll
    for (int r = 0; r < 4; r++) {
        if (row + r < M) {
#pragma unroll
            for (int j = 0; j < 4; j++) {
                int col = wc + j * 16 + fm;    // local 0..127
                float v = acc[j][r];
                if (isZ) Zb[(size_t)(row + r) * DDIM + col] = f2bf(v);
                else     GH[(size_t)(row + r) * GATE_H_ + col] = v + bg1[col];
            }
        }
    }
}

// ============== head GEMM + logits epilogue: logits = relu(Hb@Wh1+bh1) . Wh2 + bh2 ========
__global__ __launch_bounds__(256) void head_gemm_kernel(
    const unsigned short* __restrict__ A, const unsigned short* __restrict__ Bt,
    const float* __restrict__ bh1, const float* __restrict__ Wh2,
    const float* __restrict__ bh2, float* __restrict__ logits, int M)
{
    __shared__ unsigned short sA[2][32 * 64];
    __shared__ unsigned short sB[2][128 * 64];
    __shared__ float sred[2][32];
    int tid = threadIdx.x;
    int tileM = blockIdx.x * 32;
    int w = tid >> 6, lane = tid & 63;
    int wr = (w & 1) * 16, wc = (w >> 1) * 64;
    int fm = lane & 15, fq = lane >> 4;
    int crow = lane >> 3;
    int gsw = (lane & 7) ^ crow;

    frag_cd acc[4] = {};

    auto stage = [&](int buf, int k0) {
        {
            int row = w * 8 + crow;
            int ar = min(tileM + row, M - 1);
            gld16(A + (size_t)ar * DDIM + k0 + gsw * 8, &sA[buf][w * 512]);
        }
#pragma unroll
        for (int t = 0; t < 4; t++) {
            int chunk = w * 4 + t;
            int row = chunk * 8 + crow;
            gld16(Bt + (size_t)row * DDIM + k0 + gsw * 8, &sB[buf][chunk * 512]);
        }
    };

    stage(0, 0);
#pragma unroll
    for (int t = 0; t < 2; t++) {
        int cur = t & 1;
        if (t == 0) { stage(1, 64); PIPE_WAIT_NEXT(); }
        else        { PIPE_WAIT_LAST(); }
        PIPE_BAR();
        PIPE_FENCE();
#pragma unroll
        for (int s = 0; s < 2; s++) {
            int sw = ((s * 4 + fq) ^ (fm & 7)) * 8;
            frag_ab af = *(const frag_ab*)&sA[cur][(wr + fm) * 64 + sw];
#pragma unroll
            for (int j = 0; j < 4; j++) {
                frag_ab bf = *(const frag_ab*)&sB[cur][(wc + j * 16 + fm) * 64 + sw];
                acc[j] = __builtin_amdgcn_mfma_f32_16x16x32_bf16(af, bf, acc[j], 0, 0, 0);
            }
        }
        PIPE_FENCE();
        PIPE_BAR();
    }
    float wv[4], bh[4];
#pragma unroll
    for (int j = 0; j < 4; j++) {
        int c = wc + j * 16 + fm;
        wv[j] = Wh2[c];
        bh[j] = bh1[c];
    }
    float part[4];
#pragma unroll
    for (int r = 0; r < 4; r++) {
        float p = 0.f;
#pragma unroll
        for (int j = 0; j < 4; j++) {
            float v = fmaxf(acc[j][r] + bh[j], 0.f);
            p += v * wv[j];
        }
        part[r] = p;
    }
#pragma unroll
    for (int m = 1; m < 16; m <<= 1)
#pragma unroll
        for (int r = 0; r < 4; r++)
            part[r] += __shfl_xor(part[r], m, 64);
    if (fm == 0) {
#pragma unroll
        for (int r = 0; r < 4; r++)
            sred[w >> 1][wr + fq * 4 + r] = part[r];
    }
    __syncthreads();
    if (tid < 32 && tileM + tid < M)
        logits[tileM + tid] = sred[0][tid] + sred[1][tid] + bh2[0];
}

// ============== gate GEMM with IN-KERNEL gather + FUSED alpha/Y/pairnorm epilogue ==========
// block covers 32 q = 8 full nodes. Wave w gathers rows w*8..w*8+8 from Zb (CSR),
// clips, writes bf16 into swizzled sA LDS (both K-tiles). Then MFMA vs Wg1m,
// scores -> softmax -> alpha -> Y = H + sum_k a_k M (M read from LDS) + pairnorm partials.
__global__ __launch_bounds__(256) void gate_fuse_kernel(
    const int* __restrict__ offs, const int* __restrict__ ends,
    const int* __restrict__ edst, const unsigned short* __restrict__ Zb,
    const unsigned short* __restrict__ Bt,
    const float* __restrict__ GH, const float* __restrict__ logdeg,
    const float* __restrict__ wld, const float* __restrict__ Wg2,
    const float* __restrict__ bg2, const float* __restrict__ mask,
    const float* __restrict__ H, float* __restrict__ Y,
    float* __restrict__ alpha_out, float* __restrict__ red)
{
    __shared__ __align__(16) unsigned short sA[2][32 * 64];   // M, swizzled, k-tile 0/1
    __shared__ __align__(16) unsigned short sB[2][128 * 64];
    __shared__ float sred[2][32];
    __shared__ float sc_al[64];          // [0:32) scores, [32:64) alpha
    __shared__ float sx[256], sy[256], sqs[256];
    int tid = threadIdx.x;
    int tile0 = blockIdx.x * 32;
    int node0 = blockIdx.x * 8;
    int w = tid >> 6, lane = tid & 63;
    int wr = (w & 1) * 16, wc = (w >> 1) * 64;
    int fm = lane & 15, fq = lane >> 4;
    int crow = lane >> 3;
    int gsw = (lane & 7) ^ crow;

    // ---- stage B (both K-tiles) upfront: 8 gld16/wave, completes under the gather ----
#pragma unroll
    for (int t = 0; t < 4; t++) {
        int chunk = w * 4 + t;
        int row = chunk * 8 + crow;
        gld16(Bt + (size_t)row * DDIM + 0  + gsw * 8, &sB[0][chunk * 512]);
        gld16(Bt + (size_t)row * DDIM + 64 + gsw * 8, &sB[1][chunk * 512]);
    }

    // ---- gather: wave w computes M rows w*8..w*8+8 (quarter-wave, 4 edges in flight) ----
    int qw = lane >> 4;          // edge slot within pass
    int l = lane & 15;           // 16 lanes x 16B per Z-row
    for (int qi = 0; qi < 8; qi++) {
        int lq = w * 8 + qi;                 // local row 0..31 (chunk == w)
        int qp = tile0 + lq;                 // node-major q' = r*KADJ + k
        int r = qp >> 2, kk = qp & 3;
        int qc = kk * N_NODES + r;           // CSR index (k-major)
        int start = offs[qc], end = ends[qc];

        float a0 = 0.f, a1 = 0.f, a2 = 0.f, a3 = 0.f;
        float a4 = 0.f, a5 = 0.f, a6 = 0.f, a7 = 0.f;
#define ACC8(P) {                                  \
        a0 += bflo(P.x); a1 += bfhi(P.x);          \
        a2 += bflo(P.y); a3 += bfhi(P.y);          \
        a4 += bflo(P.z); a5 += bfhi(P.z);          \
        a6 += bflo(P.w); a7 += bfhi(P.w); }
        int i = start + qw;
        for (; i + 12 < end; i += 16) {
            int c0 = edst[i], c1 = edst[i + 4], c2 = edst[i + 8], c3 = edst[i + 12];
            uint4 p0 = *(const uint4*)(Zb + (size_t)c0 * DDIM + l * 8);
            uint4 p1 = *(const uint4*)(Zb + (size_t)c1 * DDIM + l * 8);
            uint4 p2 = *(const uint4*)(Zb + (size_t)c2 * DDIM + l * 8);
            uint4 p3 = *(const uint4*)(Zb + (size_t)c3 * DDIM + l * 8);
            ACC8(p0); ACC8(p1); ACC8(p2); ACC8(p3);
        }
        for (; i + 4 < end; i += 8) {
            int c0 = edst[i], c1 = edst[i + 4];
            uint4 p0 = *(const uint4*)(Zb + (size_t)c0 * DDIM + l * 8);
            uint4 p1 = *(const uint4*)(Zb + (size_t)c1 * DDIM + l * 8);
            ACC8(p0); ACC8(p1);
        }
        if (i < end) {
            int c0 = edst[i];
            uint4 p0 = *(const uint4*)(Zb + (size_t)c0 * DDIM + l * 8);
            ACC8(p0);
        }
#undef ACC8
#define QRED(x) { x += __shfl_xor(x, 16, 64); x += __shfl_xor(x, 32, 64); }
        QRED(a0) QRED(a1) QRED(a2) QRED(a3) QRED(a4) QRED(a5) QRED(a6) QRED(a7)
#undef QRED
        if (qw == 0) {
#define CLIP(v) fminf(fmaxf(v, -M_CLAMP_), M_CLAMP_)
            unsigned int w0 = (unsigned int)f2bf(CLIP(a0)) | ((unsigned int)f2bf(CLIP(a1)) << 16);
            unsigned int w1 = (unsigned int)f2bf(CLIP(a2)) | ((unsigned int)f2bf(CLIP(a3)) << 16);
            unsigned int w2 = (unsigned int)f2bf(CLIP(a4)) | ((unsigned int)f2bf(CLIP(a5)) << 16);
            unsigned int w3 = (unsigned int)f2bf(CLIP(a6)) | ((unsigned int)f2bf(CLIP(a7)) << 16);
#undef CLIP
            // swizzled LDS store: granule g=l of row lq lands at slot g^(row&7)
            int buf = l >> 3, gg = l & 7, cr = lq & 7;
            int soff = w * 512 + (cr * 8 + (gg ^ cr)) * 8;
            *(uint4*)&sA[buf][soff] = make_uint4(w0, w1, w2, w3);
        }
    }
    __syncthreads();   // drains B gld16s (vmcnt) + M ds_writes (lgkmcnt)

    // ---- MFMA: 2 K-tiles x 2 sub-steps ----
    frag_cd acc[4] = {};
#pragma unroll
    for (int tkt = 0; tkt < 2; tkt++) {
#pragma unroll
        for (int s = 0; s < 2; s++) {
            int sw = ((s * 4 + fq) ^ (fm & 7)) * 8;
            frag_ab af = *(const frag_ab*)&sA[tkt][(wr + fm) * 64 + sw];
#pragma unroll
            for (int j = 0; j < 4; j++) {
                frag_ab bf = *(const frag_ab*)&sB[tkt][(wc + j * 16 + fm) * 64 + sw];
                acc[j] = __builtin_amdgcn_mfma_f32_16x16x32_bf16(af, bf, acc[j], 0, 0, 0);
            }
        }
    }
    // ---- scores ----
    float wg2v[4], wldv[4];
#pragma unroll
    for (int j = 0; j < 4; j++) {
        int c = wc + j * 16 + fm;
        wg2v[j] = Wg2[c];
        wldv[j] = wld[c];
    }
    float part[4];
#pragma unroll
    for (int r = 0; r < 4; r++) {
        int q = tile0 + wr + fq * 4 + r;
        int n = q >> 2;
        float ld = logdeg[q];
        float p = 0.f;
#pragma unroll
        for (int j = 0; j < 4; j++) {
            int c = wc + j * 16 + fm;
            float v = acc[j][r] + GH[(size_t)n * GATE_H_ + c] + ld * wldv[j];
            p += fmaxf(v, 0.f) * wg2v[j];
        }
        part[r] = p;
    }
#pragma unroll
    for (int m = 1; m < 16; m <<= 1)
#pragma unroll
        for (int r = 0; r < 4; r++)
            part[r] += __shfl_xor(part[r], m, 64);
    if (fm == 0) {
#pragma unroll
        for (int r = 0; r < 4; r++)
            sred[w >> 1][wr + fq * 4 + r] = part[r];
    }
    __syncthreads();
    if (tid < 32) sc_al[tid] = sred[0][tid] + sred[1][tid] + bg2[0];
    __syncthreads();
    // ---- softmax + mask renorm per node (threads 0..7) ----
    if (tid < 8) {
        int n = node0 + tid;
        float a[KADJ];
        float mx = -1e30f;
#pragma unroll
        for (int k = 0; k < KADJ; k++) {
            a[k] = sc_al[tid * 4 + k] * (1.0f / TEMP_);
            mx = fmaxf(mx, a[k]);
        }
        float sum = 0.f;
#pragma unroll
        for (int k = 0; k < KADJ; k++) { a[k] = expf(a[k] - mx); sum += a[k]; }
#pragma unroll
        for (int k = 0; k < KADJ; k++) a[k] = (a[k] / sum) * mask[(size_t)n * KADJ + k];
        float s2 = 0.f;
#pragma unroll
        for (int k = 0; k < KADJ; k++) s2 += a[k];
        float inv = 1.f / fmaxf(s2, 1e-12f);
#pragma unroll
        for (int k = 0; k < KADJ; k++) a[k] = fmaxf(a[k] * inv, 1e-8f);
        s2 = 0.f;
#pragma unroll
        for (int k = 0; k < KADJ; k++) s2 += a[k];
        inv = 1.f / fmaxf(s2, 1e-12f);
#pragma unroll
        for (int k = 0; k < KADJ; k++) sc_al[32 + tid * 4 + k] = a[k] * inv;
    }
    __syncthreads();
    if (tid < 32) alpha_out[tile0 + tid] = sc_al[32 + tid];
    // ---- Y = H + sum_k a_k M (M from LDS), + pairnorm partials ----
    float csx = 0.f, csy = 0.f, sq = 0.f;
    int j = tid & 63, dd = j * 2;
    int g = dd >> 3, mbuf = g >> 3, gg2 = g & 7, din = dd & 7;
#pragma unroll
    for (int it = 0; it < 2; it++) {
        int nl = (tid >> 6) + it * 4;
        int n = node0 + nl;
        const float* alp = &sc_al[32 + nl * 4];
        float2 h = *(const float2*)(H + (size_t)n * DDIM + dd);
        float yx = h.x, yy = h.y;
#pragma unroll
        for (int k = 0; k < KADJ; k++) {
            int row = nl * 4 + k;
            int soff = (row >> 3) * 512 + ((row & 7) * 8 + (gg2 ^ (row & 7))) * 8 + din;
            unsigned int u = *(const unsigned int*)&sA[mbuf][soff];
            yx += alp[k] * bflo(u);
            yy += alp[k] * bfhi(u);
        }
        *(float2*)(Y + (size_t)n * DDIM + dd) = make_float2(yx, yy);
        csx += yx; csy += yy;
        sq += yx * yx + yy * yy;
    }
    sx[tid] = csx; sy[tid] = csy; sqs[tid] = sq;
    __syncthreads();
    int st = (blockIdx.x & 7) * 132;
    if (tid < 64) {
        float ax = sx[tid] + sx[tid + 64] + sx[tid + 128] + sx[tid + 192];
        float ay = sy[tid] + sy[tid + 64] + sy[tid + 128] + sy[tid + 192];
        atomicAdd(&red[st + tid * 2], ax);
        atomicAdd(&red[st + tid * 2 + 1], ay);
    }
    for (int s = 128; s > 0; s >>= 1) {
        if (tid < s) sqs[tid] += sqs[tid + s];
        __syncthreads();
    }
    if (tid == 0) atomicAdd(&red[st + 128], sqs[0]);
}

// ---------------- pairnorm apply: sums 8 red stripes, writes H fp32 + Hb bf16 ----------
__global__ __launch_bounds__(256) void pairnorm_kernel(
    const float* __restrict__ Y, const float* __restrict__ red,
    float* __restrict__ Hout, unsigned short* __restrict__ Hb, int N)
{
    int tid = threadIdx.x;
    int d = tid & 127;
    float invN = 1.0f / (float)N;
    float s = 0.f, rq = 0.f;
#pragma unroll
    for (int st = 0; st < 8; st++) {
        s += red[st * 132 + d];
        rq += red[st * 132 + 128];
    }
    float mu = s * invN;
    __shared__ float smu2[128];
    if (tid < 128) smu2[tid] = mu * mu;
    __syncthreads();
    for (int t = 64; t > 0; t >>= 1) {
        if (tid < t) smu2[tid] += smu2[tid + t];
        __syncthreads();
    }
    float summu2 = smu2[0];
    float var = rq * invN - summu2;
    float norm = sqrtf(fmaxf(var, 0.f)) + 1e-6f;
    float inv = 1.0f / norm;
    int n = blockIdx.x * 2 + (tid >> 7);
    if (n < N) {
        float v = (Y[(size_t)n * DDIM + d] - mu) * inv;
        v = fmaxf(v, 0.f);
        Hout[(size_t)n * DDIM + d] = v;
        Hb[(size_t)n * DDIM + d] = f2bf(v);
    }
}

extern "C" void kernel_launch(void* const* d_in, const int* in_sizes, int n_in,
                              void* d_out, int out_size, void* d_ws, size_t ws_size,
                              hipStream_t stream)
{
    const float* X      = (const float*)d_in[0];
    const int*   rows   = (const int*)d_in[1];
    const int*   cols   = (const int*)d_in[2];
    const float* mask   = (const float*)d_in[3];
    const float* logdeg = (const float*)d_in[4];
    const float* W_in0  = (const float*)d_in[5];
    const float* b_in0  = (const float*)d_in[6];
    const float* W_in1  = (const float*)d_in[7];
    const float* b_in1  = (const float*)d_in[8];
    const float* W_in2  = (const float*)d_in[9];
    const float* b_in2  = (const float*)d_in[10];
    const float* Wmsg[2] = {(const float*)d_in[11], (const float*)d_in[16]};
    const float* Wg1[2]  = {(const float*)d_in[12], (const float*)d_in[17]};
    const float* bg1[2]  = {(const float*)d_in[13], (const float*)d_in[18]};
    const float* Wg2[2]  = {(const float*)d_in[14], (const float*)d_in[19]};
    const float* bg2[2]  = {(const float*)d_in[15], (const float*)d_in[20]};
    const float* Wh1 = (const float*)d_in[21];
    const float* bh1 = (const float*)d_in[22];
    const float* Wh2 = (const float*)d_in[23];
    const float* bh2 = (const float*)d_in[24];

    // workspace layout (float slots), ~85 MB.
    // LIFETIME MAP (race-audited):
    //   Xb      0        - 10240000   written prep, read gemm1
    //   H0b     10240000 - 12800000   written gemm1, read gemm2
    //   H1b/Zb  12800000 - 15360000   gemm2->gemm3; zg->gate_fuse
    //   staging 15360000 - 18505728   written prep(binA2), read binB2 (inside gemm1 launch).
    //                                 Dead before gemm3 writes H/Hb to the same region.
    //                                 (MUST NOT alias H0b: binB2 runs concurrently with gemm1!)
    //   H       15360000 - 17920000   written gemm3 (after staging dead)
    //   Hb      17920000 - 19200000   written gemm3
    float* ws = (float*)d_ws;
    unsigned short* Xb  = (unsigned short*)ws;
    float* Ybuf  = ws + 5120000;
    float* GH    = ws + 7680000;
    unsigned short* H0b = (unsigned short*)(ws + 10240000);
    unsigned short* H1b = (unsigned short*)(ws + 12800000);
    unsigned short* Zb  = (unsigned short*)(ws + 12800000);
    uint2* staging = (uint2*)(ws + 15360000);       // NCOARSE*ESTRIDE*2 = 3,145,728 slots
    float* H     = ws + 15360000;                   // 2.56M (after staging dead)
    unsigned short* Hb = (unsigned short*)(ws + 17920000);  // 1.28M slots
    int*   bcnt  = (int*)(ws + 19200000);           // 128
    float* red   = ws + 19200128;                   // 2 blocks x 8 stripes x 132
    int*   offs   = (int*)(ws + 19280000);          // 80000
    int*   ends   = (int*)(ws + 19360000);          // 80000
    int*   edst   = (int*)(ws + 19440000);          // NCOARSE*ESTRIDE = 1,572,864
    unsigned short* w0t  = (unsigned short*)(ws + 21013248);  // 131072 slots
    unsigned short* w1t  = (unsigned short*)(ws + 21144320);  // 32768
    unsigned short* w2t  = (unsigned short*)(ws + 21177088);  // 16384
    unsigned short* wzg[2]  = {(unsigned short*)(ws + 21193472), (unsigned short*)(ws + 21209856)};  // 256x128 each
    unsigned short* wgmt[2] = {(unsigned short*)(ws + 21226240), (unsigned short*)(ws + 21234432)};
    unsigned short* wh1t = (unsigned short*)(ws + 21242624);
    float* logits = (float*)d_out;
    float* alpha_out = (float*)d_out + N_NODES;

    dim3 blk(256);
    int gM32 = (N_NODES + 31) / 32;     // 625

    // ---- one memset: bcnt(128 ints) + red(2x8x132 floats) contiguous ----
    (void)hipMemsetAsync(bcnt, 0, (128 + 2 * 8 * 132) * sizeof(float), stream);

    // ---- prep: binA2 (first) + transposes + cast in ONE launch ----
    TD10 descs;
    descs.d[0] = {W_in0, w0t, IN_DIM_, H_IN_};
    descs.d[1] = {W_in1, w1t, H_IN_, H_IN_};
    descs.d[2] = {W_in2, w2t, H_IN_, DDIM};
    descs.d[3] = {Wmsg[0], wzg[0], DDIM, DDIM};                           // rows 0-127 of wzg0
    descs.d[4] = {Wg1[0], wzg[0] + DDIM * DDIM, DDIM, GATE_H_};           // rows 128-255 of wzg0
    descs.d[5] = {Wmsg[1], wzg[1], DDIM, DDIM};
    descs.d[6] = {Wg1[1], wzg[1] + DDIM * DDIM, DDIM, GATE_H_};
    descs.d[7] = {Wg1[0] + DDIM * GATE_H_, wgmt[0], DDIM, GATE_H_};
    descs.d[8] = {Wg1[1] + DDIM * GATE_H_, wgmt[1], DDIM, GATE_H_};
    descs.d[9] = {Wh1, wh1t, DDIM, DDIM};
    prep_kernel<<<BINA_NB + NB_TRANS + NB_CAST, blk, 0, stream>>>(
        X, Xb, descs, rows, cols, bcnt, staging);

    // ---- gemm1 ++ binB2 (independent, one launch; staging no longer aliases H0b) ----
    gemm1_binb_kernel<<<2 * gM32 + NCOARSE, blk, 0, stream>>>(
        Xb, w0t, b_in0, H0b, N_NODES, H_IN_, IN_DIM_,
        staging, bcnt, offs, ends, edst);

    gemm_async_kernel<<<dim3(2, gM32), blk, 0, stream>>>(H0b, w1t, b_in1, nullptr, H1b, N_NODES, H_IN_, H_IN_, 1);
    gemm_async_kernel<<<dim3(1, gM32), blk, 0, stream>>>(H1b, w2t, b_in2, H, Hb, N_NODES, DDIM, H_IN_, 1);

    for (int b = 0; b < 2; b++) {
        zg_gemm_kernel<<<dim3(2, gM32), blk, 0, stream>>>(Hb, wzg[b], bg1[b], Zb, GH, N_NODES);
        float* alph = alpha_out + (size_t)b * N_NODES * KADJ;
        gate_fuse_kernel<<<CSR_TOTAL / 32, blk, 0, stream>>>(
            offs, ends, edst, Zb, wgmt[b], GH, logdeg, Wg1[b] + 256 * GATE_H_,
            Wg2[b], bg2[b], mask, H, Ybuf, alph, red + b * 8 * 132);
        pairnorm_kernel<<<(N_NODES + 1) / 2, blk, 0, stream>>>(Ybuf, red + b * 8 * 132, H, Hb, N_NODES);
    }

    // head (+ fused logits)
    head_gemm_kernel<<<gM32, blk, 0, stream>>>(Hb, wh1t, bh1, Wh2, bh2, logits, N_NODES);
}

// Round 7
// 463.332 us; speedup vs baseline: 1.0142x; 1.0142x over previous
//
#include <hip/hip_runtime.h>
#include <hip/hip_bf16.h>

#define N_NODES 20000
#define KADJ 4
#define NEDGE 320000
#define ETOTAL (KADJ * NEDGE)               // 1,280,000
#define IN_DIM_ 1024
#define H_IN_ 256
#define DDIM 128
#define GATE_H_ 128
#define TEMP_ 0.6f
#define M_CLAMP_ 20.0f
#define CSR_TOTAL (KADJ * N_NODES)          // 80000
#define NCOARSE 128
#define QPER (CSR_TOTAL / NCOARSE)          // 625
#define ESTRIDE 12288                       // bucket slot stride (exp fill 10000, sigma~100)
#define TILE_A 4096
#define BINA_NB ((ETOTAL + TILE_A - 1) / TILE_A)  // 313
#define NB_CAST (N_NODES * IN_DIM_ / 8 / 256)     // 10000
#define NB_TRANS 2560                              // 8 x 32 x 10

typedef __attribute__((ext_vector_type(8))) short frag_ab;      // 8 bf16
typedef __attribute__((ext_vector_type(4))) float frag_cd;      // 4 fp32
typedef __attribute__((ext_vector_type(8))) unsigned short us8;

__device__ inline unsigned short f2bf(float f) {
    unsigned int u = __float_as_uint(f);
    u += 0x7FFFu + ((u >> 16) & 1);   // RNE
    return (unsigned short)(u >> 16);
}
__device__ inline float bflo(unsigned int p) { return __uint_as_float(p << 16); }
__device__ inline float bfhi(unsigned int p) { return __uint_as_float(p & 0xffff0000u); }

// async 16B global->LDS (wave-uniform LDS base + lane*16)
__device__ __forceinline__ void gld16(const unsigned short* g, unsigned short* l) {
    __builtin_amdgcn_global_load_lds(
        (const __attribute__((address_space(1))) void*)g,
        (__attribute__((address_space(3))) void*)l, 16, 0, 0);
}

// ---- pipelined K-loop building blocks: per wave per stage exactly 5 gld16 ----
#define PIPE_WAIT_NEXT()  asm volatile("s_waitcnt vmcnt(5)" ::: "memory")
#define PIPE_WAIT_LAST()  asm volatile("s_waitcnt vmcnt(0)" ::: "memory")
#define PIPE_BAR()        __builtin_amdgcn_s_barrier()
#define PIPE_FENCE()      __builtin_amdgcn_sched_barrier(0)

struct TD { const float* src; unsigned short* dst; int K; int N; };
struct TD10 { TD d[10]; };

// ============== prep mega-kernel: binA2 FIRST (latency-bound) ++ transposes ++ X cast =======
__global__ __launch_bounds__(256) void prep_kernel(
    const float* __restrict__ X, unsigned short* __restrict__ Xb,
    TD10 descs,
    const int* __restrict__ rows, const int* __restrict__ cols,
    int* __restrict__ bcnt, uint2* __restrict__ staging)
{
    __shared__ __align__(16) char sraw[2048 + TILE_A * 8];   // 34 KB
    int bid = blockIdx.x;
    int tid = threadIdx.x;

    if (bid >= BINA_NB + NB_TRANS) {
        // ---- X fp32 -> bf16 streaming cast (scheduled last; BW-bound) ----
        int i = ((bid - BINA_NB - NB_TRANS) * 256 + tid) * 8;
        float4 a = *(const float4*)(X + i), b = *(const float4*)(X + i + 4);
        us8 o;
        o[0] = f2bf(a.x); o[1] = f2bf(a.y); o[2] = f2bf(a.z); o[3] = f2bf(a.w);
        o[4] = f2bf(b.x); o[5] = f2bf(b.y); o[6] = f2bf(b.z); o[7] = f2bf(b.w);
        *(us8*)(Xb + i) = o;
        return;
    }
    if (bid >= BINA_NB) {
        // ---- weight transpose ----
        int b2 = bid - BINA_NB;
        TD t = descs.d[b2 >> 8];
        int rem = b2 & 255;
        int n0 = (rem & 7) * 32, k0 = (rem >> 3) * 32;
        if (n0 >= t.N || k0 >= t.K) return;
        float (*tile)[33] = (float(*)[33])sraw;
        int tx = tid & 31, ty4 = (tid >> 5) * 4;
#pragma unroll
        for (int i = 0; i < 4; i++)
            tile[ty4 + i][tx] = t.src[(size_t)(k0 + ty4 + i) * t.N + n0 + tx];
        __syncthreads();
#pragma unroll
        for (int i = 0; i < 4; i++)
            t.dst[(size_t)(n0 + ty4 + i) * t.K + k0 + tx] = f2bf(tile[tx][ty4 + i]);
        return;
    }
    // ---- binA2: CSR coarse binning (dispatched FIRST, overlaps with cast) ----
    int* hist  = (int*)sraw;
    int* hscan = hist + NCOARSE;
    int* lcur  = hscan + NCOARSE;
    int* gbase = lcur + NCOARSE;
    uint2* pairs = (uint2*)(sraw + 2048);

    int base = bid * TILE_A;
    int cnt_t = min(TILE_A, ETOTAL - base);

    for (int i = tid; i < NCOARSE; i += 256) hist[i] = 0;
    __syncthreads();

    unsigned int q[16], c[16];
    bool valid[16];
#pragma unroll
    for (int i = 0; i < 16; i++) {
        int loc = i * 256 + tid;
        valid[i] = loc < cnt_t;
        if (valid[i]) {
            int e = base + loc;
            int k = e / NEDGE;
            unsigned int qq = (unsigned int)(k * N_NODES + rows[e]);
            q[i] = qq;
            c[i] = (unsigned int)cols[e];
            atomicAdd(&hist[qq / QPER], 1);
        }
    }
    __syncthreads();
    if (tid < NCOARSE) hscan[tid] = hist[tid];
    __syncthreads();
    for (int d = 1; d < NCOARSE; d <<= 1) {
        int v = (tid >= d && tid < NCOARSE) ? hscan[tid - d] : 0;
        __syncthreads();
        if (tid < NCOARSE) hscan[tid] += v;
        __syncthreads();
    }
    if (tid < NCOARSE) {
        int ex = hscan[tid] - hist[tid];
        hscan[tid] = ex;
        lcur[tid] = ex;
        gbase[tid] = hist[tid] ? (tid * ESTRIDE + atomicAdd(&bcnt[tid], hist[tid])) : 0;
    }
    __syncthreads();
#pragma unroll
    for (int i = 0; i < 16; i++) {
        if (valid[i]) {
            int b = q[i] / QPER;
            int p = atomicAdd(&lcur[b], 1);
            pairs[p] = make_uint2(q[i], c[i]);
        }
    }
    __syncthreads();
    for (int i = tid; i < cnt_t; i += 256) {
        uint2 pr = pairs[i];
        int b = pr.x / QPER;
        staging[gbase[b] + (i - hscan[b])] = pr;
    }
}

// ============== gemm1 ++ binB2 in one launch (independent; staging must NOT alias H0b!) ======
__global__ __launch_bounds__(256) void gemm1_binb_kernel(
    const unsigned short* __restrict__ A, const unsigned short* __restrict__ Bt,
    const float* __restrict__ bias, unsigned short* __restrict__ Cb,
    int M, int N, int K,
    const uint2* __restrict__ staging, const int* __restrict__ bcnt,
    int* __restrict__ offs, int* __restrict__ ends, int* __restrict__ edst)
{
    __shared__ __align__(16) char smem[40960];
    int tid = threadIdx.x;
    int bid = blockIdx.x;
    const int GEMM_NB = 2 * 625;

    if (bid < GEMM_NB) {
        unsigned short* sA0 = (unsigned short*)smem;           // 2 x 2048 shorts
        unsigned short* sB0 = (unsigned short*)(smem + 8192);  // 2 x 8192 shorts
        int tileM = (bid >> 1) * 32, tileN = (bid & 1) * 128;
        int w = tid >> 6, lane = tid & 63;
        int wr = (w & 1) * 16, wc = (w >> 1) * 64;
        int fm = lane & 15, fq = lane >> 4;
        int crow = lane >> 3;
        int gsw = (lane & 7) ^ crow;

        frag_cd acc[4] = {};

        auto stage = [&](int buf, int k0) {
            {
                int row = w * 8 + crow;
                int ar = min(tileM + row, M - 1);
                gld16(A + (size_t)ar * K + k0 + gsw * 8, sA0 + buf * 2048 + w * 512);
            }
#pragma unroll
            for (int t = 0; t < 4; t++) {
                int chunk = w * 4 + t;
                int row = chunk * 8 + crow;
                gld16(Bt + (size_t)(tileN + row) * K + k0 + gsw * 8, sB0 + buf * 8192 + chunk * 512);
            }
        };

        int nt = K >> 6;
        stage(0, 0);
        for (int t = 0; t < nt; t++) {
            int cur = t & 1;
            if (t + 1 < nt) { stage(cur ^ 1, (t + 1) << 6); PIPE_WAIT_NEXT(); }
            else            { PIPE_WAIT_LAST(); }
            PIPE_BAR();
            PIPE_FENCE();
#pragma unroll
            for (int s = 0; s < 2; s++) {
                int sw = ((s * 4 + fq) ^ (fm & 7)) * 8;
                frag_ab af = *(const frag_ab*)(sA0 + cur * 2048 + (wr + fm) * 64 + sw);
#pragma unroll
                for (int j = 0; j < 4; j++) {
                    frag_ab bf = *(const frag_ab*)(sB0 + cur * 8192 + (wc + j * 16 + fm) * 64 + sw);
                    acc[j] = __builtin_amdgcn_mfma_f32_16x16x32_bf16(af, bf, acc[j], 0, 0, 0);
                }
            }
            PIPE_FENCE();
            PIPE_BAR();
        }
        int row = tileM + wr + fq * 4;
#pragma unroll
        for (int r = 0; r < 4; r++) {
            if (row + r < M) {
#pragma unroll
                for (int j = 0; j < 4; j++) {
                    int col = tileN + wc + j * 16 + fm;
                    float v = fmaxf(acc[j][r] + bias[col], 0.f);
                    Cb[(size_t)(row + r) * N + col] = f2bf(v);
                }
            }
        }
        return;
    }
    // ---- binB2 ----
    int* cntS = (int*)smem;
    int* sofs = cntS + QPER;
    int* lcur = sofs + QPER;
    int* psum = lcur + QPER;
    int b = bid - GEMM_NB;
    int q0 = b * QPER, base = b * ESTRIDE;
    int fill = bcnt[b];
    for (int i = tid; i < QPER; i += 256) cntS[i] = 0;
    __syncthreads();
    for (int i = tid; i < fill; i += 256)
        atomicAdd(&cntS[staging[base + i].x - q0], 1);
    __syncthreads();
    const int CH = 3;
    int lo = tid * CH, hi = min(lo + CH, QPER);
    int s = 0;
    for (int i = lo; i < hi; i++) s += cntS[i];
    psum[tid] = s;
    __syncthreads();
    for (int d = 1; d < 256; d <<= 1) {
        int v = (tid >= d) ? psum[tid - d] : 0;
        __syncthreads();
        psum[tid] += v;
        __syncthreads();
    }
    int run = (tid == 0) ? 0 : psum[tid - 1];
    for (int i = lo; i < hi; i++) {
        sofs[i] = run;
        lcur[i] = run;
        run += cntS[i];
    }
    __syncthreads();
    for (int i = tid; i < QPER; i += 256) {
        offs[q0 + i] = base + sofs[i];
        ends[q0 + i] = base + sofs[i] + cntS[i];
    }
    for (int i = tid; i < fill; i += 256) {
        uint2 p = staging[base + i];
        int pos = atomicAdd(&lcur[p.x - q0], 1);
        edst[base + pos] = (int)p.y;
    }
}

// ============== async bf16 MFMA GEMM: C = [relu](A[M,K]_bf16 @ (Bt[N,K]_bf16)^T + bias) =========
__global__ __launch_bounds__(256) void gemm_async_kernel(
    const unsigned short* __restrict__ A, const unsigned short* __restrict__ Bt,
    const float* __restrict__ bias, float* __restrict__ Cf, unsigned short* __restrict__ Cb,
    int M, int N, int K, int do_relu)
{
    __shared__ unsigned short sA[2][32 * 64];
    __shared__ unsigned short sB[2][128 * 64];
    int tid = threadIdx.x;
    int tileM = blockIdx.y * 32, tileN = blockIdx.x * 128;
    int w = tid >> 6, lane = tid & 63;
    int wr = (w & 1) * 16, wc = (w >> 1) * 64;
    int fm = lane & 15, fq = lane >> 4;
    int crow = lane >> 3;
    int gsw = (lane & 7) ^ crow;

    frag_cd acc[4] = {};

    auto stage = [&](int buf, int k0) {
        {
            int row = w * 8 + crow;
            int ar = min(tileM + row, M - 1);
            gld16(A + (size_t)ar * K + k0 + gsw * 8, &sA[buf][w * 512]);
        }
#pragma unroll
        for (int t = 0; t < 4; t++) {
            int chunk = w * 4 + t;
            int row = chunk * 8 + crow;
            gld16(Bt + (size_t)(tileN + row) * K + k0 + gsw * 8, &sB[buf][chunk * 512]);
        }
    };

    int nt = K >> 6;
    stage(0, 0);
    for (int t = 0; t < nt; t++) {
        int cur = t & 1;
        if (t + 1 < nt) { stage(cur ^ 1, (t + 1) << 6); PIPE_WAIT_NEXT(); }
        else            { PIPE_WAIT_LAST(); }
        PIPE_BAR();
        PIPE_FENCE();
#pragma unroll
        for (int s = 0; s < 2; s++) {
            int sw = ((s * 4 + fq) ^ (fm & 7)) * 8;
            frag_ab af = *(const frag_ab*)&sA[cur][(wr + fm) * 64 + sw];
#pragma unroll
            for (int j = 0; j < 4; j++) {
                frag_ab bf = *(const frag_ab*)&sB[cur][(wc + j * 16 + fm) * 64 + sw];
                acc[j] = __builtin_amdgcn_mfma_f32_16x16x32_bf16(af, bf, acc[j], 0, 0, 0);
            }
        }
        PIPE_FENCE();
        PIPE_BAR();
    }
    int row = tileM + wr + fq * 4;
#pragma unroll
    for (int r = 0; r < 4; r++) {
        if (row + r < M) {
#pragma unroll
            for (int j = 0; j < 4; j++) {
                int col = tileN + wc + j * 16 + fm;
                float v = acc[j][r];
                if (bias) v += bias[col];
                if (do_relu) v = fmaxf(v, 0.f);
                if (Cf) Cf[(size_t)(row + r) * N + col] = v;
                if (Cb) Cb[(size_t)(row + r) * N + col] = f2bf(v);
            }
        }
    }
}

// ============== fused Z+GH GEMM: A=Hb[M,128], Bt=wzg[256][128] ==============
__global__ __launch_bounds__(256) void zg_gemm_kernel(
    const unsigned short* __restrict__ A, const unsigned short* __restrict__ Bt,
    const float* __restrict__ bg1, unsigned short* __restrict__ Zb,
    float* __restrict__ GH, int M)
{
    __shared__ unsigned short sA[2][32 * 64];
    __shared__ unsigned short sB[2][128 * 64];
    int tid = threadIdx.x;
    int tileM = blockIdx.y * 32, tileN = blockIdx.x * 128;
    int w = tid >> 6, lane = tid & 63;
    int wr = (w & 1) * 16, wc = (w >> 1) * 64;
    int fm = lane & 15, fq = lane >> 4;
    int crow = lane >> 3;
    int gsw = (lane & 7) ^ crow;

    frag_cd acc[4] = {};

    auto stage = [&](int buf, int k0) {
        {
            int row = w * 8 + crow;
            int ar = min(tileM + row, M - 1);
            gld16(A + (size_t)ar * DDIM + k0 + gsw * 8, &sA[buf][w * 512]);
        }
#pragma unroll
        for (int t = 0; t < 4; t++) {
            int chunk = w * 4 + t;
            int row = chunk * 8 + crow;
            gld16(Bt + (size_t)(tileN + row) * DDIM + k0 + gsw * 8, &sB[buf][chunk * 512]);
        }
    };

    stage(0, 0);
#pragma unroll
    for (int t = 0; t < 2; t++) {
        int cur = t & 1;
        if (t == 0) { stage(1, 64); PIPE_WAIT_NEXT(); }
        else        { PIPE_WAIT_LAST(); }
        PIPE_BAR();
        PIPE_FENCE();
#pragma unroll
        for (int s = 0; s < 2; s++) {
            int sw = ((s * 4 + fq) ^ (fm & 7)) * 8;
            frag_ab af = *(const frag_ab*)&sA[cur][(wr + fm) * 64 + sw];
#pragma unroll
            for (int j = 0; j < 4; j++) {
                frag_ab bf = *(const frag_ab*)&sB[cur][(wc + j * 16 + fm) * 64 + sw];
                acc[j] = __builtin_amdgcn_mfma_f32_16x16x32_bf16(af, bf, acc[j], 0, 0, 0);
            }
        }
        PIPE_FENCE();
        PIPE_BAR();
    }
    int isZ = (blockIdx.x == 0);
    int row = tileM + wr + fq * 4;
#pragma unroll
    for (int r = 0; r < 4; r++) {
        if (row + r < M) {
#pragma unroll
            for (int j = 0; j < 4; j++) {
                int col = wc + j * 16 + fm;    // local 0..127
                float v = acc[j][r];
                if (isZ) Zb[(size_t)(row + r) * DDIM + col] = f2bf(v);
                else     GH[(size_t)(row + r) * GATE_H_ + col] = v + bg1[col];
            }
        }
    }
}

// ============== head GEMM + logits epilogue: logits = relu(Hb@Wh1+bh1) . Wh2 + bh2 ========
__global__ __launch_bounds__(256) void head_gemm_kernel(
    const unsigned short* __restrict__ A, const unsigned short* __restrict__ Bt,
    const float* __restrict__ bh1, const float* __restrict__ Wh2,
    const float* __restrict__ bh2, float* __restrict__ logits, int M)
{
    __shared__ unsigned short sA[2][32 * 64];
    __shared__ unsigned short sB[2][128 * 64];
    __shared__ float sred[2][32];
    int tid = threadIdx.x;
    int tileM = blockIdx.x * 32;
    int w = tid >> 6, lane = tid & 63;
    int wr = (w & 1) * 16, wc = (w >> 1) * 64;
    int fm = lane & 15, fq = lane >> 4;
    int crow = lane >> 3;
    int gsw = (lane & 7) ^ crow;

    frag_cd acc[4] = {};

    auto stage = [&](int buf, int k0) {
        {
            int row = w * 8 + crow;
            int ar = min(tileM + row, M - 1);
            gld16(A + (size_t)ar * DDIM + k0 + gsw * 8, &sA[buf][w * 512]);
        }
#pragma unroll
        for (int t = 0; t < 4; t++) {
            int chunk = w * 4 + t;
            int row = chunk * 8 + crow;
            gld16(Bt + (size_t)row * DDIM + k0 + gsw * 8, &sB[buf][chunk * 512]);
        }
    };

    stage(0, 0);
#pragma unroll
    for (int t = 0; t < 2; t++) {
        int cur = t & 1;
        if (t == 0) { stage(1, 64); PIPE_WAIT_NEXT(); }
        else        { PIPE_WAIT_LAST(); }
        PIPE_BAR();
        PIPE_FENCE();
#pragma unroll
        for (int s = 0; s < 2; s++) {
            int sw = ((s * 4 + fq) ^ (fm & 7)) * 8;
            frag_ab af = *(const frag_ab*)&sA[cur][(wr + fm) * 64 + sw];
#pragma unroll
            for (int j = 0; j < 4; j++) {
                frag_ab bf = *(const frag_ab*)&sB[cur][(wc + j * 16 + fm) * 64 + sw];
                acc[j] = __builtin_amdgcn_mfma_f32_16x16x32_bf16(af, bf, acc[j], 0, 0, 0);
            }
        }
        PIPE_FENCE();
        PIPE_BAR();
    }
    float wv[4], bh[4];
#pragma unroll
    for (int j = 0; j < 4; j++) {
        int c = wc + j * 16 + fm;
        wv[j] = Wh2[c];
        bh[j] = bh1[c];
    }
    float part[4];
#pragma unroll
    for (int r = 0; r < 4; r++) {
        float p = 0.f;
#pragma unroll
        for (int j = 0; j < 4; j++) {
            float v = fmaxf(acc[j][r] + bh[j], 0.f);
            p += v * wv[j];
        }
        part[r] = p;
    }
#pragma unroll
    for (int m = 1; m < 16; m <<= 1)
#pragma unroll
        for (int r = 0; r < 4; r++)
            part[r] += __shfl_xor(part[r], m, 64);
    if (fm == 0) {
#pragma unroll
        for (int r = 0; r < 4; r++)
            sred[w >> 1][wr + fq * 4 + r] = part[r];
    }
    __syncthreads();
    if (tid < 32 && tileM + tid < M)
        logits[tileM + tid] = sred[0][tid] + sred[1][tid] + bh2[0];
}

// ---------------- gather: Mb[r*4+k, half*64 + :64] = bf16(clip(sum Zb[col_e, half])) --------
// d-half split + XCD routing: half = (bid>>2)&1 -> in each run of 8 consecutive blocks,
// blocks 0-3 do half 0, 4-7 do half 1. Under round-robin block->XCD dispatch each XCD
// touches only 2.56 MB of Zb -> fits 4 MiB L2 (perf heuristic only, not correctness).
// Per wave: one q, 8 edge-groups x 8 lanes x 16B, 16 edge-loads in flight.
__global__ __launch_bounds__(256) void gather_kernel(
    const int* __restrict__ offs, const int* __restrict__ ends,
    const int* __restrict__ edst,
    const unsigned short* __restrict__ Zb, unsigned short* __restrict__ Mb)
{
    int bid = blockIdx.x;                    // 40000
    int half = (bid >> 2) & 1;
    int qgroup = (bid >> 3) * 4 + (bid & 3); // 0..19999
    int w = threadIdx.x >> 6;
    int q = qgroup * 4 + w;                  // CSR index q = k*N + r
    int lane = threadIdx.x & 63;
    int eg = lane >> 3;                      // edge group 0..7
    int l = lane & 7;                        // 8 lanes x 16B cover one 128B half-row
    int k = q / N_NODES;
    int r = q - k * N_NODES;
    int start = offs[q];
    int end = ends[q];
    const unsigned short* Zh = Zb + half * 64 + l * 8;

    float a0 = 0.f, a1 = 0.f, a2 = 0.f, a3 = 0.f;
    float a4 = 0.f, a5 = 0.f, a6 = 0.f, a7 = 0.f;

#define ACC8(P) {                                  \
        a0 += bflo(P.x); a1 += bfhi(P.x);          \
        a2 += bflo(P.y); a3 += bfhi(P.y);          \
        a4 += bflo(P.z); a5 += bfhi(P.z);          \
        a6 += bflo(P.w); a7 += bfhi(P.w); }

    int i = start + eg;
    // 2 edges per group in flight (16 per wave)
    for (; i + 8 < end; i += 16) {
        int c0 = edst[i], c1 = edst[i + 8];
        uint4 p0 = *(const uint4*)(Zh + (size_t)c0 * DDIM);
        uint4 p1 = *(const uint4*)(Zh + (size_t)c1 * DDIM);
        ACC8(p0); ACC8(p1);
    }
    if (i < end) {
        int c0 = edst[i];
        uint4 p0 = *(const uint4*)(Zh + (size_t)c0 * DDIM);
        ACC8(p0);
    }
#undef ACC8

    // combine 8 edge-groups: lanes l, l+8, ..., l+56 hold the same d-range
#define GRED(x) { x += __shfl_xor(x, 8, 64); x += __shfl_xor(x, 16, 64); x += __shfl_xor(x, 32, 64); }
    GRED(a0) GRED(a1) GRED(a2) GRED(a3) GRED(a4) GRED(a5) GRED(a6) GRED(a7)
#undef GRED

#define CLIP(v) fminf(fmaxf(v, -M_CLAMP_), M_CLAMP_)
    unsigned int w0 = (unsigned int)f2bf(CLIP(a0)) | ((unsigned int)f2bf(CLIP(a1)) << 16);
    unsigned int w1 = (unsigned int)f2bf(CLIP(a2)) | ((unsigned int)f2bf(CLIP(a3)) << 16);
    unsigned int w2 = (unsigned int)f2bf(CLIP(a4)) | ((unsigned int)f2bf(CLIP(a5)) << 16);
    unsigned int w3 = (unsigned int)f2bf(CLIP(a6)) | ((unsigned int)f2bf(CLIP(a7)) << 16);
#undef CLIP
    if (eg == 0) {
        uint4 o = make_uint4(w0, w1, w2, w3);
        *(uint4*)(Mb + ((size_t)r * KADJ + k) * DDIM + half * 64 + l * 8) = o;
    }
}

// ============== gate GEMM + FUSED alpha/Y/pairnorm-partial epilogue (Mb from global) =========
__global__ __launch_bounds__(256) void gate_fuse_kernel(
    const unsigned short* __restrict__ Mb, const unsigned short* __restrict__ Bt,
    const float* __restrict__ GH, const float* __restrict__ logdeg,
    const float* __restrict__ wld, const float* __restrict__ Wg2,
    const float* __restrict__ bg2, const float* __restrict__ mask,
    const float* __restrict__ H, float* __restrict__ Y,
    float* __restrict__ alpha_out, float* __restrict__ red)
{
    __shared__ unsigned short sA[2][32 * 64];
    __shared__ unsigned short sB[2][128 * 64];
    __shared__ float sred[2][32];
    __shared__ float sc_al[64];          // [0:32) scores, [32:64) alpha
    __shared__ float sx[256], sy[256], sqs[256];
    int tid = threadIdx.x;
    int tile0 = blockIdx.x * 32;
    int node0 = blockIdx.x * 8;
    int w = tid >> 6, lane = tid & 63;
    int wr = (w & 1) * 16, wc = (w >> 1) * 64;
    int fm = lane & 15, fq = lane >> 4;
    int crow = lane >> 3;
    int gsw = (lane & 7) ^ crow;

    frag_cd acc[4] = {};

    auto stage = [&](int buf, int k0) {
        {
            int row = w * 8 + crow;
            gld16(Mb + (size_t)(tile0 + row) * DDIM + k0 + gsw * 8, &sA[buf][w * 512]);
        }
#pragma unroll
        for (int t = 0; t < 4; t++) {
            int chunk = w * 4 + t;
            int row = chunk * 8 + crow;
            gld16(Bt + (size_t)row * DDIM + k0 + gsw * 8, &sB[buf][chunk * 512]);
        }
    };

    stage(0, 0);
#pragma unroll
    for (int t = 0; t < 2; t++) {
        int cur = t & 1;
        if (t == 0) { stage(1, 64); PIPE_WAIT_NEXT(); }
        else        { PIPE_WAIT_LAST(); }
        PIPE_BAR();
        PIPE_FENCE();
#pragma unroll
        for (int s = 0; s < 2; s++) {
            int sw = ((s * 4 + fq) ^ (fm & 7)) * 8;
            frag_ab af = *(const frag_ab*)&sA[cur][(wr + fm) * 64 + sw];
#pragma unroll
            for (int j = 0; j < 4; j++) {
                frag_ab bf = *(const frag_ab*)&sB[cur][(wc + j * 16 + fm) * 64 + sw];
                acc[j] = __builtin_amdgcn_mfma_f32_16x16x32_bf16(af, bf, acc[j], 0, 0, 0);
            }
        }
        PIPE_FENCE();
        PIPE_BAR();
    }
    float wg2v[4], wldv[4];
#pragma unroll
    for (int j = 0; j < 4; j++) {
        int c = wc + j * 16 + fm;
        wg2v[j] = Wg2[c];
        wldv[j] = wld[c];
    }
    float part[4];
#pragma unroll
    for (int r = 0; r < 4; r++) {
        int q = tile0 + wr + fq * 4 + r;
        int n = q >> 2;
        float ld = logdeg[q];
        float p = 0.f;
#pragma unroll
        for (int j = 0; j < 4; j++) {
            int c = wc + j * 16 + fm;
            float v = acc[j][r] + GH[(size_t)n * GATE_H_ + c] + ld * wldv[j];
            p += fmaxf(v, 0.f) * wg2v[j];
        }
        part[r] = p;
    }
#pragma unroll
    for (int m = 1; m < 16; m <<= 1)
#pragma unroll
        for (int r = 0; r < 4; r++)
            part[r] += __shfl_xor(part[r], m, 64);
    if (fm == 0) {
#pragma unroll
        for (int r = 0; r < 4; r++)
            sred[w >> 1][wr + fq * 4 + r] = part[r];
    }
    __syncthreads();
    if (tid < 32) sc_al[tid] = sred[0][tid] + sred[1][tid] + bg2[0];
    __syncthreads();
    // ---- softmax + mask renorm per node (threads 0..7) ----
    if (tid < 8) {
        int n = node0 + tid;
        float a[KADJ];
        float mx = -1e30f;
#pragma unroll
        for (int k = 0; k < KADJ; k++) {
            a[k] = sc_al[tid * 4 + k] * (1.0f / TEMP_);
            mx = fmaxf(mx, a[k]);
        }
        float sum = 0.f;
#pragma unroll
        for (int k = 0; k < KADJ; k++) { a[k] = expf(a[k] - mx); sum += a[k]; }
#pragma unroll
        for (int k = 0; k < KADJ; k++) a[k] = (a[k] / sum) * mask[(size_t)n * KADJ + k];
        float s2 = 0.f;
#pragma unroll
        for (int k = 0; k < KADJ; k++) s2 += a[k];
        float inv = 1.f / fmaxf(s2, 1e-12f);
#pragma unroll
        for (int k = 0; k < KADJ; k++) a[k] = fmaxf(a[k] * inv, 1e-8f);
        s2 = 0.f;
#pragma unroll
        for (int k = 0; k < KADJ; k++) s2 += a[k];
        inv = 1.f / fmaxf(s2, 1e-12f);
#pragma unroll
        for (int k = 0; k < KADJ; k++) sc_al[32 + tid * 4 + k] = a[k] * inv;
    }
    __syncthreads();
    if (tid < 32) alpha_out[tile0 + tid] = sc_al[32 + tid];
    // ---- Y = H + sum_k a_k M, + pairnorm partials (8 nodes x 64 d-pairs) ----
    float csx = 0.f, csy = 0.f, sq = 0.f;
    int j = tid & 63, dd = j * 2;
#pragma unroll
    for (int it = 0; it < 2; it++) {
        int nl = (tid >> 6) + it * 4;
        int n = node0 + nl;
        const float* alp = &sc_al[32 + nl * 4];
        float2 h = *(const float2*)(H + (size_t)n * DDIM + dd);
        float yx = h.x, yy = h.y;
#pragma unroll
        for (int k = 0; k < KADJ; k++) {
            unsigned int u = *(const unsigned int*)(Mb + ((size_t)n * KADJ + k) * DDIM + dd);
            yx += alp[k] * bflo(u);
            yy += alp[k] * bfhi(u);
        }
        *(float2*)(Y + (size_t)n * DDIM + dd) = make_float2(yx, yy);
        csx += yx; csy += yy;
        sq += yx * yx + yy * yy;
    }
    sx[tid] = csx; sy[tid] = csy; sqs[tid] = sq;
    __syncthreads();
    int st = (blockIdx.x & 7) * 132;
    if (tid < 64) {
        float ax = sx[tid] + sx[tid + 64] + sx[tid + 128] + sx[tid + 192];
        float ay = sy[tid] + sy[tid + 64] + sy[tid + 128] + sy[tid + 192];
        atomicAdd(&red[st + tid * 2], ax);
        atomicAdd(&red[st + tid * 2 + 1], ay);
    }
    for (int s = 128; s > 0; s >>= 1) {
        if (tid < s) sqs[tid] += sqs[tid + s];
        __syncthreads();
    }
    if (tid == 0) atomicAdd(&red[st + 128], sqs[0]);
}

// ---------------- pairnorm apply: sums 8 red stripes, writes H fp32 + Hb bf16 ----------
__global__ __launch_bounds__(256) void pairnorm_kernel(
    const float* __restrict__ Y, const float* __restrict__ red,
    float* __restrict__ Hout, unsigned short* __restrict__ Hb, int N)
{
    int tid = threadIdx.x;
    int d = tid & 127;
    float invN = 1.0f / (float)N;
    float s = 0.f, rq = 0.f;
#pragma unroll
    for (int st = 0; st < 8; st++) {
        s += red[st * 132 + d];
        rq += red[st * 132 + 128];
    }
    float mu = s * invN;
    __shared__ float smu2[128];
    if (tid < 128) smu2[tid] = mu * mu;
    __syncthreads();
    for (int t = 64; t > 0; t >>= 1) {
        if (tid < t) smu2[tid] += smu2[tid + t];
        __syncthreads();
    }
    float summu2 = smu2[0];
    float var = rq * invN - summu2;
    float norm = sqrtf(fmaxf(var, 0.f)) + 1e-6f;
    float inv = 1.0f / norm;
    int n = blockIdx.x * 2 + (tid >> 7);
    if (n < N) {
        float v = (Y[(size_t)n * DDIM + d] - mu) * inv;
        v = fmaxf(v, 0.f);
        Hout[(size_t)n * DDIM + d] = v;
        Hb[(size_t)n * DDIM + d] = f2bf(v);
    }
}

extern "C" void kernel_launch(void* const* d_in, const int* in_sizes, int n_in,
                              void* d_out, int out_size, void* d_ws, size_t ws_size,
                              hipStream_t stream)
{
    const float* X      = (const float*)d_in[0];
    const int*   rows   = (const int*)d_in[1];
    const int*   cols   = (const int*)d_in[2];
    const float* mask   = (const float*)d_in[3];
    const float* logdeg = (const float*)d_in[4];
    const float* W_in0  = (const float*)d_in[5];
    const float* b_in0  = (const float*)d_in[6];
    const float* W_in1  = (const float*)d_in[7];
    const float* b_in1  = (const float*)d_in[8];
    const float* W_in2  = (const float*)d_in[9];
    const float* b_in2  = (const float*)d_in[10];
    const float* Wmsg[2] = {(const float*)d_in[11], (const float*)d_in[16]};
    const float* Wg1[2]  = {(const float*)d_in[12], (const float*)d_in[17]};
    const float* bg1[2]  = {(const float*)d_in[13], (const float*)d_in[18]};
    const float* Wg2[2]  = {(const float*)d_in[14], (const float*)d_in[19]};
    const float* bg2[2]  = {(const float*)d_in[15], (const float*)d_in[20]};
    const float* Wh1 = (const float*)d_in[21];
    const float* bh1 = (const float*)d_in[22];
    const float* Wh2 = (const float*)d_in[23];
    const float* bh2 = (const float*)d_in[24];

    // workspace layout (float slots), ~85 MB.
    // LIFETIME MAP (race-audited):
    //   Xb      0        - 10240000   written prep, read gemm1. Dead after gemm1.
    //   Mb      0        -  5120000   written gather (block loop), read gate_fuse. (Xb dead)
    //   H0b     10240000 - 12800000   written gemm1, read gemm2
    //   H1b/Zb  12800000 - 15360000   gemm2->gemm3; zg->gather
    //   staging 15360000 - 18505728   written prep(binA2), read binB2 (inside gemm1 launch).
    //                                 (MUST NOT alias H0b: binB2 runs concurrently with gemm1!)
    //   H       15360000 - 17920000   written gemm3 (after staging dead)
    //   Hb      17920000 - 19200000   written gemm3
    float* ws = (float*)d_ws;
    unsigned short* Xb  = (unsigned short*)ws;
    unsigned short* Mb  = (unsigned short*)ws;
    float* Ybuf  = ws + 5120000;
    float* GH    = ws + 7680000;
    unsigned short* H0b = (unsigned short*)(ws + 10240000);
    unsigned short* H1b = (unsigned short*)(ws + 12800000);
    unsigned short* Zb  = (unsigned short*)(ws + 12800000);
    uint2* staging = (uint2*)(ws + 15360000);       // NCOARSE*ESTRIDE*2 = 3,145,728 slots
    float* H     = ws + 15360000;                   // 2.56M (after staging dead)
    unsigned short* Hb = (unsigned short*)(ws + 17920000);  // 1.28M slots
    int*   bcnt  = (int*)(ws + 19200000);           // 128
    float* red   = ws + 19200128;                   // 2 blocks x 8 stripes x 132
    int*   offs   = (int*)(ws + 19280000);          // 80000
    int*   ends   = (int*)(ws + 19360000);          // 80000
    int*   edst   = (int*)(ws + 19440000);          // NCOARSE*ESTRIDE = 1,572,864
    unsigned short* w0t  = (unsigned short*)(ws + 21013248);  // 131072 slots
    unsigned short* w1t  = (unsigned short*)(ws + 21144320);  // 32768
    unsigned short* w2t  = (unsigned short*)(ws + 21177088);  // 16384
    unsigned short* wzg[2]  = {(unsigned short*)(ws + 21193472), (unsigned short*)(ws + 21209856)};  // 256x128 each
    unsigned short* wgmt[2] = {(unsigned short*)(ws + 21226240), (unsigned short*)(ws + 21234432)};
    unsigned short* wh1t = (unsigned short*)(ws + 21242624);
    float* logits = (float*)d_out;
    float* alpha_out = (float*)d_out + N_NODES;

    dim3 blk(256);
    int gM32 = (N_NODES + 31) / 32;     // 625

    // ---- one memset: bcnt(128 ints) + red(2x8x132 floats) contiguous ----
    (void)hipMemsetAsync(bcnt, 0, (128 + 2 * 8 * 132) * sizeof(float), stream);

    // ---- prep: binA2 (first) + transposes + cast in ONE launch ----
    TD10 descs;
    descs.d[0] = {W_in0, w0t, IN_DIM_, H_IN_};
    descs.d[1] = {W_in1, w1t, H_IN_, H_IN_};
    descs.d[2] = {W_in2, w2t, H_IN_, DDIM};
    descs.d[3] = {Wmsg[0], wzg[0], DDIM, DDIM};                           // rows 0-127 of wzg0
    descs.d[4] = {Wg1[0], wzg[0] + DDIM * DDIM, DDIM, GATE_H_};           // rows 128-255 of wzg0
    descs.d[5] = {Wmsg[1], wzg[1], DDIM, DDIM};
    descs.d[6] = {Wg1[1], wzg[1] + DDIM * DDIM, DDIM, GATE_H_};
    descs.d[7] = {Wg1[0] + DDIM * GATE_H_, wgmt[0], DDIM, GATE_H_};
    descs.d[8] = {Wg1[1] + DDIM * GATE_H_, wgmt[1], DDIM, GATE_H_};
    descs.d[9] = {Wh1, wh1t, DDIM, DDIM};
    prep_kernel<<<BINA_NB + NB_TRANS + NB_CAST, blk, 0, stream>>>(
        X, Xb, descs, rows, cols, bcnt, staging);

    // ---- gemm1 ++ binB2 (independent, one launch; staging does not alias H0b) ----
    gemm1_binb_kernel<<<2 * gM32 + NCOARSE, blk, 0, stream>>>(
        Xb, w0t, b_in0, H0b, N_NODES, H_IN_, IN_DIM_,
        staging, bcnt, offs, ends, edst);

    gemm_async_kernel<<<dim3(2, gM32), blk, 0, stream>>>(H0b, w1t, b_in1, nullptr, H1b, N_NODES, H_IN_, H_IN_, 1);
    gemm_async_kernel<<<dim3(1, gM32), blk, 0, stream>>>(H1b, w2t, b_in2, H, Hb, N_NODES, DDIM, H_IN_, 1);

    for (int b = 0; b < 2; b++) {
        zg_gemm_kernel<<<dim3(2, gM32), blk, 0, stream>>>(Hb, wzg[b], bg1[b], Zb, GH, N_NODES);
        gather_kernel<<<CSR_TOTAL / 2, blk, 0, stream>>>(offs, ends, edst, Zb, Mb);
        float* alph = alpha_out + (size_t)b * N_NODES * KADJ;
        gate_fuse_kernel<<<CSR_TOTAL / 32, blk, 0, stream>>>(
            Mb, wgmt[b], GH, logdeg, Wg1[b] + 256 * GATE_H_, Wg2[b], bg2[b],
            mask, H, Ybuf, alph, red + b * 8 * 132);
        pairnorm_kernel<<<(N_NODES + 1) / 2, blk, 0, stream>>>(Ybuf, red + b * 8 * 132, H, Hb, N_NODES);
    }

    // head (+ fused logits)
    head_gemm_kernel<<<gM32, blk, 0, stream>>>(Hb, wh1t, bh1, Wh2, bh2, logits, N_NODES);
}

// Round 8
// 419.622 us; speedup vs baseline: 1.1198x; 1.1042x over previous
//
#include <hip/hip_runtime.h>
#include <hip/hip_bf16.h>

#define N_NODES 20000
#define KADJ 4
#define NEDGE 320000
#define ETOTAL (KADJ * NEDGE)               // 1,280,000
#define IN_DIM_ 1024
#define H_IN_ 256
#define DDIM 128
#define GATE_H_ 128
#define TEMP_ 0.6f
#define M_CLAMP_ 20.0f
#define CSR_TOTAL (KADJ * N_NODES)          // 80000
#define NCOARSE 128
#define QPER (CSR_TOTAL / NCOARSE)          // 625
#define ESTRIDE 12288                       // bucket slot stride (exp fill 10000, sigma~100)
#define TILE_A 4096
#define BINA_NB ((ETOTAL + TILE_A - 1) / TILE_A)  // 313
#define NB_CAST (N_NODES * IN_DIM_ / 8 / 256)     // 10000
#define NB_TRANS 2560                              // 8 x 32 x 10

typedef __attribute__((ext_vector_type(8))) short frag_ab;      // 8 bf16
typedef __attribute__((ext_vector_type(4))) float frag_cd;      // 4 fp32
typedef __attribute__((ext_vector_type(8))) unsigned short us8;

__device__ inline unsigned short f2bf(float f) {
    unsigned int u = __float_as_uint(f);
    u += 0x7FFFu + ((u >> 16) & 1);   // RNE
    return (unsigned short)(u >> 16);
}
__device__ inline float bflo(unsigned int p) { return __uint_as_float(p << 16); }
__device__ inline float bfhi(unsigned int p) { return __uint_as_float(p & 0xffff0000u); }

// async 16B global->LDS (wave-uniform LDS base + lane*16)
__device__ __forceinline__ void gld16(const unsigned short* g, unsigned short* l) {
    __builtin_amdgcn_global_load_lds(
        (const __attribute__((address_space(1))) void*)g,
        (__attribute__((address_space(3))) void*)l, 16, 0, 0);
}

// ---- pipelined K-loop building blocks: per wave per stage exactly 5 gld16 ----
#define PIPE_WAIT_NEXT()  asm volatile("s_waitcnt vmcnt(5)" ::: "memory")
#define PIPE_WAIT_LAST()  asm volatile("s_waitcnt vmcnt(0)" ::: "memory")
#define PIPE_BAR()        __builtin_amdgcn_s_barrier()
#define PIPE_FENCE()      __builtin_amdgcn_sched_barrier(0)

struct TD { const float* src; unsigned short* dst; int K; int N; };
struct TD10 { TD d[10]; };

// ============== prep mega-kernel: binA2 FIRST (latency-bound) ++ transposes ++ X cast =======
__global__ __launch_bounds__(256) void prep_kernel(
    const float* __restrict__ X, unsigned short* __restrict__ Xb,
    TD10 descs,
    const int* __restrict__ rows, const int* __restrict__ cols,
    int* __restrict__ bcnt, uint2* __restrict__ staging)
{
    __shared__ __align__(16) char sraw[2048 + TILE_A * 8];   // 34 KB
    int bid = blockIdx.x;
    int tid = threadIdx.x;

    if (bid >= BINA_NB + NB_TRANS) {
        // ---- X fp32 -> bf16 streaming cast (scheduled last; BW-bound) ----
        int i = ((bid - BINA_NB - NB_TRANS) * 256 + tid) * 8;
        float4 a = *(const float4*)(X + i), b = *(const float4*)(X + i + 4);
        us8 o;
        o[0] = f2bf(a.x); o[1] = f2bf(a.y); o[2] = f2bf(a.z); o[3] = f2bf(a.w);
        o[4] = f2bf(b.x); o[5] = f2bf(b.y); o[6] = f2bf(b.z); o[7] = f2bf(b.w);
        *(us8*)(Xb + i) = o;
        return;
    }
    if (bid >= BINA_NB) {
        // ---- weight transpose ----
        int b2 = bid - BINA_NB;
        TD t = descs.d[b2 >> 8];
        int rem = b2 & 255;
        int n0 = (rem & 7) * 32, k0 = (rem >> 3) * 32;
        if (n0 >= t.N || k0 >= t.K) return;
        float (*tile)[33] = (float(*)[33])sraw;
        int tx = tid & 31, ty4 = (tid >> 5) * 4;
#pragma unroll
        for (int i = 0; i < 4; i++)
            tile[ty4 + i][tx] = t.src[(size_t)(k0 + ty4 + i) * t.N + n0 + tx];
        __syncthreads();
#pragma unroll
        for (int i = 0; i < 4; i++)
            t.dst[(size_t)(n0 + ty4 + i) * t.K + k0 + tx] = f2bf(tile[tx][ty4 + i]);
        return;
    }
    // ---- binA2: CSR coarse binning (dispatched FIRST, overlaps with cast) ----
    int* hist  = (int*)sraw;
    int* hscan = hist + NCOARSE;
    int* lcur  = hscan + NCOARSE;
    int* gbase = lcur + NCOARSE;
    uint2* pairs = (uint2*)(sraw + 2048);

    int base = bid * TILE_A;
    int cnt_t = min(TILE_A, ETOTAL - base);

    for (int i = tid; i < NCOARSE; i += 256) hist[i] = 0;
    __syncthreads();

    unsigned int q[16], c[16];
    bool valid[16];
#pragma unroll
    for (int i = 0; i < 16; i++) {
        int loc = i * 256 + tid;
        valid[i] = loc < cnt_t;
        if (valid[i]) {
            int e = base + loc;
            int k = e / NEDGE;
            unsigned int qq = (unsigned int)(k * N_NODES + rows[e]);
            q[i] = qq;
            c[i] = (unsigned int)cols[e];
            atomicAdd(&hist[qq / QPER], 1);
        }
    }
    __syncthreads();
    if (tid < NCOARSE) hscan[tid] = hist[tid];
    __syncthreads();
    for (int d = 1; d < NCOARSE; d <<= 1) {
        int v = (tid >= d && tid < NCOARSE) ? hscan[tid - d] : 0;
        __syncthreads();
        if (tid < NCOARSE) hscan[tid] += v;
        __syncthreads();
    }
    if (tid < NCOARSE) {
        int ex = hscan[tid] - hist[tid];
        hscan[tid] = ex;
        lcur[tid] = ex;
        gbase[tid] = hist[tid] ? (tid * ESTRIDE + atomicAdd(&bcnt[tid], hist[tid])) : 0;
    }
    __syncthreads();
#pragma unroll
    for (int i = 0; i < 16; i++) {
        if (valid[i]) {
            int b = q[i] / QPER;
            int p = atomicAdd(&lcur[b], 1);
            pairs[p] = make_uint2(q[i], c[i]);
        }
    }
    __syncthreads();
    for (int i = tid; i < cnt_t; i += 256) {
        uint2 pr = pairs[i];
        int b = pr.x / QPER;
        staging[gbase[b] + (i - hscan[b])] = pr;
    }
}

// ============== gemm1 ++ binB2 in one launch (independent; staging must NOT alias H0b!) ======
__global__ __launch_bounds__(256) void gemm1_binb_kernel(
    const unsigned short* __restrict__ A, const unsigned short* __restrict__ Bt,
    const float* __restrict__ bias, unsigned short* __restrict__ Cb,
    int M, int N, int K,
    const uint2* __restrict__ staging, const int* __restrict__ bcnt,
    int* __restrict__ offs, int* __restrict__ ends, int* __restrict__ edst)
{
    __shared__ __align__(16) char smem[40960];
    int tid = threadIdx.x;
    int bid = blockIdx.x;
    const int GEMM_NB = 2 * 625;

    if (bid < GEMM_NB) {
        unsigned short* sA0 = (unsigned short*)smem;           // 2 x 2048 shorts
        unsigned short* sB0 = (unsigned short*)(smem + 8192);  // 2 x 8192 shorts
        int tileM = (bid >> 1) * 32, tileN = (bid & 1) * 128;
        int w = tid >> 6, lane = tid & 63;
        int wr = (w & 1) * 16, wc = (w >> 1) * 64;
        int fm = lane & 15, fq = lane >> 4;
        int crow = lane >> 3;
        int gsw = (lane & 7) ^ crow;

        frag_cd acc[4] = {};

        auto stage = [&](int buf, int k0) {
            {
                int row = w * 8 + crow;
                int ar = min(tileM + row, M - 1);
                gld16(A + (size_t)ar * K + k0 + gsw * 8, sA0 + buf * 2048 + w * 512);
            }
#pragma unroll
            for (int t = 0; t < 4; t++) {
                int chunk = w * 4 + t;
                int row = chunk * 8 + crow;
                gld16(Bt + (size_t)(tileN + row) * K + k0 + gsw * 8, sB0 + buf * 8192 + chunk * 512);
            }
        };

        int nt = K >> 6;
        stage(0, 0);
        for (int t = 0; t < nt; t++) {
            int cur = t & 1;
            if (t + 1 < nt) { stage(cur ^ 1, (t + 1) << 6); PIPE_WAIT_NEXT(); }
            else            { PIPE_WAIT_LAST(); }
            PIPE_BAR();
            PIPE_FENCE();
#pragma unroll
            for (int s = 0; s < 2; s++) {
                int sw = ((s * 4 + fq) ^ (fm & 7)) * 8;
                frag_ab af = *(const frag_ab*)(sA0 + cur * 2048 + (wr + fm) * 64 + sw);
#pragma unroll
                for (int j = 0; j < 4; j++) {
                    frag_ab bf = *(const frag_ab*)(sB0 + cur * 8192 + (wc + j * 16 + fm) * 64 + sw);
                    acc[j] = __builtin_amdgcn_mfma_f32_16x16x32_bf16(af, bf, acc[j], 0, 0, 0);
                }
            }
            PIPE_FENCE();
            PIPE_BAR();
        }
        int row = tileM + wr + fq * 4;
#pragma unroll
        for (int r = 0; r < 4; r++) {
            if (row + r < M) {
#pragma unroll
                for (int j = 0; j < 4; j++) {
                    int col = tileN + wc + j * 16 + fm;
                    float v = fmaxf(acc[j][r] + bias[col], 0.f);
                    Cb[(size_t)(row + r) * N + col] = f2bf(v);
                }
            }
        }
        return;
    }
    // ---- binB2 ----
    int* cntS = (int*)smem;
    int* sofs = cntS + QPER;
    int* lcur = sofs + QPER;
    int* psum = lcur + QPER;
    int b = bid - GEMM_NB;
    int q0 = b * QPER, base = b * ESTRIDE;
    int fill = bcnt[b];
    for (int i = tid; i < QPER; i += 256) cntS[i] = 0;
    __syncthreads();
    for (int i = tid; i < fill; i += 256)
        atomicAdd(&cntS[staging[base + i].x - q0], 1);
    __syncthreads();
    const int CH = 3;
    int lo = tid * CH, hi = min(lo + CH, QPER);
    int s = 0;
    for (int i = lo; i < hi; i++) s += cntS[i];
    psum[tid] = s;
    __syncthreads();
    for (int d = 1; d < 256; d <<= 1) {
        int v = (tid >= d) ? psum[tid - d] : 0;
        __syncthreads();
        psum[tid] += v;
        __syncthreads();
    }
    int run = (tid == 0) ? 0 : psum[tid - 1];
    for (int i = lo; i < hi; i++) {
        sofs[i] = run;
        lcur[i] = run;
        run += cntS[i];
    }
    __syncthreads();
    for (int i = tid; i < QPER; i += 256) {
        offs[q0 + i] = base + sofs[i];
        ends[q0 + i] = base + sofs[i] + cntS[i];
    }
    for (int i = tid; i < fill; i += 256) {
        uint2 p = staging[base + i];
        int pos = atomicAdd(&lcur[p.x - q0], 1);
        edst[base + pos] = (int)p.y;
    }
}

// ============== async bf16 MFMA GEMM: C = [relu](A[M,K]_bf16 @ (Bt[N,K]_bf16)^T + bias) =========
__global__ __launch_bounds__(256) void gemm_async_kernel(
    const unsigned short* __restrict__ A, const unsigned short* __restrict__ Bt,
    const float* __restrict__ bias, float* __restrict__ Cf, unsigned short* __restrict__ Cb,
    int M, int N, int K, int do_relu)
{
    __shared__ unsigned short sA[2][32 * 64];
    __shared__ unsigned short sB[2][128 * 64];
    int tid = threadIdx.x;
    int tileM = blockIdx.y * 32, tileN = blockIdx.x * 128;
    int w = tid >> 6, lane = tid & 63;
    int wr = (w & 1) * 16, wc = (w >> 1) * 64;
    int fm = lane & 15, fq = lane >> 4;
    int crow = lane >> 3;
    int gsw = (lane & 7) ^ crow;

    frag_cd acc[4] = {};

    auto stage = [&](int buf, int k0) {
        {
            int row = w * 8 + crow;
            int ar = min(tileM + row, M - 1);
            gld16(A + (size_t)ar * K + k0 + gsw * 8, &sA[buf][w * 512]);
        }
#pragma unroll
        for (int t = 0; t < 4; t++) {
            int chunk = w * 4 + t;
            int row = chunk * 8 + crow;
            gld16(Bt + (size_t)(tileN + row) * K + k0 + gsw * 8, &sB[buf][chunk * 512]);
        }
    };

    int nt = K >> 6;
    stage(0, 0);
    for (int t = 0; t < nt; t++) {
        int cur = t & 1;
        if (t + 1 < nt) { stage(cur ^ 1, (t + 1) << 6); PIPE_WAIT_NEXT(); }
        else            { PIPE_WAIT_LAST(); }
        PIPE_BAR();
        PIPE_FENCE();
#pragma unroll
        for (int s = 0; s < 2; s++) {
            int sw = ((s * 4 + fq) ^ (fm & 7)) * 8;
            frag_ab af = *(const frag_ab*)&sA[cur][(wr + fm) * 64 + sw];
#pragma unroll
            for (int j = 0; j < 4; j++) {
                frag_ab bf = *(const frag_ab*)&sB[cur][(wc + j * 16 + fm) * 64 + sw];
                acc[j] = __builtin_amdgcn_mfma_f32_16x16x32_bf16(af, bf, acc[j], 0, 0, 0);
            }
        }
        PIPE_FENCE();
        PIPE_BAR();
    }
    int row = tileM + wr + fq * 4;
#pragma unroll
    for (int r = 0; r < 4; r++) {
        if (row + r < M) {
#pragma unroll
            for (int j = 0; j < 4; j++) {
                int col = tileN + wc + j * 16 + fm;
                float v = acc[j][r];
                if (bias) v += bias[col];
                if (do_relu) v = fmaxf(v, 0.f);
                if (Cf) Cf[(size_t)(row + r) * N + col] = v;
                if (Cb) Cb[(size_t)(row + r) * N + col] = f2bf(v);
            }
        }
    }
}

// ============== fused Z+GH GEMM: A=Hb[M,128], Bt=wzg[256][128] ==============
__global__ __launch_bounds__(256) void zg_gemm_kernel(
    const unsigned short* __restrict__ A, const unsigned short* __restrict__ Bt,
    const float* __restrict__ bg1, unsigned short* __restrict__ Zb,
    float* __restrict__ GH, int M)
{
    __shared__ unsigned short sA[2][32 * 64];
    __shared__ unsigned short sB[2][128 * 64];
    int tid = threadIdx.x;
    int tileM = blockIdx.y * 32, tileN = blockIdx.x * 128;
    int w = tid >> 6, lane = tid & 63;
    int wr = (w & 1) * 16, wc = (w >> 1) * 64;
    int fm = lane & 15, fq = lane >> 4;
    int crow = lane >> 3;
    int gsw = (lane & 7) ^ crow;

    frag_cd acc[4] = {};

    auto stage = [&](int buf, int k0) {
        {
            int row = w * 8 + crow;
            int ar = min(tileM + row, M - 1);
            gld16(A + (size_t)ar * DDIM + k0 + gsw * 8, &sA[buf][w * 512]);
        }
#pragma unroll
        for (int t = 0; t < 4; t++) {
            int chunk = w * 4 + t;
            int row = chunk * 8 + crow;
            gld16(Bt + (size_t)(tileN + row) * DDIM + k0 + gsw * 8, &sB[buf][chunk * 512]);
        }
    };

    stage(0, 0);
#pragma unroll
    for (int t = 0; t < 2; t++) {
        int cur = t & 1;
        if (t == 0) { stage(1, 64); PIPE_WAIT_NEXT(); }
        else        { PIPE_WAIT_LAST(); }
        PIPE_BAR();
        PIPE_FENCE();
#pragma unroll
        for (int s = 0; s < 2; s++) {
            int sw = ((s * 4 + fq) ^ (fm & 7)) * 8;
            frag_ab af = *(const frag_ab*)&sA[cur][(wr + fm) * 64 + sw];
#pragma unroll
            for (int j = 0; j < 4; j++) {
                frag_ab bf = *(const frag_ab*)&sB[cur][(wc + j * 16 + fm) * 64 + sw];
                acc[j] = __builtin_amdgcn_mfma_f32_16x16x32_bf16(af, bf, acc[j], 0, 0, 0);
            }
        }
        PIPE_FENCE();
        PIPE_BAR();
    }
    int isZ = (blockIdx.x == 0);
    int row = tileM + wr + fq * 4;
#pragma unroll
    for (int r = 0; r < 4; r++) {
        if (row + r < M) {
#pragma unroll
            for (int j = 0; j < 4; j++) {
                int col = wc + j * 16 + fm;    // local 0..127
                float v = acc[j][r];
                if (isZ) Zb[(size_t)(row + r) * DDIM + col] = f2bf(v);
                else     GH[(size_t)(row + r) * GATE_H_ + col] = v + bg1[col];
            }
        }
    }
}

// ============== head GEMM + logits epilogue: logits = relu(Hb@Wh1+bh1) . Wh2 + bh2 ========
__global__ __launch_bounds__(256) void head_gemm_kernel(
    const unsigned short* __restrict__ A, const unsigned short* __restrict__ Bt,
    const float* __restrict__ bh1, const float* __restrict__ Wh2,
    const float* __restrict__ bh2, float* __restrict__ logits, int M)
{
    __shared__ unsigned short sA[2][32 * 64];
    __shared__ unsigned short sB[2][128 * 64];
    __shared__ float sred[2][32];
    int tid = threadIdx.x;
    int tileM = blockIdx.x * 32;
    int w = tid >> 6, lane = tid & 63;
    int wr = (w & 1) * 16, wc = (w >> 1) * 64;
    int fm = lane & 15, fq = lane >> 4;
    int crow = lane >> 3;
    int gsw = (lane & 7) ^ crow;

    frag_cd acc[4] = {};

    auto stage = [&](int buf, int k0) {
        {
            int row = w * 8 + crow;
            int ar = min(tileM + row, M - 1);
            gld16(A + (size_t)ar * DDIM + k0 + gsw * 8, &sA[buf][w * 512]);
        }
#pragma unroll
        for (int t = 0; t < 4; t++) {
            int chunk = w * 4 + t;
            int row = chunk * 8 + crow;
            gld16(Bt + (size_t)row * DDIM + k0 + gsw * 8, &sB[buf][chunk * 512]);
        }
    };

    stage(0, 0);
#pragma unroll
    for (int t = 0; t < 2; t++) {
        int cur = t & 1;
        if (t == 0) { stage(1, 64); PIPE_WAIT_NEXT(); }
        else        { PIPE_WAIT_LAST(); }
        PIPE_BAR();
        PIPE_FENCE();
#pragma unroll
        for (int s = 0; s < 2; s++) {
            int sw = ((s * 4 + fq) ^ (fm & 7)) * 8;
            frag_ab af = *(const frag_ab*)&sA[cur][(wr + fm) * 64 + sw];
#pragma unroll
            for (int j = 0; j < 4; j++) {
                frag_ab bf = *(const frag_ab*)&sB[cur][(wc + j * 16 + fm) * 64 + sw];
                acc[j] = __builtin_amdgcn_mfma_f32_16x16x32_bf16(af, bf, acc[j], 0, 0, 0);
            }
        }
        PIPE_FENCE();
        PIPE_BAR();
    }
    float wv[4], bh[4];
#pragma unroll
    for (int j = 0; j < 4; j++) {
        int c = wc + j * 16 + fm;
        wv[j] = Wh2[c];
        bh[j] = bh1[c];
    }
    float part[4];
#pragma unroll
    for (int r = 0; r < 4; r++) {
        float p = 0.f;
#pragma unroll
        for (int j = 0; j < 4; j++) {
            float v = fmaxf(acc[j][r] + bh[j], 0.f);
            p += v * wv[j];
        }
        part[r] = p;
    }
#pragma unroll
    for (int m = 1; m < 16; m <<= 1)
#pragma unroll
        for (int r = 0; r < 4; r++)
            part[r] += __shfl_xor(part[r], m, 64);
    if (fm == 0) {
#pragma unroll
        for (int r = 0; r < 4; r++)
            sred[w >> 1][wr + fq * 4 + r] = part[r];
    }
    __syncthreads();
    if (tid < 32 && tileM + tid < M)
        logits[tileM + tid] = sred[0][tid] + sred[1][tid] + bh2[0];
}

// ---------------- gather: Mb[r*4+k, half*64+:64] = bf16(clip(sum Zb[col_e, half-slice])) ----
// 8-lane groups own one q-half end-to-end (NO cross-lane reduce); 8 groups/wave, 4 waves/block
// -> 32 q-halves per block. d-half XCD routing preserved: bid = 8j+m, half = m>>2,
// qblk = j*4+(m&3); round-robin block->XCD puts half 0 on XCDs 0-3, half 1 on XCDs 4-7 ->
// each XCD's Zb working set = 2.56 MB, fits 4 MiB L2 (perf heuristic only, not correctness).
// 2 edges in flight per group = 16 loads/wave. Divergent trip counts across groups accepted.
__global__ __launch_bounds__(256) void gather_kernel(
    const int* __restrict__ offs, const int* __restrict__ ends,
    const int* __restrict__ edst,
    const unsigned short* __restrict__ Zb, unsigned short* __restrict__ Mb)
{
    int bid = blockIdx.x;                    // 5000
    int half = (bid >> 2) & 1;
    int qblk = (bid >> 3) * 4 + (bid & 3);   // 0..2499
    int w = threadIdx.x >> 6;
    int lane = threadIdx.x & 63;
    int g = lane >> 3;                       // group 0..7 owns one q
    int l = lane & 7;                        // 8 lanes x 16B = 128B half-row
    int q = qblk * 32 + w * 8 + g;           // CSR index q = k*N + r
    int k = q / N_NODES;
    int r = q - k * N_NODES;
    int start = offs[q];
    int end = ends[q];
    const unsigned short* Zh = Zb + half * 64 + l * 8;

    float a0 = 0.f, a1 = 0.f, a2 = 0.f, a3 = 0.f;
    float a4 = 0.f, a5 = 0.f, a6 = 0.f, a7 = 0.f;

#define ACC8(P) {                                  \
        a0 += bflo(P.x); a1 += bfhi(P.x);          \
        a2 += bflo(P.y); a3 += bfhi(P.y);          \
        a4 += bflo(P.z); a5 += bfhi(P.z);          \
        a6 += bflo(P.w); a7 += bfhi(P.w); }

    int i = start;
    for (; i + 2 <= end; i += 2) {
        int c0 = edst[i], c1 = edst[i + 1];
        uint4 p0 = *(const uint4*)(Zh + (size_t)c0 * DDIM);
        uint4 p1 = *(const uint4*)(Zh + (size_t)c1 * DDIM);
        ACC8(p0); ACC8(p1);
    }
    if (i < end) {
        uint4 p0 = *(const uint4*)(Zh + (size_t)edst[i] * DDIM);
        ACC8(p0);
    }
#undef ACC8

#define CLIP(v) fminf(fmaxf(v, -M_CLAMP_), M_CLAMP_)
    unsigned int w0 = (unsigned int)f2bf(CLIP(a0)) | ((unsigned int)f2bf(CLIP(a1)) << 16);
    unsigned int w1 = (unsigned int)f2bf(CLIP(a2)) | ((unsigned int)f2bf(CLIP(a3)) << 16);
    unsigned int w2 = (unsigned int)f2bf(CLIP(a4)) | ((unsigned int)f2bf(CLIP(a5)) << 16);
    unsigned int w3 = (unsigned int)f2bf(CLIP(a6)) | ((unsigned int)f2bf(CLIP(a7)) << 16);
#undef CLIP
    uint4 o = make_uint4(w0, w1, w2, w3);
    *(uint4*)(Mb + ((size_t)r * KADJ + k) * DDIM + half * 64 + l * 8) = o;
}

// ============== gate GEMM + FUSED alpha/Y/pairnorm-partial epilogue (Mb from global) =========
__global__ __launch_bounds__(256) void gate_fuse_kernel(
    const unsigned short* __restrict__ Mb, const unsigned short* __restrict__ Bt,
    const float* __restrict__ GH, const float* __restrict__ logdeg,
    const float* __restrict__ wld, const float* __restrict__ Wg2,
    const float* __restrict__ bg2, const float* __restrict__ mask,
    const float* __restrict__ H, float* __restrict__ Y,
    float* __restrict__ alpha_out, float* __restrict__ red)
{
    __shared__ unsigned short sA[2][32 * 64];
    __shared__ unsigned short sB[2][128 * 64];
    __shared__ float sred[2][32];
    __shared__ float sc_al[64];          // [0:32) scores, [32:64) alpha
    __shared__ float sx[256], sy[256], sqs[256];
    int tid = threadIdx.x;
    int tile0 = blockIdx.x * 32;
    int node0 = blockIdx.x * 8;
    int w = tid >> 6, lane = tid & 63;
    int wr = (w & 1) * 16, wc = (w >> 1) * 64;
    int fm = lane & 15, fq = lane >> 4;
    int crow = lane >> 3;
    int gsw = (lane & 7) ^ crow;

    frag_cd acc[4] = {};

    auto stage = [&](int buf, int k0) {
        {
            int row = w * 8 + crow;
            gld16(Mb + (size_t)(tile0 + row) * DDIM + k0 + gsw * 8, &sA[buf][w * 512]);
        }
#pragma unroll
        for (int t = 0; t < 4; t++) {
            int chunk = w * 4 + t;
            int row = chunk * 8 + crow;
            gld16(Bt + (size_t)row * DDIM + k0 + gsw * 8, &sB[buf][chunk * 512]);
        }
    };

    stage(0, 0);
#pragma unroll
    for (int t = 0; t < 2; t++) {
        int cur = t & 1;
        if (t == 0) { stage(1, 64); PIPE_WAIT_NEXT(); }
        else        { PIPE_WAIT_LAST(); }
        PIPE_BAR();
        PIPE_FENCE();
#pragma unroll
        for (int s = 0; s < 2; s++) {
            int sw = ((s * 4 + fq) ^ (fm & 7)) * 8;
            frag_ab af = *(const frag_ab*)&sA[cur][(wr + fm) * 64 + sw];
#pragma unroll
            for (int j = 0; j < 4; j++) {
                frag_ab bf = *(const frag_ab*)&sB[cur][(wc + j * 16 + fm) * 64 + sw];
                acc[j] = __builtin_amdgcn_mfma_f32_16x16x32_bf16(af, bf, acc[j], 0, 0, 0);
            }
        }
        PIPE_FENCE();
        PIPE_BAR();
    }
    float wg2v[4], wldv[4];
#pragma unroll
    for (int j = 0; j < 4; j++) {
        int c = wc + j * 16 + fm;
        wg2v[j] = Wg2[c];
        wldv[j] = wld[c];
    }
    float part[4];
#pragma unroll
    for (int r = 0; r < 4; r++) {
        int q = tile0 + wr + fq * 4 + r;
        int n = q >> 2;
        float ld = logdeg[q];
        float p = 0.f;
#pragma unroll
        for (int j = 0; j < 4; j++) {
            int c = wc + j * 16 + fm;
            float v = acc[j][r] + GH[(size_t)n * GATE_H_ + c] + ld * wldv[j];
            p += fmaxf(v, 0.f) * wg2v[j];
        }
        part[r] = p;
    }
#pragma unroll
    for (int m = 1; m < 16; m <<= 1)
#pragma unroll
        for (int r = 0; r < 4; r++)
            part[r] += __shfl_xor(part[r], m, 64);
    if (fm == 0) {
#pragma unroll
        for (int r = 0; r < 4; r++)
            sred[w >> 1][wr + fq * 4 + r] = part[r];
    }
    __syncthreads();
    if (tid < 32) sc_al[tid] = sred[0][tid] + sred[1][tid] + bg2[0];
    __syncthreads();
    // ---- softmax + mask renorm per node (threads 0..7) ----
    if (tid < 8) {
        int n = node0 + tid;
        float a[KADJ];
        float mx = -1e30f;
#pragma unroll
        for (int k = 0; k < KADJ; k++) {
            a[k] = sc_al[tid * 4 + k] * (1.0f / TEMP_);
            mx = fmaxf(mx, a[k]);
        }
        float sum = 0.f;
#pragma unroll
        for (int k = 0; k < KADJ; k++) { a[k] = expf(a[k] - mx); sum += a[k]; }
#pragma unroll
        for (int k = 0; k < KADJ; k++) a[k] = (a[k] / sum) * mask[(size_t)n * KADJ + k];
        float s2 = 0.f;
#pragma unroll
        for (int k = 0; k < KADJ; k++) s2 += a[k];
        float inv = 1.f / fmaxf(s2, 1e-12f);
#pragma unroll
        for (int k = 0; k < KADJ; k++) a[k] = fmaxf(a[k] * inv, 1e-8f);
        s2 = 0.f;
#pragma unroll
        for (int k = 0; k < KADJ; k++) s2 += a[k];
        inv = 1.f / fmaxf(s2, 1e-12f);
#pragma unroll
        for (int k = 0; k < KADJ; k++) sc_al[32 + tid * 4 + k] = a[k] * inv;
    }
    __syncthreads();
    if (tid < 32) alpha_out[tile0 + tid] = sc_al[32 + tid];
    // ---- Y = H + sum_k a_k M, + pairnorm partials (8 nodes x 64 d-pairs) ----
    float csx = 0.f, csy = 0.f, sq = 0.f;
    int j = tid & 63, dd = j * 2;
#pragma unroll
    for (int it = 0; it < 2; it++) {
        int nl = (tid >> 6) + it * 4;
        int n = node0 + nl;
        const float* alp = &sc_al[32 + nl * 4];
        float2 h = *(const float2*)(H + (size_t)n * DDIM + dd);
        float yx = h.x, yy = h.y;
#pragma unroll
        for (int k = 0; k < KADJ; k++) {
            unsigned int u = *(const unsigned int*)(Mb + ((size_t)n * KADJ + k) * DDIM + dd);
            yx += alp[k] * bflo(u);
            yy += alp[k] * bfhi(u);
        }
        *(float2*)(Y + (size_t)n * DDIM + dd) = make_float2(yx, yy);
        csx += yx; csy += yy;
        sq += yx * yx + yy * yy;
    }
    sx[tid] = csx; sy[tid] = csy; sqs[tid] = sq;
    __syncthreads();
    int st = (blockIdx.x & 7) * 132;
    if (tid < 64) {
        float ax = sx[tid] + sx[tid + 64] + sx[tid + 128] + sx[tid + 192];
        float ay = sy[tid] + sy[tid + 64] + sy[tid + 128] + sy[tid + 192];
        atomicAdd(&red[st + tid * 2], ax);
        atomicAdd(&red[st + tid * 2 + 1], ay);
    }
    for (int s = 128; s > 0; s >>= 1) {
        if (tid < s) sqs[tid] += sqs[tid + s];
        __syncthreads();
    }
    if (tid == 0) atomicAdd(&red[st + 128], sqs[0]);
}

// ---------------- pairnorm apply: sums 8 red stripes, writes H fp32 + Hb bf16 ----------
__global__ __launch_bounds__(256) void pairnorm_kernel(
    const float* __restrict__ Y, const float* __restrict__ red,
    float* __restrict__ Hout, unsigned short* __restrict__ Hb, int N)
{
    int tid = threadIdx.x;
    int d = tid & 127;
    float invN = 1.0f / (float)N;
    float s = 0.f, rq = 0.f;
#pragma unroll
    for (int st = 0; st < 8; st++) {
        s += red[st * 132 + d];
        rq += red[st * 132 + 128];
    }
    float mu = s * invN;
    __shared__ float smu2[128];
    if (tid < 128) smu2[tid] = mu * mu;
    __syncthreads();
    for (int t = 64; t > 0; t >>= 1) {
        if (tid < t) smu2[tid] += smu2[tid + t];
        __syncthreads();
    }
    float summu2 = smu2[0];
    float var = rq * invN - summu2;
    float norm = sqrtf(fmaxf(var, 0.f)) + 1e-6f;
    float inv = 1.0f / norm;
    int n = blockIdx.x * 2 + (tid >> 7);
    if (n < N) {
        float v = (Y[(size_t)n * DDIM + d] - mu) * inv;
        v = fmaxf(v, 0.f);
        Hout[(size_t)n * DDIM + d] = v;
        Hb[(size_t)n * DDIM + d] = f2bf(v);
    }
}

extern "C" void kernel_launch(void* const* d_in, const int* in_sizes, int n_in,
                              void* d_out, int out_size, void* d_ws, size_t ws_size,
                              hipStream_t stream)
{
    const float* X      = (const float*)d_in[0];
    const int*   rows   = (const int*)d_in[1];
    const int*   cols   = (const int*)d_in[2];
    const float* mask   = (const float*)d_in[3];
    const float* logdeg = (const float*)d_in[4];
    const float* W_in0  = (const float*)d_in[5];
    const float* b_in0  = (const float*)d_in[6];
    const float* W_in1  = (const float*)d_in[7];
    const float* b_in1  = (const float*)d_in[8];
    const float* W_in2  = (const float*)d_in[9];
    const float* b_in2  = (const float*)d_in[10];
    const float* Wmsg[2] = {(const float*)d_in[11], (const float*)d_in[16]};
    const float* Wg1[2]  = {(const float*)d_in[12], (const float*)d_in[17]};
    const float* bg1[2]  = {(const float*)d_in[13], (const float*)d_in[18]};
    const float* Wg2[2]  = {(const float*)d_in[14], (const float*)d_in[19]};
    const float* bg2[2]  = {(const float*)d_in[15], (const float*)d_in[20]};
    const float* Wh1 = (const float*)d_in[21];
    const float* bh1 = (const float*)d_in[22];
    const float* Wh2 = (const float*)d_in[23];
    const float* bh2 = (const float*)d_in[24];

    // workspace layout (float slots), ~85 MB.
    // LIFETIME MAP (race-audited):
    //   Xb      0        - 10240000   written prep, read gemm1. Dead after gemm1.
    //   Mb      0        -  5120000   written gather (block loop), read gate_fuse. (Xb dead)
    //   H0b     10240000 - 12800000   written gemm1, read gemm2
    //   H1b/Zb  12800000 - 15360000   gemm2->gemm3; zg->gather
    //   staging 15360000 - 18505728   written prep(binA2), read binB2 (inside gemm1 launch).
    //                                 (MUST NOT alias H0b: binB2 runs concurrently with gemm1!)
    //   H       15360000 - 17920000   written gemm3 (after staging dead)
    //   Hb      17920000 - 19200000   written gemm3
    float* ws = (float*)d_ws;
    unsigned short* Xb  = (unsigned short*)ws;
    unsigned short* Mb  = (unsigned short*)ws;
    float* Ybuf  = ws + 5120000;
    float* GH    = ws + 7680000;
    unsigned short* H0b = (unsigned short*)(ws + 10240000);
    unsigned short* H1b = (unsigned short*)(ws + 12800000);
    unsigned short* Zb  = (unsigned short*)(ws + 12800000);
    uint2* staging = (uint2*)(ws + 15360000);       // NCOARSE*ESTRIDE*2 = 3,145,728 slots
    float* H     = ws + 15360000;                   // 2.56M (after staging dead)
    unsigned short* Hb = (unsigned short*)(ws + 17920000);  // 1.28M slots
    int*   bcnt  = (int*)(ws + 19200000);           // 128
    float* red   = ws + 19200128;                   // 2 blocks x 8 stripes x 132
    int*   offs   = (int*)(ws + 19280000);          // 80000
    int*   ends   = (int*)(ws + 19360000);          // 80000
    int*   edst   = (int*)(ws + 19440000);          // NCOARSE*ESTRIDE = 1,572,864
    unsigned short* w0t  = (unsigned short*)(ws + 21013248);  // 131072 slots
    unsigned short* w1t  = (unsigned short*)(ws + 21144320);  // 32768
    unsigned short* w2t  = (unsigned short*)(ws + 21177088);  // 16384
    unsigned short* wzg[2]  = {(unsigned short*)(ws + 21193472), (unsigned short*)(ws + 21209856)};  // 256x128 each
    unsigned short* wgmt[2] = {(unsigned short*)(ws + 21226240), (unsigned short*)(ws + 21234432)};
    unsigned short* wh1t = (unsigned short*)(ws + 21242624);
    float* logits = (float*)d_out;
    float* alpha_out = (float*)d_out + N_NODES;

    dim3 blk(256);
    int gM32 = (N_NODES + 31) / 32;     // 625

    // ---- one memset: bcnt(128 ints) + red(2x8x132 floats) contiguous ----
    (void)hipMemsetAsync(bcnt, 0, (128 + 2 * 8 * 132) * sizeof(float), stream);

    // ---- prep: binA2 (first) + transposes + cast in ONE launch ----
    TD10 descs;
    descs.d[0] = {W_in0, w0t, IN_DIM_, H_IN_};
    descs.d[1] = {W_in1, w1t, H_IN_, H_IN_};
    descs.d[2] = {W_in2, w2t, H_IN_, DDIM};
    descs.d[3] = {Wmsg[0], wzg[0], DDIM, DDIM};                           // rows 0-127 of wzg0
    descs.d[4] = {Wg1[0], wzg[0] + DDIM * DDIM, DDIM, GATE_H_};           // rows 128-255 of wzg0
    descs.d[5] = {Wmsg[1], wzg[1], DDIM, DDIM};
    descs.d[6] = {Wg1[1], wzg[1] + DDIM * DDIM, DDIM, GATE_H_};
    descs.d[7] = {Wg1[0] + DDIM * GATE_H_, wgmt[0], DDIM, GATE_H_};
    descs.d[8] = {Wg1[1] + DDIM * GATE_H_, wgmt[1], DDIM, GATE_H_};
    descs.d[9] = {Wh1, wh1t, DDIM, DDIM};
    prep_kernel<<<BINA_NB + NB_TRANS + NB_CAST, blk, 0, stream>>>(
        X, Xb, descs, rows, cols, bcnt, staging);

    // ---- gemm1 ++ binB2 (independent, one launch; staging does not alias H0b) ----
    gemm1_binb_kernel<<<2 * gM32 + NCOARSE, blk, 0, stream>>>(
        Xb, w0t, b_in0, H0b, N_NODES, H_IN_, IN_DIM_,
        staging, bcnt, offs, ends, edst);

    gemm_async_kernel<<<dim3(2, gM32), blk, 0, stream>>>(H0b, w1t, b_in1, nullptr, H1b, N_NODES, H_IN_, H_IN_, 1);
    gemm_async_kernel<<<dim3(1, gM32), blk, 0, stream>>>(H1b, w2t, b_in2, H, Hb, N_NODES, DDIM, H_IN_, 1);

    for (int b = 0; b < 2; b++) {
        zg_gemm_kernel<<<dim3(2, gM32), blk, 0, stream>>>(Hb, wzg[b], bg1[b], Zb, GH, N_NODES);
        gather_kernel<<<CSR_TOTAL / 16, blk, 0, stream>>>(offs, ends, edst, Zb, Mb);  // 5000 blocks
        float* alph = alpha_out + (size_t)b * N_NODES * KADJ;
        gate_fuse_kernel<<<CSR_TOTAL / 32, blk, 0, stream>>>(
            Mb, wgmt[b], GH, logdeg, Wg1[b] + 256 * GATE_H_, Wg2[b], bg2[b],
            mask, H, Ybuf, alph, red + b * 8 * 132);
        pairnorm_kernel<<<(N_NODES + 1) / 2, blk, 0, stream>>>(Ybuf, red + b * 8 * 132, H, Hb, N_NODES);
    }

    // head (+ fused logits)
    head_gemm_kernel<<<gM32, blk, 0, stream>>>(Hb, wh1t, bh1, Wh2, bh2, logits, N_NODES);
}

// Round 9
// 412.274 us; speedup vs baseline: 1.1398x; 1.0178x over previous
//
#include <hip/hip_runtime.h>
#include <hip/hip_bf16.h>

#define N_NODES 20000
#define KADJ 4
#define NEDGE 320000
#define ETOTAL (KADJ * NEDGE)               // 1,280,000
#define IN_DIM_ 1024
#define H_IN_ 256
#define DDIM 128
#define GATE_H_ 128
#define TEMP_ 0.6f
#define M_CLAMP_ 20.0f
#define CSR_TOTAL (KADJ * N_NODES)          // 80000
#define NCOARSE 128
#define QPER (CSR_TOTAL / NCOARSE)          // 625
#define ESTRIDE 12288                       // bucket slot stride (exp fill 10000, sigma~100)
#define TILE_A 4096
#define BINA_NB ((ETOTAL + TILE_A - 1) / TILE_A)  // 313
#define NB_CAST (N_NODES * IN_DIM_ / 8 / 256)     // 10000
#define NB_TRANS 2560                              // 8 x 32 x 10

typedef __attribute__((ext_vector_type(8))) short frag_ab;      // 8 bf16
typedef __attribute__((ext_vector_type(4))) float frag_cd;      // 4 fp32
typedef __attribute__((ext_vector_type(8))) unsigned short us8;

__device__ inline unsigned short f2bf(float f) {
    unsigned int u = __float_as_uint(f);
    u += 0x7FFFu + ((u >> 16) & 1);   // RNE
    return (unsigned short)(u >> 16);
}
__device__ inline float bflo(unsigned int p) { return __uint_as_float(p << 16); }
__device__ inline float bfhi(unsigned int p) { return __uint_as_float(p & 0xffff0000u); }

// async 16B global->LDS (wave-uniform LDS base + lane*16)
__device__ __forceinline__ void gld16(const unsigned short* g, unsigned short* l) {
    __builtin_amdgcn_global_load_lds(
        (const __attribute__((address_space(1))) void*)g,
        (__attribute__((address_space(3))) void*)l, 16, 0, 0);
}

// ---- pipelined K-loop building blocks ----
#define PIPE_WAIT_N(n)    asm volatile("s_waitcnt vmcnt(" #n ")" ::: "memory")
#define PIPE_WAIT_LAST()  asm volatile("s_waitcnt vmcnt(0)" ::: "memory")
#define PIPE_BAR()        __builtin_amdgcn_s_barrier()
#define PIPE_FENCE()      __builtin_amdgcn_sched_barrier(0)

struct TD { const float* src; unsigned short* dst; int K; int N; };
struct TD10 { TD d[10]; };

// ============== prep mega-kernel: binA2 FIRST (latency-bound) ++ transposes ++ X cast =======
__global__ __launch_bounds__(256) void prep_kernel(
    const float* __restrict__ X, unsigned short* __restrict__ Xb,
    TD10 descs,
    const int* __restrict__ rows, const int* __restrict__ cols,
    int* __restrict__ bcnt, uint2* __restrict__ staging)
{
    __shared__ __align__(16) char sraw[2048 + TILE_A * 8];   // 34 KB
    int bid = blockIdx.x;
    int tid = threadIdx.x;

    if (bid >= BINA_NB + NB_TRANS) {
        // ---- X fp32 -> bf16 streaming cast (scheduled last; BW-bound) ----
        int i = ((bid - BINA_NB - NB_TRANS) * 256 + tid) * 8;
        float4 a = *(const float4*)(X + i), b = *(const float4*)(X + i + 4);
        us8 o;
        o[0] = f2bf(a.x); o[1] = f2bf(a.y); o[2] = f2bf(a.z); o[3] = f2bf(a.w);
        o[4] = f2bf(b.x); o[5] = f2bf(b.y); o[6] = f2bf(b.z); o[7] = f2bf(b.w);
        *(us8*)(Xb + i) = o;
        return;
    }
    if (bid >= BINA_NB) {
        // ---- weight transpose ----
        int b2 = bid - BINA_NB;
        TD t = descs.d[b2 >> 8];
        int rem = b2 & 255;
        int n0 = (rem & 7) * 32, k0 = (rem >> 3) * 32;
        if (n0 >= t.N || k0 >= t.K) return;
        float (*tile)[33] = (float(*)[33])sraw;
        int tx = tid & 31, ty4 = (tid >> 5) * 4;
#pragma unroll
        for (int i = 0; i < 4; i++)
            tile[ty4 + i][tx] = t.src[(size_t)(k0 + ty4 + i) * t.N + n0 + tx];
        __syncthreads();
#pragma unroll
        for (int i = 0; i < 4; i++)
            t.dst[(size_t)(n0 + ty4 + i) * t.K + k0 + tx] = f2bf(tile[tx][ty4 + i]);
        return;
    }
    // ---- binA2: CSR coarse binning (dispatched FIRST, overlaps with cast) ----
    int* hist  = (int*)sraw;
    int* hscan = hist + NCOARSE;
    int* lcur  = hscan + NCOARSE;
    int* gbase = lcur + NCOARSE;
    uint2* pairs = (uint2*)(sraw + 2048);

    int base = bid * TILE_A;
    int cnt_t = min(TILE_A, ETOTAL - base);

    for (int i = tid; i < NCOARSE; i += 256) hist[i] = 0;
    __syncthreads();

    unsigned int q[16], c[16];
    bool valid[16];
#pragma unroll
    for (int i = 0; i < 16; i++) {
        int loc = i * 256 + tid;
        valid[i] = loc < cnt_t;
        if (valid[i]) {
            int e = base + loc;
            int k = e / NEDGE;
            unsigned int qq = (unsigned int)(k * N_NODES + rows[e]);
            q[i] = qq;
            c[i] = (unsigned int)cols[e];
            atomicAdd(&hist[qq / QPER], 1);
        }
    }
    __syncthreads();
    if (tid < NCOARSE) hscan[tid] = hist[tid];
    __syncthreads();
    for (int d = 1; d < NCOARSE; d <<= 1) {
        int v = (tid >= d && tid < NCOARSE) ? hscan[tid - d] : 0;
        __syncthreads();
        if (tid < NCOARSE) hscan[tid] += v;
        __syncthreads();
    }
    if (tid < NCOARSE) {
        int ex = hscan[tid] - hist[tid];
        hscan[tid] = ex;
        lcur[tid] = ex;
        gbase[tid] = hist[tid] ? (tid * ESTRIDE + atomicAdd(&bcnt[tid], hist[tid])) : 0;
    }
    __syncthreads();
#pragma unroll
    for (int i = 0; i < 16; i++) {
        if (valid[i]) {
            int b = q[i] / QPER;
            int p = atomicAdd(&lcur[b], 1);
            pairs[p] = make_uint2(q[i], c[i]);
        }
    }
    __syncthreads();
    for (int i = tid; i < cnt_t; i += 256) {
        uint2 pr = pairs[i];
        int b = pr.x / QPER;
        staging[gbase[b] + (i - hscan[b])] = pr;
    }
}

// ======= BM=64/BN=128 GEMM body (cuts staged bytes 0.6x vs BM=32) ++ binB2 merge =======
// 4 waves: wave w covers rows wr=(w&1)*32..+32 (2 sub-tiles of 16), cols wc=(w>>1)*64..+64.
// Per K-step per wave: 2 A-chunks + 4 B-chunks staged (6 gld16), 16 MFMA, acc[2][4].
__global__ __launch_bounds__(256) void gemm64_binb_kernel(
    const unsigned short* __restrict__ A, const unsigned short* __restrict__ Bt,
    const float* __restrict__ bias, unsigned short* __restrict__ Cb,
    int M, int N, int K, int GEMM_NB,
    const uint2* __restrict__ staging, const int* __restrict__ bcnt,
    int* __restrict__ offs, int* __restrict__ ends, int* __restrict__ edst)
{
    __shared__ __align__(16) char smem[49152];   // 2x8KB sA + 2x16KB sB (or binB2 scratch)
    int tid = threadIdx.x;
    int bid = blockIdx.x;

    if (bid < GEMM_NB) {
        unsigned short* sA0 = (unsigned short*)smem;            // 2 x 4096 shorts
        unsigned short* sB0 = (unsigned short*)(smem + 16384);  // 2 x 8192 shorts
        int nTn = N >> 7;                                       // N-tiles of 128
        int tileM = (bid / nTn) * 64, tileN = (bid % nTn) * 128;
        int w = tid >> 6, lane = tid & 63;
        int wr = (w & 1) * 32, wc = (w >> 1) * 64;
        int fm = lane & 15, fq = lane >> 4;
        int crow = lane >> 3;
        int gsw = (lane & 7) ^ crow;

        frag_cd acc[2][4] = {};

        auto stage = [&](int buf, int k0) {
#pragma unroll
            for (int t = 0; t < 2; t++) {           // A chunks 2w, 2w+1
                int chunk = w * 2 + t;
                int row = chunk * 8 + crow;
                int ar = min(tileM + row, M - 1);   // clamp keeps vmcnt wave-uniform
                gld16(A + (size_t)ar * K + k0 + gsw * 8, sA0 + buf * 4096 + chunk * 512);
            }
#pragma unroll
            for (int t = 0; t < 4; t++) {           // B chunks
                int chunk = w * 4 + t;
                int row = chunk * 8 + crow;
                gld16(Bt + (size_t)(tileN + row) * K + k0 + gsw * 8, sB0 + buf * 8192 + chunk * 512);
            }
        };

        int nt = K >> 6;
        stage(0, 0);
        for (int t = 0; t < nt; t++) {
            int cur = t & 1;
            if (t + 1 < nt) { stage(cur ^ 1, (t + 1) << 6); PIPE_WAIT_N(6); }
            else            { PIPE_WAIT_LAST(); }
            PIPE_BAR();
            PIPE_FENCE();
#pragma unroll
            for (int s = 0; s < 2; s++) {
                int sw = ((s * 4 + fq) ^ (fm & 7)) * 8;
                frag_ab af[2], bf[4];
#pragma unroll
                for (int i = 0; i < 2; i++)
                    af[i] = *(const frag_ab*)(sA0 + cur * 4096 + (wr + i * 16 + fm) * 64 + sw);
#pragma unroll
                for (int j = 0; j < 4; j++)
                    bf[j] = *(const frag_ab*)(sB0 + cur * 8192 + (wc + j * 16 + fm) * 64 + sw);
#pragma unroll
                for (int i = 0; i < 2; i++)
#pragma unroll
                    for (int j = 0; j < 4; j++)
                        acc[i][j] = __builtin_amdgcn_mfma_f32_16x16x32_bf16(af[i], bf[j], acc[i][j], 0, 0, 0);
            }
            PIPE_FENCE();
            PIPE_BAR();
        }
#pragma unroll
        for (int i = 0; i < 2; i++) {
            int row = tileM + wr + i * 16 + fq * 4;
#pragma unroll
            for (int r = 0; r < 4; r++) {
                if (row + r < M) {
#pragma unroll
                    for (int j = 0; j < 4; j++) {
                        int col = tileN + wc + j * 16 + fm;
                        float v = fmaxf(acc[i][j][r] + bias[col], 0.f);
                        Cb[(size_t)(row + r) * N + col] = f2bf(v);
                    }
                }
            }
        }
        return;
    }
    // ---- binB2 (only when staging != null) ----
    int* cntS = (int*)smem;
    int* sofs = cntS + QPER;
    int* lcur = sofs + QPER;
    int* psum = lcur + QPER;
    int b = bid - GEMM_NB;
    int q0 = b * QPER, base = b * ESTRIDE;
    int fill = bcnt[b];
    for (int i = tid; i < QPER; i += 256) cntS[i] = 0;
    __syncthreads();
    for (int i = tid; i < fill; i += 256)
        atomicAdd(&cntS[staging[base + i].x - q0], 1);
    __syncthreads();
    const int CH = 3;
    int lo = tid * CH, hi = min(lo + CH, QPER);
    int s = 0;
    for (int i = lo; i < hi; i++) s += cntS[i];
    psum[tid] = s;
    __syncthreads();
    for (int d = 1; d < 256; d <<= 1) {
        int v = (tid >= d) ? psum[tid - d] : 0;
        __syncthreads();
        psum[tid] += v;
        __syncthreads();
    }
    int run = (tid == 0) ? 0 : psum[tid - 1];
    for (int i = lo; i < hi; i++) {
        sofs[i] = run;
        lcur[i] = run;
        run += cntS[i];
    }
    __syncthreads();
    for (int i = tid; i < QPER; i += 256) {
        offs[q0 + i] = base + sofs[i];
        ends[q0 + i] = base + sofs[i] + cntS[i];
    }
    for (int i = tid; i < fill; i += 256) {
        uint2 p = staging[base + i];
        int pos = atomicAdd(&lcur[p.x - q0], 1);
        edst[base + pos] = (int)p.y;
    }
}

// ============== async bf16 MFMA GEMM (BM=32): C = [relu](A@Bt^T + bias) =========
__global__ __launch_bounds__(256) void gemm_async_kernel(
    const unsigned short* __restrict__ A, const unsigned short* __restrict__ Bt,
    const float* __restrict__ bias, float* __restrict__ Cf, unsigned short* __restrict__ Cb,
    int M, int N, int K, int do_relu)
{
    __shared__ unsigned short sA[2][32 * 64];
    __shared__ unsigned short sB[2][128 * 64];
    int tid = threadIdx.x;
    int tileM = blockIdx.y * 32, tileN = blockIdx.x * 128;
    int w = tid >> 6, lane = tid & 63;
    int wr = (w & 1) * 16, wc = (w >> 1) * 64;
    int fm = lane & 15, fq = lane >> 4;
    int crow = lane >> 3;
    int gsw = (lane & 7) ^ crow;

    frag_cd acc[4] = {};

    auto stage = [&](int buf, int k0) {
        {
            int row = w * 8 + crow;
            int ar = min(tileM + row, M - 1);
            gld16(A + (size_t)ar * K + k0 + gsw * 8, &sA[buf][w * 512]);
        }
#pragma unroll
        for (int t = 0; t < 4; t++) {
            int chunk = w * 4 + t;
            int row = chunk * 8 + crow;
            gld16(Bt + (size_t)(tileN + row) * K + k0 + gsw * 8, &sB[buf][chunk * 512]);
        }
    };

    int nt = K >> 6;
    stage(0, 0);
    for (int t = 0; t < nt; t++) {
        int cur = t & 1;
        if (t + 1 < nt) { stage(cur ^ 1, (t + 1) << 6); PIPE_WAIT_N(5); }
        else            { PIPE_WAIT_LAST(); }
        PIPE_BAR();
        PIPE_FENCE();
#pragma unroll
        for (int s = 0; s < 2; s++) {
            int sw = ((s * 4 + fq) ^ (fm & 7)) * 8;
            frag_ab af = *(const frag_ab*)&sA[cur][(wr + fm) * 64 + sw];
#pragma unroll
            for (int j = 0; j < 4; j++) {
                frag_ab bf = *(const frag_ab*)&sB[cur][(wc + j * 16 + fm) * 64 + sw];
                acc[j] = __builtin_amdgcn_mfma_f32_16x16x32_bf16(af, bf, acc[j], 0, 0, 0);
            }
        }
        PIPE_FENCE();
        PIPE_BAR();
    }
    int row = tileM + wr + fq * 4;
#pragma unroll
    for (int r = 0; r < 4; r++) {
        if (row + r < M) {
#pragma unroll
            for (int j = 0; j < 4; j++) {
                int col = tileN + wc + j * 16 + fm;
                float v = acc[j][r];
                if (bias) v += bias[col];
                if (do_relu) v = fmaxf(v, 0.f);
                if (Cf) Cf[(size_t)(row + r) * N + col] = v;
                if (Cb) Cb[(size_t)(row + r) * N + col] = f2bf(v);
            }
        }
    }
}

// ============== fused Z+GH GEMM: A=Hb[M,128], Bt=wzg[256][128] ==============
__global__ __launch_bounds__(256) void zg_gemm_kernel(
    const unsigned short* __restrict__ A, const unsigned short* __restrict__ Bt,
    const float* __restrict__ bg1, unsigned short* __restrict__ Zb,
    float* __restrict__ GH, int M)
{
    __shared__ unsigned short sA[2][32 * 64];
    __shared__ unsigned short sB[2][128 * 64];
    int tid = threadIdx.x;
    int tileM = blockIdx.y * 32, tileN = blockIdx.x * 128;
    int w = tid >> 6, lane = tid & 63;
    int wr = (w & 1) * 16, wc = (w >> 1) * 64;
    int fm = lane & 15, fq = lane >> 4;
    int crow = lane >> 3;
    int gsw = (lane & 7) ^ crow;

    frag_cd acc[4] = {};

    auto stage = [&](int buf, int k0) {
        {
            int row = w * 8 + crow;
            int ar = min(tileM + row, M - 1);
            gld16(A + (size_t)ar * DDIM + k0 + gsw * 8, &sA[buf][w * 512]);
        }
#pragma unroll
        for (int t = 0; t < 4; t++) {
            int chunk = w * 4 + t;
            int row = chunk * 8 + crow;
            gld16(Bt + (size_t)(tileN + row) * DDIM + k0 + gsw * 8, &sB[buf][chunk * 512]);
        }
    };

    stage(0, 0);
#pragma unroll
    for (int t = 0; t < 2; t++) {
        int cur = t & 1;
        if (t == 0) { stage(1, 64); PIPE_WAIT_N(5); }
        else        { PIPE_WAIT_LAST(); }
        PIPE_BAR();
        PIPE_FENCE();
#pragma unroll
        for (int s = 0; s < 2; s++) {
            int sw = ((s * 4 + fq) ^ (fm & 7)) * 8;
            frag_ab af = *(const frag_ab*)&sA[cur][(wr + fm) * 64 + sw];
#pragma unroll
            for (int j = 0; j < 4; j++) {
                frag_ab bf = *(const frag_ab*)&sB[cur][(wc + j * 16 + fm) * 64 + sw];
                acc[j] = __builtin_amdgcn_mfma_f32_16x16x32_bf16(af, bf, acc[j], 0, 0, 0);
            }
        }
        PIPE_FENCE();
        PIPE_BAR();
    }
    int isZ = (blockIdx.x == 0);
    int row = tileM + wr + fq * 4;
#pragma unroll
    for (int r = 0; r < 4; r++) {
        if (row + r < M) {
#pragma unroll
            for (int j = 0; j < 4; j++) {
                int col = wc + j * 16 + fm;    // local 0..127
                float v = acc[j][r];
                if (isZ) Zb[(size_t)(row + r) * DDIM + col] = f2bf(v);
                else     GH[(size_t)(row + r) * GATE_H_ + col] = v + bg1[col];
            }
        }
    }
}

// ============== head GEMM + logits epilogue: logits = relu(Hb@Wh1+bh1) . Wh2 + bh2 ========
__global__ __launch_bounds__(256) void head_gemm_kernel(
    const unsigned short* __restrict__ A, const unsigned short* __restrict__ Bt,
    const float* __restrict__ bh1, const float* __restrict__ Wh2,
    const float* __restrict__ bh2, float* __restrict__ logits, int M)
{
    __shared__ unsigned short sA[2][32 * 64];
    __shared__ unsigned short sB[2][128 * 64];
    __shared__ float sred[2][32];
    int tid = threadIdx.x;
    int tileM = blockIdx.x * 32;
    int w = tid >> 6, lane = tid & 63;
    int wr = (w & 1) * 16, wc = (w >> 1) * 64;
    int fm = lane & 15, fq = lane >> 4;
    int crow = lane >> 3;
    int gsw = (lane & 7) ^ crow;

    frag_cd acc[4] = {};

    auto stage = [&](int buf, int k0) {
        {
            int row = w * 8 + crow;
            int ar = min(tileM + row, M - 1);
            gld16(A + (size_t)ar * DDIM + k0 + gsw * 8, &sA[buf][w * 512]);
        }
#pragma unroll
        for (int t = 0; t < 4; t++) {
            int chunk = w * 4 + t;
            int row = chunk * 8 + crow;
            gld16(Bt + (size_t)row * DDIM + k0 + gsw * 8, &sB[buf][chunk * 512]);
        }
    };

    stage(0, 0);
#pragma unroll
    for (int t = 0; t < 2; t++) {
        int cur = t & 1;
        if (t == 0) { stage(1, 64); PIPE_WAIT_N(5); }
        else        { PIPE_WAIT_LAST(); }
        PIPE_BAR();
        PIPE_FENCE();
#pragma unroll
        for (int s = 0; s < 2; s++) {
            int sw = ((s * 4 + fq) ^ (fm & 7)) * 8;
            frag_ab af = *(const frag_ab*)&sA[cur][(wr + fm) * 64 + sw];
#pragma unroll
            for (int j = 0; j < 4; j++) {
                frag_ab bf = *(const frag_ab*)&sB[cur][(wc + j * 16 + fm) * 64 + sw];
                acc[j] = __builtin_amdgcn_mfma_f32_16x16x32_bf16(af, bf, acc[j], 0, 0, 0);
            }
        }
        PIPE_FENCE();
        PIPE_BAR();
    }
    float wv[4], bh[4];
#pragma unroll
    for (int j = 0; j < 4; j++) {
        int c = wc + j * 16 + fm;
        wv[j] = Wh2[c];
        bh[j] = bh1[c];
    }
    float part[4];
#pragma unroll
    for (int r = 0; r < 4; r++) {
        float p = 0.f;
#pragma unroll
        for (int j = 0; j < 4; j++) {
            float v = fmaxf(acc[j][r] + bh[j], 0.f);
            p += v * wv[j];
        }
        part[r] = p;
    }
#pragma unroll
    for (int m = 1; m < 16; m <<= 1)
#pragma unroll
        for (int r = 0; r < 4; r++)
            part[r] += __shfl_xor(part[r], m, 64);
    if (fm == 0) {
#pragma unroll
        for (int r = 0; r < 4; r++)
            sred[w >> 1][wr + fq * 4 + r] = part[r];
    }
    __syncthreads();
    if (tid < 32 && tileM + tid < M)
        logits[tileM + tid] = sred[0][tid] + sred[1][tid] + bh2[0];
}

// ---------------- gather: Mb[r*4+k, half*64+:64] = bf16(clip(sum Zb[col_e, half-slice])) ----
// 8-lane groups own one q-half end-to-end (NO cross-lane reduce); 8 groups/wave, 4 waves/block
// -> 32 q-halves per block. d-half XCD routing: bid = 8j+m, half = m>>2, qblk = j*4+(m&3);
// round-robin block->XCD puts half 0 on XCDs 0-3, half 1 on XCDs 4-7 -> per-XCD Zb working
// set = 2.56 MB, fits 4 MiB L2 (perf heuristic only, not correctness).
__global__ __launch_bounds__(256) void gather_kernel(
    const int* __restrict__ offs, const int* __restrict__ ends,
    const int* __restrict__ edst,
    const unsigned short* __restrict__ Zb, unsigned short* __restrict__ Mb)
{
    int bid = blockIdx.x;                    // 5000
    int half = (bid >> 2) & 1;
    int qblk = (bid >> 3) * 4 + (bid & 3);   // 0..2499
    int w = threadIdx.x >> 6;
    int lane = threadIdx.x & 63;
    int g = lane >> 3;                       // group 0..7 owns one q
    int l = lane & 7;                        // 8 lanes x 16B = 128B half-row
    int q = qblk * 32 + w * 8 + g;           // CSR index q = k*N + r
    int k = q / N_NODES;
    int r = q - k * N_NODES;
    int start = offs[q];
    int end = ends[q];
    const unsigned short* Zh = Zb + half * 64 + l * 8;

    float a0 = 0.f, a1 = 0.f, a2 = 0.f, a3 = 0.f;
    float a4 = 0.f, a5 = 0.f, a6 = 0.f, a7 = 0.f;

#define ACC8(P) {                                  \
        a0 += bflo(P.x); a1 += bfhi(P.x);          \
        a2 += bflo(P.y); a3 += bfhi(P.y);          \
        a4 += bflo(P.z); a5 += bfhi(P.z);          \
        a6 += bflo(P.w); a7 += bfhi(P.w); }

    int i = start;
    for (; i + 2 <= end; i += 2) {
        int c0 = edst[i], c1 = edst[i + 1];
        uint4 p0 = *(const uint4*)(Zh + (size_t)c0 * DDIM);
        uint4 p1 = *(const uint4*)(Zh + (size_t)c1 * DDIM);
        ACC8(p0); ACC8(p1);
    }
    if (i < end) {
        uint4 p0 = *(const uint4*)(Zh + (size_t)edst[i] * DDIM);
        ACC8(p0);
    }
#undef ACC8

#define CLIP(v) fminf(fmaxf(v, -M_CLAMP_), M_CLAMP_)
    unsigned int w0 = (unsigned int)f2bf(CLIP(a0)) | ((unsigned int)f2bf(CLIP(a1)) << 16);
    unsigned int w1 = (unsigned int)f2bf(CLIP(a2)) | ((unsigned int)f2bf(CLIP(a3)) << 16);
    unsigned int w2 = (unsigned int)f2bf(CLIP(a4)) | ((unsigned int)f2bf(CLIP(a5)) << 16);
    unsigned int w3 = (unsigned int)f2bf(CLIP(a6)) | ((unsigned int)f2bf(CLIP(a7)) << 16);
#undef CLIP
    uint4 o = make_uint4(w0, w1, w2, w3);
    *(uint4*)(Mb + ((size_t)r * KADJ + k) * DDIM + half * 64 + l * 8) = o;
}

// ============== gate GEMM + FUSED alpha/Y/pairnorm-partial epilogue (Mb from global) =========
__global__ __launch_bounds__(256) void gate_fuse_kernel(
    const unsigned short* __restrict__ Mb, const unsigned short* __restrict__ Bt,
    const float* __restrict__ GH, const float* __restrict__ logdeg,
    const float* __restrict__ wld, const float* __restrict__ Wg2,
    const float* __restrict__ bg2, const float* __restrict__ mask,
    const float* __restrict__ H, float* __restrict__ Y,
    float* __restrict__ alpha_out, float* __restrict__ red)
{
    __shared__ unsigned short sA[2][32 * 64];
    __shared__ unsigned short sB[2][128 * 64];
    __shared__ float sred[2][32];
    __shared__ float sc_al[64];          // [0:32) scores, [32:64) alpha
    __shared__ float sx[256], sy[256], sqs[256];
    int tid = threadIdx.x;
    int tile0 = blockIdx.x * 32;
    int node0 = blockIdx.x * 8;
    int w = tid >> 6, lane = tid & 63;
    int wr = (w & 1) * 16, wc = (w >> 1) * 64;
    int fm = lane & 15, fq = lane >> 4;
    int crow = lane >> 3;
    int gsw = (lane & 7) ^ crow;

    frag_cd acc[4] = {};

    auto stage = [&](int buf, int k0) {
        {
            int row = w * 8 + crow;
            gld16(Mb + (size_t)(tile0 + row) * DDIM + k0 + gsw * 8, &sA[buf][w * 512]);
        }
#pragma unroll
        for (int t = 0; t < 4; t++) {
            int chunk = w * 4 + t;
            int row = chunk * 8 + crow;
            gld16(Bt + (size_t)row * DDIM + k0 + gsw * 8, &sB[buf][chunk * 512]);
        }
    };

    stage(0, 0);
#pragma unroll
    for (int t = 0; t < 2; t++) {
        int cur = t & 1;
        if (t == 0) { stage(1, 64); PIPE_WAIT_N(5); }
        else        { PIPE_WAIT_LAST(); }
        PIPE_BAR();
        PIPE_FENCE();
#pragma unroll
        for (int s = 0; s < 2; s++) {
            int sw = ((s * 4 + fq) ^ (fm & 7)) * 8;
            frag_ab af = *(const frag_ab*)&sA[cur][(wr + fm) * 64 + sw];
#pragma unroll
            for (int j = 0; j < 4; j++) {
                frag_ab bf = *(const frag_ab*)&sB[cur][(wc + j * 16 + fm) * 64 + sw];
                acc[j] = __builtin_amdgcn_mfma_f32_16x16x32_bf16(af, bf, acc[j], 0, 0, 0);
            }
        }
        PIPE_FENCE();
        PIPE_BAR();
    }
    float wg2v[4], wldv[4];
#pragma unroll
    for (int j = 0; j < 4; j++) {
        int c = wc + j * 16 + fm;
        wg2v[j] = Wg2[c];
        wldv[j] = wld[c];
    }
    float part[4];
#pragma unroll
    for (int r = 0; r < 4; r++) {
        int q = tile0 + wr + fq * 4 + r;
        int n = q >> 2;
        float ld = logdeg[q];
        float p = 0.f;
#pragma unroll
        for (int j = 0; j < 4; j++) {
            int c = wc + j * 16 + fm;
            float v = acc[j][r] + GH[(size_t)n * GATE_H_ + c] + ld * wldv[j];
            p += fmaxf(v, 0.f) * wg2v[j];
        }
        part[r] = p;
    }
#pragma unroll
    for (int m = 1; m < 16; m <<= 1)
#pragma unroll
        for (int r = 0; r < 4; r++)
            part[r] += __shfl_xor(part[r], m, 64);
    if (fm == 0) {
#pragma unroll
        for (int r = 0; r < 4; r++)
            sred[w >> 1][wr + fq * 4 + r] = part[r];
    }
    __syncthreads();
    if (tid < 32) sc_al[tid] = sred[0][tid] + sred[1][tid] + bg2[0];
    __syncthreads();
    // ---- softmax + mask renorm per node (threads 0..7) ----
    if (tid < 8) {
        int n = node0 + tid;
        float a[KADJ];
        float mx = -1e30f;
#pragma unroll
        for (int k = 0; k < KADJ; k++) {
            a[k] = sc_al[tid * 4 + k] * (1.0f / TEMP_);
            mx = fmaxf(mx, a[k]);
        }
        float sum = 0.f;
#pragma unroll
        for (int k = 0; k < KADJ; k++) { a[k] = expf(a[k] - mx); sum += a[k]; }
#pragma unroll
        for (int k = 0; k < KADJ; k++) a[k] = (a[k] / sum) * mask[(size_t)n * KADJ + k];
        float s2 = 0.f;
#pragma unroll
        for (int k = 0; k < KADJ; k++) s2 += a[k];
        float inv = 1.f / fmaxf(s2, 1e-12f);
#pragma unroll
        for (int k = 0; k < KADJ; k++) a[k] = fmaxf(a[k] * inv, 1e-8f);
        s2 = 0.f;
#pragma unroll
        for (int k = 0; k < KADJ; k++) s2 += a[k];
        inv = 1.f / fmaxf(s2, 1e-12f);
#pragma unroll
        for (int k = 0; k < KADJ; k++) sc_al[32 + tid * 4 + k] = a[k] * inv;
    }
    __syncthreads();
    if (tid < 32) alpha_out[tile0 + tid] = sc_al[32 + tid];
    // ---- Y = H + sum_k a_k M, + pairnorm partials (8 nodes x 64 d-pairs) ----
    float csx = 0.f, csy = 0.f, sq = 0.f;
    int j = tid & 63, dd = j * 2;
#pragma unroll
    for (int it = 0; it < 2; it++) {
        int nl = (tid >> 6) + it * 4;
        int n = node0 + nl;
        const float* alp = &sc_al[32 + nl * 4];
        float2 h = *(const float2*)(H + (size_t)n * DDIM + dd);
        float yx = h.x, yy = h.y;
#pragma unroll
        for (int k = 0; k < KADJ; k++) {
            unsigned int u = *(const unsigned int*)(Mb + ((size_t)n * KADJ + k) * DDIM + dd);
            yx += alp[k] * bflo(u);
            yy += alp[k] * bfhi(u);
        }
        *(float2*)(Y + (size_t)n * DDIM + dd) = make_float2(yx, yy);
        csx += yx; csy += yy;
        sq += yx * yx + yy * yy;
    }
    sx[tid] = csx; sy[tid] = csy; sqs[tid] = sq;
    __syncthreads();
    int st = (blockIdx.x & 7) * 132;
    if (tid < 64) {
        float ax = sx[tid] + sx[tid + 64] + sx[tid + 128] + sx[tid + 192];
        float ay = sy[tid] + sy[tid + 64] + sy[tid + 128] + sy[tid + 192];
        atomicAdd(&red[st + tid * 2], ax);
        atomicAdd(&red[st + tid * 2 + 1], ay);
    }
    for (int s = 128; s > 0; s >>= 1) {
        if (tid < s) sqs[tid] += sqs[tid + s];
        __syncthreads();
    }
    if (tid == 0) atomicAdd(&red[st + 128], sqs[0]);
}

// ---------------- pairnorm apply: sums 8 red stripes, writes H fp32 + Hb bf16 ----------
__global__ __launch_bounds__(256) void pairnorm_kernel(
    const float* __restrict__ Y, const float* __restrict__ red,
    float* __restrict__ Hout, unsigned short* __restrict__ Hb, int N)
{
    int tid = threadIdx.x;
    int d = tid & 127;
    float invN = 1.0f / (float)N;
    float s = 0.f, rq = 0.f;
#pragma unroll
    for (int st = 0; st < 8; st++) {
        s += red[st * 132 + d];
        rq += red[st * 132 + 128];
    }
    float mu = s * invN;
    __shared__ float smu2[128];
    if (tid < 128) smu2[tid] = mu * mu;
    __syncthreads();
    for (int t = 64; t > 0; t >>= 1) {
        if (tid < t) smu2[tid] += smu2[tid + t];
        __syncthreads();
    }
    float summu2 = smu2[0];
    float var = rq * invN - summu2;
    float norm = sqrtf(fmaxf(var, 0.f)) + 1e-6f;
    float inv = 1.0f / norm;
    int n = blockIdx.x * 2 + (tid >> 7);
    if (n < N) {
        float v = (Y[(size_t)n * DDIM + d] - mu) * inv;
        v = fmaxf(v, 0.f);
        Hout[(size_t)n * DDIM + d] = v;
        Hb[(size_t)n * DDIM + d] = f2bf(v);
    }
}

extern "C" void kernel_launch(void* const* d_in, const int* in_sizes, int n_in,
                              void* d_out, int out_size, void* d_ws, size_t ws_size,
                              hipStream_t stream)
{
    const float* X      = (const float*)d_in[0];
    const int*   rows   = (const int*)d_in[1];
    const int*   cols   = (const int*)d_in[2];
    const float* mask   = (const float*)d_in[3];
    const float* logdeg = (const float*)d_in[4];
    const float* W_in0  = (const float*)d_in[5];
    const float* b_in0  = (const float*)d_in[6];
    const float* W_in1  = (const float*)d_in[7];
    const float* b_in1  = (const float*)d_in[8];
    const float* W_in2  = (const float*)d_in[9];
    const float* b_in2  = (const float*)d_in[10];
    const float* Wmsg[2] = {(const float*)d_in[11], (const float*)d_in[16]};
    const float* Wg1[2]  = {(const float*)d_in[12], (const float*)d_in[17]};
    const float* bg1[2]  = {(const float*)d_in[13], (const float*)d_in[18]};
    const float* Wg2[2]  = {(const float*)d_in[14], (const float*)d_in[19]};
    const float* bg2[2]  = {(const float*)d_in[15], (const float*)d_in[20]};
    const float* Wh1 = (const float*)d_in[21];
    const float* bh1 = (const float*)d_in[22];
    const float* Wh2 = (const float*)d_in[23];
    const float* bh2 = (const float*)d_in[24];

    // workspace layout (float slots), ~85 MB.
    // LIFETIME MAP (race-audited):
    //   Xb      0        - 10240000   written prep, read gemm1. Dead after gemm1.
    //   Mb      0        -  5120000   written gather (block loop), read gate_fuse. (Xb dead)
    //   H0b     10240000 - 12800000   written gemm1, read gemm2
    //   H1b/Zb  12800000 - 15360000   gemm2->gemm3; zg->gather
    //   staging 15360000 - 18505728   written prep(binA2), read binB2 (inside gemm1 launch).
    //                                 (MUST NOT alias H0b: binB2 runs concurrently with gemm1!)
    //   H       15360000 - 17920000   written gemm3 (after staging dead)
    //   Hb      17920000 - 19200000   written gemm3
    float* ws = (float*)d_ws;
    unsigned short* Xb  = (unsigned short*)ws;
    unsigned short* Mb  = (unsigned short*)ws;
    float* Ybuf  = ws + 5120000;
    float* GH    = ws + 7680000;
    unsigned short* H0b = (unsigned short*)(ws + 10240000);
    unsigned short* H1b = (unsigned short*)(ws + 12800000);
    unsigned short* Zb  = (unsigned short*)(ws + 12800000);
    uint2* staging = (uint2*)(ws + 15360000);       // NCOARSE*ESTRIDE*2 = 3,145,728 slots
    float* H     = ws + 15360000;                   // 2.56M (after staging dead)
    unsigned short* Hb = (unsigned short*)(ws + 17920000);  // 1.28M slots
    int*   bcnt  = (int*)(ws + 19200000);           // 128
    float* red   = ws + 19200128;                   // 2 blocks x 8 stripes x 132
    int*   offs   = (int*)(ws + 19280000);          // 80000
    int*   ends   = (int*)(ws + 19360000);          // 80000
    int*   edst   = (int*)(ws + 19440000);          // NCOARSE*ESTRIDE = 1,572,864
    unsigned short* w0t  = (unsigned short*)(ws + 21013248);  // 131072 slots
    unsigned short* w1t  = (unsigned short*)(ws + 21144320);  // 32768
    unsigned short* w2t  = (unsigned short*)(ws + 21177088);  // 16384
    unsigned short* wzg[2]  = {(unsigned short*)(ws + 21193472), (unsigned short*)(ws + 21209856)};  // 256x128 each
    unsigned short* wgmt[2] = {(unsigned short*)(ws + 21226240), (unsigned short*)(ws + 21234432)};
    unsigned short* wh1t = (unsigned short*)(ws + 21242624);
    float* logits = (float*)d_out;
    float* alpha_out = (float*)d_out + N_NODES;

    dim3 blk(256);
    int gM32 = (N_NODES + 31) / 32;     // 625
    int gM64 = (N_NODES + 63) / 64;     // 313

    // ---- one memset: bcnt(128 ints) + red(2x8x132 floats) contiguous ----
    (void)hipMemsetAsync(bcnt, 0, (128 + 2 * 8 * 132) * sizeof(float), stream);

    // ---- prep: binA2 (first) + transposes + cast in ONE launch ----
    TD10 descs;
    descs.d[0] = {W_in0, w0t, IN_DIM_, H_IN_};
    descs.d[1] = {W_in1, w1t, H_IN_, H_IN_};
    descs.d[2] = {W_in2, w2t, H_IN_, DDIM};
    descs.d[3] = {Wmsg[0], wzg[0], DDIM, DDIM};                           // rows 0-127 of wzg0
    descs.d[4] = {Wg1[0], wzg[0] + DDIM * DDIM, DDIM, GATE_H_};           // rows 128-255 of wzg0
    descs.d[5] = {Wmsg[1], wzg[1], DDIM, DDIM};
    descs.d[6] = {Wg1[1], wzg[1] + DDIM * DDIM, DDIM, GATE_H_};
    descs.d[7] = {Wg1[0] + DDIM * GATE_H_, wgmt[0], DDIM, GATE_H_};
    descs.d[8] = {Wg1[1] + DDIM * GATE_H_, wgmt[1], DDIM, GATE_H_};
    descs.d[9] = {Wh1, wh1t, DDIM, DDIM};
    prep_kernel<<<BINA_NB + NB_TRANS + NB_CAST, blk, 0, stream>>>(
        X, Xb, descs, rows, cols, bcnt, staging);

    // ---- gemm1 (BM=64, 626 blocks) ++ binB2 (128 blocks), one launch ----
    gemm64_binb_kernel<<<2 * gM64 + NCOARSE, blk, 0, stream>>>(
        Xb, w0t, b_in0, H0b, N_NODES, H_IN_, IN_DIM_, 2 * gM64,
        staging, bcnt, offs, ends, edst);

    // ---- gemm2 (BM=64) ----
    gemm64_binb_kernel<<<2 * gM64, blk, 0, stream>>>(
        H0b, w1t, b_in1, H1b, N_NODES, H_IN_, H_IN_, 2 * gM64,
        nullptr, nullptr, nullptr, nullptr, nullptr);

    gemm_async_kernel<<<dim3(1, gM32), blk, 0, stream>>>(H1b, w2t, b_in2, H, Hb, N_NODES, DDIM, H_IN_, 1);

    for (int b = 0; b < 2; b++) {
        zg_gemm_kernel<<<dim3(2, gM32), blk, 0, stream>>>(Hb, wzg[b], bg1[b], Zb, GH, N_NODES);
        gather_kernel<<<CSR_TOTAL / 16, blk, 0, stream>>>(offs, ends, edst, Zb, Mb);  // 5000 blocks
        float* alph = alpha_out + (size_t)b * N_NODES * KADJ;
        gate_fuse_kernel<<<CSR_TOTAL / 32, blk, 0, stream>>>(
            Mb, wgmt[b], GH, logdeg, Wg1[b] + 256 * GATE_H_, Wg2[b], bg2[b],
            mask, H, Ybuf, alph, red + b * 8 * 132);
        pairnorm_kernel<<<(N_NODES + 1) / 2, blk, 0, stream>>>(Ybuf, red + b * 8 * 132, H, Hb, N_NODES);
    }

    // head (+ fused logits)
    head_gemm_kernel<<<gM32, blk, 0, stream>>>(Hb, wh1t, bh1, Wh2, bh2, logits, N_NODES);
}

// Round 10
// 399.624 us; speedup vs baseline: 1.1759x; 1.0317x over previous
//
#include <hip/hip_runtime.h>
#include <hip/hip_bf16.h>

#define N_NODES 20000
#define KADJ 4
#define NEDGE 320000
#define ETOTAL (KADJ * NEDGE)               // 1,280,000
#define IN_DIM_ 1024
#define H_IN_ 256
#define DDIM 128
#define GATE_H_ 128
#define TEMP_ 0.6f
#define M_CLAMP_ 20.0f
#define CSR_TOTAL (KADJ * N_NODES)          // 80000
#define NCOARSE 128
#define QPER (CSR_TOTAL / NCOARSE)          // 625
#define ESTRIDE 12288                       // bucket slot stride (exp fill 10000, sigma~100)
#define TILE_A 4096
#define BINA_NB ((ETOTAL + TILE_A - 1) / TILE_A)  // 313
#define NB_CAST (N_NODES * IN_DIM_ / 8 / 256)     // 10000
#define NB_TRANS 2560                              // 8 x 32 x 10

typedef __attribute__((ext_vector_type(8))) short frag_ab;      // 8 bf16
typedef __attribute__((ext_vector_type(4))) float frag_cd;      // 4 fp32
typedef __attribute__((ext_vector_type(8))) unsigned short us8;

__device__ inline unsigned short f2bf(float f) {
    unsigned int u = __float_as_uint(f);
    u += 0x7FFFu + ((u >> 16) & 1);   // RNE
    return (unsigned short)(u >> 16);
}
__device__ inline float bflo(unsigned int p) { return __uint_as_float(p << 16); }
__device__ inline float bfhi(unsigned int p) { return __uint_as_float(p & 0xffff0000u); }

// async 16B global->LDS (wave-uniform LDS base + lane*16)
__device__ __forceinline__ void gld16(const unsigned short* g, unsigned short* l) {
    __builtin_amdgcn_global_load_lds(
        (const __attribute__((address_space(1))) void*)g,
        (__attribute__((address_space(3))) void*)l, 16, 0, 0);
}

// ---- pipelined K-loop building blocks ----
#define PIPE_WAIT_N(n)    asm volatile("s_waitcnt vmcnt(" #n ")" ::: "memory")
#define PIPE_WAIT_LAST()  asm volatile("s_waitcnt vmcnt(0)" ::: "memory")
#define PIPE_BAR()        __builtin_amdgcn_s_barrier()
#define PIPE_FENCE()      __builtin_amdgcn_sched_barrier(0)

struct TD { const float* src; unsigned short* dst; int K; int N; };
struct TD10 { TD d[10]; };

// ============== prep mega-kernel: binA2 FIRST (latency-bound) ++ transposes ++ X cast =======
__global__ __launch_bounds__(256) void prep_kernel(
    const float* __restrict__ X, unsigned short* __restrict__ Xb,
    TD10 descs,
    const int* __restrict__ rows, const int* __restrict__ cols,
    int* __restrict__ bcnt, uint2* __restrict__ staging)
{
    __shared__ __align__(16) char sraw[2048 + TILE_A * 8];   // 34 KB
    int bid = blockIdx.x;
    int tid = threadIdx.x;

    if (bid >= BINA_NB + NB_TRANS) {
        // ---- X fp32 -> bf16 streaming cast (scheduled last; BW-bound) ----
        int i = ((bid - BINA_NB - NB_TRANS) * 256 + tid) * 8;
        float4 a = *(const float4*)(X + i), b = *(const float4*)(X + i + 4);
        us8 o;
        o[0] = f2bf(a.x); o[1] = f2bf(a.y); o[2] = f2bf(a.z); o[3] = f2bf(a.w);
        o[4] = f2bf(b.x); o[5] = f2bf(b.y); o[6] = f2bf(b.z); o[7] = f2bf(b.w);
        *(us8*)(Xb + i) = o;
        return;
    }
    if (bid >= BINA_NB) {
        // ---- weight transpose ----
        int b2 = bid - BINA_NB;
        TD t = descs.d[b2 >> 8];
        int rem = b2 & 255;
        int n0 = (rem & 7) * 32, k0 = (rem >> 3) * 32;
        if (n0 >= t.N || k0 >= t.K) return;
        float (*tile)[33] = (float(*)[33])sraw;
        int tx = tid & 31, ty4 = (tid >> 5) * 4;
#pragma unroll
        for (int i = 0; i < 4; i++)
            tile[ty4 + i][tx] = t.src[(size_t)(k0 + ty4 + i) * t.N + n0 + tx];
        __syncthreads();
#pragma unroll
        for (int i = 0; i < 4; i++)
            t.dst[(size_t)(n0 + ty4 + i) * t.K + k0 + tx] = f2bf(tile[tx][ty4 + i]);
        return;
    }
    // ---- binA2: CSR coarse binning (dispatched FIRST, overlaps with cast) ----
    int* hist  = (int*)sraw;
    int* hscan = hist + NCOARSE;
    int* lcur  = hscan + NCOARSE;
    int* gbase = lcur + NCOARSE;
    uint2* pairs = (uint2*)(sraw + 2048);

    int base = bid * TILE_A;
    int cnt_t = min(TILE_A, ETOTAL - base);

    for (int i = tid; i < NCOARSE; i += 256) hist[i] = 0;
    __syncthreads();

    unsigned int q[16], c[16];
    bool valid[16];
#pragma unroll
    for (int i = 0; i < 16; i++) {
        int loc = i * 256 + tid;
        valid[i] = loc < cnt_t;
        if (valid[i]) {
            int e = base + loc;
            int k = e / NEDGE;
            unsigned int qq = (unsigned int)(k * N_NODES + rows[e]);
            q[i] = qq;
            c[i] = (unsigned int)cols[e];
            atomicAdd(&hist[qq / QPER], 1);
        }
    }
    __syncthreads();
    if (tid < NCOARSE) hscan[tid] = hist[tid];
    __syncthreads();
    for (int d = 1; d < NCOARSE; d <<= 1) {
        int v = (tid >= d && tid < NCOARSE) ? hscan[tid - d] : 0;
        __syncthreads();
        if (tid < NCOARSE) hscan[tid] += v;
        __syncthreads();
    }
    if (tid < NCOARSE) {
        int ex = hscan[tid] - hist[tid];
        hscan[tid] = ex;
        lcur[tid] = ex;
        gbase[tid] = hist[tid] ? (tid * ESTRIDE + atomicAdd(&bcnt[tid], hist[tid])) : 0;
    }
    __syncthreads();
#pragma unroll
    for (int i = 0; i < 16; i++) {
        if (valid[i]) {
            int b = q[i] / QPER;
            int p = atomicAdd(&lcur[b], 1);
            pairs[p] = make_uint2(q[i], c[i]);
        }
    }
    __syncthreads();
    for (int i = tid; i < cnt_t; i += 256) {
        uint2 pr = pairs[i];
        int b = pr.x / QPER;
        staging[gbase[b] + (i - hscan[b])] = pr;
    }
}

// ======= BM=64/BN=128 GEMM body (cuts staged bytes 0.6x vs BM=32) ++ binB2 merge =======
// 4 waves: wave w covers rows wr=(w&1)*32..+32 (2 sub-tiles of 16), cols wc=(w>>1)*64..+64.
// Per K-step per wave: 2 A-chunks + 4 B-chunks staged (6 gld16), 16 MFMA, acc[2][4].
__global__ __launch_bounds__(256) void gemm64_binb_kernel(
    const unsigned short* __restrict__ A, const unsigned short* __restrict__ Bt,
    const float* __restrict__ bias, unsigned short* __restrict__ Cb,
    int M, int N, int K, int GEMM_NB,
    const uint2* __restrict__ staging, const int* __restrict__ bcnt,
    int* __restrict__ offs, int* __restrict__ ends, int* __restrict__ edst)
{
    __shared__ __align__(16) char smem[49152];   // 2x8KB sA + 2x16KB sB (or binB2 scratch)
    int tid = threadIdx.x;
    int bid = blockIdx.x;

    if (bid < GEMM_NB) {
        unsigned short* sA0 = (unsigned short*)smem;            // 2 x 4096 shorts
        unsigned short* sB0 = (unsigned short*)(smem + 16384);  // 2 x 8192 shorts
        int nTn = N >> 7;                                       // N-tiles of 128
        int tileM = (bid / nTn) * 64, tileN = (bid % nTn) * 128;
        int w = tid >> 6, lane = tid & 63;
        int wr = (w & 1) * 32, wc = (w >> 1) * 64;
        int fm = lane & 15, fq = lane >> 4;
        int crow = lane >> 3;
        int gsw = (lane & 7) ^ crow;

        frag_cd acc[2][4] = {};

        auto stage = [&](int buf, int k0) {
#pragma unroll
            for (int t = 0; t < 2; t++) {           // A chunks 2w, 2w+1
                int chunk = w * 2 + t;
                int row = chunk * 8 + crow;
                int ar = min(tileM + row, M - 1);   // clamp keeps vmcnt wave-uniform
                gld16(A + (size_t)ar * K + k0 + gsw * 8, sA0 + buf * 4096 + chunk * 512);
            }
#pragma unroll
            for (int t = 0; t < 4; t++) {           // B chunks
                int chunk = w * 4 + t;
                int row = chunk * 8 + crow;
                gld16(Bt + (size_t)(tileN + row) * K + k0 + gsw * 8, sB0 + buf * 8192 + chunk * 512);
            }
        };

        int nt = K >> 6;
        stage(0, 0);
        for (int t = 0; t < nt; t++) {
            int cur = t & 1;
            if (t + 1 < nt) { stage(cur ^ 1, (t + 1) << 6); PIPE_WAIT_N(6); }
            else            { PIPE_WAIT_LAST(); }
            PIPE_BAR();
            PIPE_FENCE();
#pragma unroll
            for (int s = 0; s < 2; s++) {
                int sw = ((s * 4 + fq) ^ (fm & 7)) * 8;
                frag_ab af[2], bf[4];
#pragma unroll
                for (int i = 0; i < 2; i++)
                    af[i] = *(const frag_ab*)(sA0 + cur * 4096 + (wr + i * 16 + fm) * 64 + sw);
#pragma unroll
                for (int j = 0; j < 4; j++)
                    bf[j] = *(const frag_ab*)(sB0 + cur * 8192 + (wc + j * 16 + fm) * 64 + sw);
#pragma unroll
                for (int i = 0; i < 2; i++)
#pragma unroll
                    for (int j = 0; j < 4; j++)
                        acc[i][j] = __builtin_amdgcn_mfma_f32_16x16x32_bf16(af[i], bf[j], acc[i][j], 0, 0, 0);
            }
            PIPE_FENCE();
            PIPE_BAR();
        }
#pragma unroll
        for (int i = 0; i < 2; i++) {
            int row = tileM + wr + i * 16 + fq * 4;
#pragma unroll
            for (int r = 0; r < 4; r++) {
                if (row + r < M) {
#pragma unroll
                    for (int j = 0; j < 4; j++) {
                        int col = tileN + wc + j * 16 + fm;
                        float v = fmaxf(acc[i][j][r] + bias[col], 0.f);
                        Cb[(size_t)(row + r) * N + col] = f2bf(v);
                    }
                }
            }
        }
        return;
    }
    // ---- binB2 (only when staging != null) ----
    int* cntS = (int*)smem;
    int* sofs = cntS + QPER;
    int* lcur = sofs + QPER;
    int* psum = lcur + QPER;
    int b = bid - GEMM_NB;
    int q0 = b * QPER, base = b * ESTRIDE;
    int fill = bcnt[b];
    for (int i = tid; i < QPER; i += 256) cntS[i] = 0;
    __syncthreads();
    for (int i = tid; i < fill; i += 256)
        atomicAdd(&cntS[staging[base + i].x - q0], 1);
    __syncthreads();
    const int CH = 3;
    int lo = tid * CH, hi = min(lo + CH, QPER);
    int s = 0;
    for (int i = lo; i < hi; i++) s += cntS[i];
    psum[tid] = s;
    __syncthreads();
    for (int d = 1; d < 256; d <<= 1) {
        int v = (tid >= d) ? psum[tid - d] : 0;
        __syncthreads();
        psum[tid] += v;
        __syncthreads();
    }
    int run = (tid == 0) ? 0 : psum[tid - 1];
    for (int i = lo; i < hi; i++) {
        sofs[i] = run;
        lcur[i] = run;
        run += cntS[i];
    }
    __syncthreads();
    for (int i = tid; i < QPER; i += 256) {
        offs[q0 + i] = base + sofs[i];
        ends[q0 + i] = base + sofs[i] + cntS[i];
    }
    for (int i = tid; i < fill; i += 256) {
        uint2 p = staging[base + i];
        int pos = atomicAdd(&lcur[p.x - q0], 1);
        edst[base + pos] = (int)p.y;
    }
}

// ============== async bf16 MFMA GEMM (BM=32): C = [relu](A@Bt^T + bias) =========
__global__ __launch_bounds__(256) void gemm_async_kernel(
    const unsigned short* __restrict__ A, const unsigned short* __restrict__ Bt,
    const float* __restrict__ bias, float* __restrict__ Cf, unsigned short* __restrict__ Cb,
    int M, int N, int K, int do_relu)
{
    __shared__ unsigned short sA[2][32 * 64];
    __shared__ unsigned short sB[2][128 * 64];
    int tid = threadIdx.x;
    int tileM = blockIdx.y * 32, tileN = blockIdx.x * 128;
    int w = tid >> 6, lane = tid & 63;
    int wr = (w & 1) * 16, wc = (w >> 1) * 64;
    int fm = lane & 15, fq = lane >> 4;
    int crow = lane >> 3;
    int gsw = (lane & 7) ^ crow;

    frag_cd acc[4] = {};

    auto stage = [&](int buf, int k0) {
        {
            int row = w * 8 + crow;
            int ar = min(tileM + row, M - 1);
            gld16(A + (size_t)ar * K + k0 + gsw * 8, &sA[buf][w * 512]);
        }
#pragma unroll
        for (int t = 0; t < 4; t++) {
            int chunk = w * 4 + t;
            int row = chunk * 8 + crow;
            gld16(Bt + (size_t)(tileN + row) * K + k0 + gsw * 8, &sB[buf][chunk * 512]);
        }
    };

    int nt = K >> 6;
    stage(0, 0);
    for (int t = 0; t < nt; t++) {
        int cur = t & 1;
        if (t + 1 < nt) { stage(cur ^ 1, (t + 1) << 6); PIPE_WAIT_N(5); }
        else            { PIPE_WAIT_LAST(); }
        PIPE_BAR();
        PIPE_FENCE();
#pragma unroll
        for (int s = 0; s < 2; s++) {
            int sw = ((s * 4 + fq) ^ (fm & 7)) * 8;
            frag_ab af = *(const frag_ab*)&sA[cur][(wr + fm) * 64 + sw];
#pragma unroll
            for (int j = 0; j < 4; j++) {
                frag_ab bf = *(const frag_ab*)&sB[cur][(wc + j * 16 + fm) * 64 + sw];
                acc[j] = __builtin_amdgcn_mfma_f32_16x16x32_bf16(af, bf, acc[j], 0, 0, 0);
            }
        }
        PIPE_FENCE();
        PIPE_BAR();
    }
    int row = tileM + wr + fq * 4;
#pragma unroll
    for (int r = 0; r < 4; r++) {
        if (row + r < M) {
#pragma unroll
            for (int j = 0; j < 4; j++) {
                int col = tileN + wc + j * 16 + fm;
                float v = acc[j][r];
                if (bias) v += bias[col];
                if (do_relu) v = fmaxf(v, 0.f);
                if (Cf) Cf[(size_t)(row + r) * N + col] = v;
                if (Cb) Cb[(size_t)(row + r) * N + col] = f2bf(v);
            }
        }
    }
}

// ============== fused Z+GH GEMM: A=Hb[M,128], Bt=wzg[256][128] ==============
__global__ __launch_bounds__(256) void zg_gemm_kernel(
    const unsigned short* __restrict__ A, const unsigned short* __restrict__ Bt,
    const float* __restrict__ bg1, unsigned short* __restrict__ Zb,
    float* __restrict__ GH, int M)
{
    __shared__ unsigned short sA[2][32 * 64];
    __shared__ unsigned short sB[2][128 * 64];
    int tid = threadIdx.x;
    int tileM = blockIdx.y * 32, tileN = blockIdx.x * 128;
    int w = tid >> 6, lane = tid & 63;
    int wr = (w & 1) * 16, wc = (w >> 1) * 64;
    int fm = lane & 15, fq = lane >> 4;
    int crow = lane >> 3;
    int gsw = (lane & 7) ^ crow;

    frag_cd acc[4] = {};

    auto stage = [&](int buf, int k0) {
        {
            int row = w * 8 + crow;
            int ar = min(tileM + row, M - 1);
            gld16(A + (size_t)ar * DDIM + k0 + gsw * 8, &sA[buf][w * 512]);
        }
#pragma unroll
        for (int t = 0; t < 4; t++) {
            int chunk = w * 4 + t;
            int row = chunk * 8 + crow;
            gld16(Bt + (size_t)(tileN + row) * DDIM + k0 + gsw * 8, &sB[buf][chunk * 512]);
        }
    };

    stage(0, 0);
#pragma unroll
    for (int t = 0; t < 2; t++) {
        int cur = t & 1;
        if (t == 0) { stage(1, 64); PIPE_WAIT_N(5); }
        else        { PIPE_WAIT_LAST(); }
        PIPE_BAR();
        PIPE_FENCE();
#pragma unroll
        for (int s = 0; s < 2; s++) {
            int sw = ((s * 4 + fq) ^ (fm & 7)) * 8;
            frag_ab af = *(const frag_ab*)&sA[cur][(wr + fm) * 64 + sw];
#pragma unroll
            for (int j = 0; j < 4; j++) {
                frag_ab bf = *(const frag_ab*)&sB[cur][(wc + j * 16 + fm) * 64 + sw];
                acc[j] = __builtin_amdgcn_mfma_f32_16x16x32_bf16(af, bf, acc[j], 0, 0, 0);
            }
        }
        PIPE_FENCE();
        PIPE_BAR();
    }
    int isZ = (blockIdx.x == 0);
    int row = tileM + wr + fq * 4;
#pragma unroll
    for (int r = 0; r < 4; r++) {
        if (row + r < M) {
#pragma unroll
            for (int j = 0; j < 4; j++) {
                int col = wc + j * 16 + fm;    // local 0..127
                float v = acc[j][r];
                if (isZ) Zb[(size_t)(row + r) * DDIM + col] = f2bf(v);
                else     GH[(size_t)(row + r) * GATE_H_ + col] = v + bg1[col];
            }
        }
    }
}

// ============== head GEMM + logits epilogue: logits = relu(Hb@Wh1+bh1) . Wh2 + bh2 ========
__global__ __launch_bounds__(256) void head_gemm_kernel(
    const unsigned short* __restrict__ A, const unsigned short* __restrict__ Bt,
    const float* __restrict__ bh1, const float* __restrict__ Wh2,
    const float* __restrict__ bh2, float* __restrict__ logits, int M)
{
    __shared__ unsigned short sA[2][32 * 64];
    __shared__ unsigned short sB[2][128 * 64];
    __shared__ float sred[2][32];
    int tid = threadIdx.x;
    int tileM = blockIdx.x * 32;
    int w = tid >> 6, lane = tid & 63;
    int wr = (w & 1) * 16, wc = (w >> 1) * 64;
    int fm = lane & 15, fq = lane >> 4;
    int crow = lane >> 3;
    int gsw = (lane & 7) ^ crow;

    frag_cd acc[4] = {};

    auto stage = [&](int buf, int k0) {
        {
            int row = w * 8 + crow;
            int ar = min(tileM + row, M - 1);
            gld16(A + (size_t)ar * DDIM + k0 + gsw * 8, &sA[buf][w * 512]);
        }
#pragma unroll
        for (int t = 0; t < 4; t++) {
            int chunk = w * 4 + t;
            int row = chunk * 8 + crow;
            gld16(Bt + (size_t)row * DDIM + k0 + gsw * 8, &sB[buf][chunk * 512]);
        }
    };

    stage(0, 0);
#pragma unroll
    for (int t = 0; t < 2; t++) {
        int cur = t & 1;
        if (t == 0) { stage(1, 64); PIPE_WAIT_N(5); }
        else        { PIPE_WAIT_LAST(); }
        PIPE_BAR();
        PIPE_FENCE();
#pragma unroll
        for (int s = 0; s < 2; s++) {
            int sw = ((s * 4 + fq) ^ (fm & 7)) * 8;
            frag_ab af = *(const frag_ab*)&sA[cur][(wr + fm) * 64 + sw];
#pragma unroll
            for (int j = 0; j < 4; j++) {
                frag_ab bf = *(const frag_ab*)&sB[cur][(wc + j * 16 + fm) * 64 + sw];
                acc[j] = __builtin_amdgcn_mfma_f32_16x16x32_bf16(af, bf, acc[j], 0, 0, 0);
            }
        }
        PIPE_FENCE();
        PIPE_BAR();
    }
    float wv[4], bh[4];
#pragma unroll
    for (int j = 0; j < 4; j++) {
        int c = wc + j * 16 + fm;
        wv[j] = Wh2[c];
        bh[j] = bh1[c];
    }
    float part[4];
#pragma unroll
    for (int r = 0; r < 4; r++) {
        float p = 0.f;
#pragma unroll
        for (int j = 0; j < 4; j++) {
            float v = fmaxf(acc[j][r] + bh[j], 0.f);
            p += v * wv[j];
        }
        part[r] = p;
    }
#pragma unroll
    for (int m = 1; m < 16; m <<= 1)
#pragma unroll
        for (int r = 0; r < 4; r++)
            part[r] += __shfl_xor(part[r], m, 64);
    if (fm == 0) {
#pragma unroll
        for (int r = 0; r < 4; r++)
            sred[w >> 1][wr + fq * 4 + r] = part[r];
    }
    __syncthreads();
    if (tid < 32 && tileM + tid < M)
        logits[tileM + tid] = sred[0][tid] + sred[1][tid] + bh2[0];
}

// ---------------- gather: Mb[r*4+k, half*64+:64] = bf16(clip(sum Zb[col_e, half-slice])) ----
// 8-lane groups own one q-half end-to-end (NO cross-lane reduce); 8 groups/wave, 4 waves/block
// -> 32 q-halves per block. d-half XCD routing: bid = 8j+m, half = m>>2, qblk = j*4+(m&3);
// round-robin block->XCD puts half 0 on XCDs 0-3, half 1 on XCDs 4-7 -> per-XCD Zb working
// set = 2.56 MB, fits 4 MiB L2 (perf heuristic only, not correctness).
// 4-deep edge unroll per group = 32 row-loads in flight per wave (L2-latency hiding).
__global__ __launch_bounds__(256) void gather_kernel(
    const int* __restrict__ offs, const int* __restrict__ ends,
    const int* __restrict__ edst,
    const unsigned short* __restrict__ Zb, unsigned short* __restrict__ Mb)
{
    int bid = blockIdx.x;                    // 5000
    int half = (bid >> 2) & 1;
    int qblk = (bid >> 3) * 4 + (bid & 3);   // 0..2499
    int w = threadIdx.x >> 6;
    int lane = threadIdx.x & 63;
    int g = lane >> 3;                       // group 0..7 owns one q
    int l = lane & 7;                        // 8 lanes x 16B = 128B half-row
    int q = qblk * 32 + w * 8 + g;           // CSR index q = k*N + r
    int k = q / N_NODES;
    int r = q - k * N_NODES;
    int start = offs[q];
    int end = ends[q];
    const unsigned short* Zh = Zb + half * 64 + l * 8;

    float a0 = 0.f, a1 = 0.f, a2 = 0.f, a3 = 0.f;
    float a4 = 0.f, a5 = 0.f, a6 = 0.f, a7 = 0.f;

#define ACC8(P) {                                  \
        a0 += bflo(P.x); a1 += bfhi(P.x);          \
        a2 += bflo(P.y); a3 += bfhi(P.y);          \
        a4 += bflo(P.z); a5 += bfhi(P.z);          \
        a6 += bflo(P.w); a7 += bfhi(P.w); }

    int i = start;
    // 4 edges in flight per group (32 per wave)
    for (; i + 4 <= end; i += 4) {
        int c0 = edst[i], c1 = edst[i + 1], c2 = edst[i + 2], c3 = edst[i + 3];
        uint4 p0 = *(const uint4*)(Zh + (size_t)c0 * DDIM);
        uint4 p1 = *(const uint4*)(Zh + (size_t)c1 * DDIM);
        uint4 p2 = *(const uint4*)(Zh + (size_t)c2 * DDIM);
        uint4 p3 = *(const uint4*)(Zh + (size_t)c3 * DDIM);
        ACC8(p0); ACC8(p1); ACC8(p2); ACC8(p3);
    }
    for (; i < end; i++) {
        uint4 p0 = *(const uint4*)(Zh + (size_t)edst[i] * DDIM);
        ACC8(p0);
    }
#undef ACC8

#define CLIP(v) fminf(fmaxf(v, -M_CLAMP_), M_CLAMP_)
    unsigned int w0 = (unsigned int)f2bf(CLIP(a0)) | ((unsigned int)f2bf(CLIP(a1)) << 16);
    unsigned int w1 = (unsigned int)f2bf(CLIP(a2)) | ((unsigned int)f2bf(CLIP(a3)) << 16);
    unsigned int w2 = (unsigned int)f2bf(CLIP(a4)) | ((unsigned int)f2bf(CLIP(a5)) << 16);
    unsigned int w3 = (unsigned int)f2bf(CLIP(a6)) | ((unsigned int)f2bf(CLIP(a7)) << 16);
#undef CLIP
    uint4 o = make_uint4(w0, w1, w2, w3);
    *(uint4*)(Mb + ((size_t)r * KADJ + k) * DDIM + half * 64 + l * 8) = o;
}

// ============== gate GEMM + FUSED alpha/Y/pairnorm-partial epilogue (Mb from global) =========
__global__ __launch_bounds__(256) void gate_fuse_kernel(
    const unsigned short* __restrict__ Mb, const unsigned short* __restrict__ Bt,
    const float* __restrict__ GH, const float* __restrict__ logdeg,
    const float* __restrict__ wld, const float* __restrict__ Wg2,
    const float* __restrict__ bg2, const float* __restrict__ mask,
    const float* __restrict__ H, float* __restrict__ Y,
    float* __restrict__ alpha_out, float* __restrict__ red)
{
    __shared__ unsigned short sA[2][32 * 64];
    __shared__ unsigned short sB[2][128 * 64];
    __shared__ float sred[2][32];
    __shared__ float sc_al[64];          // [0:32) scores, [32:64) alpha
    __shared__ float sx[256], sy[256], sqs[256];
    int tid = threadIdx.x;
    int tile0 = blockIdx.x * 32;
    int node0 = blockIdx.x * 8;
    int w = tid >> 6, lane = tid & 63;
    int wr = (w & 1) * 16, wc = (w >> 1) * 64;
    int fm = lane & 15, fq = lane >> 4;
    int crow = lane >> 3;
    int gsw = (lane & 7) ^ crow;

    frag_cd acc[4] = {};

    auto stage = [&](int buf, int k0) {
        {
            int row = w * 8 + crow;
            gld16(Mb + (size_t)(tile0 + row) * DDIM + k0 + gsw * 8, &sA[buf][w * 512]);
        }
#pragma unroll
        for (int t = 0; t < 4; t++) {
            int chunk = w * 4 + t;
            int row = chunk * 8 + crow;
            gld16(Bt + (size_t)row * DDIM + k0 + gsw * 8, &sB[buf][chunk * 512]);
        }
    };

    stage(0, 0);
#pragma unroll
    for (int t = 0; t < 2; t++) {
        int cur = t & 1;
        if (t == 0) { stage(1, 64); PIPE_WAIT_N(5); }
        else        { PIPE_WAIT_LAST(); }
        PIPE_BAR();
        PIPE_FENCE();
#pragma unroll
        for (int s = 0; s < 2; s++) {
            int sw = ((s * 4 + fq) ^ (fm & 7)) * 8;
            frag_ab af = *(const frag_ab*)&sA[cur][(wr + fm) * 64 + sw];
#pragma unroll
            for (int j = 0; j < 4; j++) {
                frag_ab bf = *(const frag_ab*)&sB[cur][(wc + j * 16 + fm) * 64 + sw];
                acc[j] = __builtin_amdgcn_mfma_f32_16x16x32_bf16(af, bf, acc[j], 0, 0, 0);
            }
        }
        PIPE_FENCE();
        PIPE_BAR();
    }
    float wg2v[4], wldv[4];
#pragma unroll
    for (int j = 0; j < 4; j++) {
        int c = wc + j * 16 + fm;
        wg2v[j] = Wg2[c];
        wldv[j] = wld[c];
    }
    float part[4];
#pragma unroll
    for (int r = 0; r < 4; r++) {
        int q = tile0 + wr + fq * 4 + r;
        int n = q >> 2;
        float ld = logdeg[q];
        float p = 0.f;
#pragma unroll
        for (int j = 0; j < 4; j++) {
            int c = wc + j * 16 + fm;
            float v = acc[j][r] + GH[(size_t)n * GATE_H_ + c] + ld * wldv[j];
            p += fmaxf(v, 0.f) * wg2v[j];
        }
        part[r] = p;
    }
#pragma unroll
    for (int m = 1; m < 16; m <<= 1)
#pragma unroll
        for (int r = 0; r < 4; r++)
            part[r] += __shfl_xor(part[r], m, 64);
    if (fm == 0) {
#pragma unroll
        for (int r = 0; r < 4; r++)
            sred[w >> 1][wr + fq * 4 + r] = part[r];
    }
    __syncthreads();
    if (tid < 32) sc_al[tid] = sred[0][tid] + sred[1][tid] + bg2[0];
    __syncthreads();
    // ---- softmax + mask renorm per node (threads 0..7) ----
    if (tid < 8) {
        int n = node0 + tid;
        float a[KADJ];
        float mx = -1e30f;
#pragma unroll
        for (int k = 0; k < KADJ; k++) {
            a[k] = sc_al[tid * 4 + k] * (1.0f / TEMP_);
            mx = fmaxf(mx, a[k]);
        }
        float sum = 0.f;
#pragma unroll
        for (int k = 0; k < KADJ; k++) { a[k] = expf(a[k] - mx); sum += a[k]; }
#pragma unroll
        for (int k = 0; k < KADJ; k++) a[k] = (a[k] / sum) * mask[(size_t)n * KADJ + k];
        float s2 = 0.f;
#pragma unroll
        for (int k = 0; k < KADJ; k++) s2 += a[k];
        float inv = 1.f / fmaxf(s2, 1e-12f);
#pragma unroll
        for (int k = 0; k < KADJ; k++) a[k] = fmaxf(a[k] * inv, 1e-8f);
        s2 = 0.f;
#pragma unroll
        for (int k = 0; k < KADJ; k++) s2 += a[k];
        inv = 1.f / fmaxf(s2, 1e-12f);
#pragma unroll
        for (int k = 0; k < KADJ; k++) sc_al[32 + tid * 4 + k] = a[k] * inv;
    }
    __syncthreads();
    if (tid < 32) alpha_out[tile0 + tid] = sc_al[32 + tid];
    // ---- Y = H + sum_k a_k M, + pairnorm partials (8 nodes x 64 d-pairs) ----
    float csx = 0.f, csy = 0.f, sq = 0.f;
    int j = tid & 63, dd = j * 2;
#pragma unroll
    for (int it = 0; it < 2; it++) {
        int nl = (tid >> 6) + it * 4;
        int n = node0 + nl;
        const float* alp = &sc_al[32 + nl * 4];
        float2 h = *(const float2*)(H + (size_t)n * DDIM + dd);
        float yx = h.x, yy = h.y;
#pragma unroll
        for (int k = 0; k < KADJ; k++) {
            unsigned int u = *(const unsigned int*)(Mb + ((size_t)n * KADJ + k) * DDIM + dd);
            yx += alp[k] * bflo(u);
            yy += alp[k] * bfhi(u);
        }
        *(float2*)(Y + (size_t)n * DDIM + dd) = make_float2(yx, yy);
        csx += yx; csy += yy;
        sq += yx * yx + yy * yy;
    }
    sx[tid] = csx; sy[tid] = csy; sqs[tid] = sq;
    __syncthreads();
    int st = (blockIdx.x & 7) * 132;
    if (tid < 64) {
        float ax = sx[tid] + sx[tid + 64] + sx[tid + 128] + sx[tid + 192];
        float ay = sy[tid] + sy[tid + 64] + sy[tid + 128] + sy[tid + 192];
        atomicAdd(&red[st + tid * 2], ax);
        atomicAdd(&red[st + tid * 2 + 1], ay);
    }
    for (int s = 128; s > 0; s >>= 1) {
        if (tid < s) sqs[tid] += sqs[tid + s];
        __syncthreads();
    }
    if (tid == 0) atomicAdd(&red[st + 128], sqs[0]);
}

// ---------------- pairnorm apply: sums 8 red stripes, writes H fp32 + Hb bf16 ----------
__global__ __launch_bounds__(256) void pairnorm_kernel(
    const float* __restrict__ Y, const float* __restrict__ red,
    float* __restrict__ Hout, unsigned short* __restrict__ Hb, int N)
{
    int tid = threadIdx.x;
    int d = tid & 127;
    float invN = 1.0f / (float)N;
    float s = 0.f, rq = 0.f;
#pragma unroll
    for (int st = 0; st < 8; st++) {
        s += red[st * 132 + d];
        rq += red[st * 132 + 128];
    }
    float mu = s * invN;
    __shared__ float smu2[128];
    if (tid < 128) smu2[tid] = mu * mu;
    __syncthreads();
    for (int t = 64; t > 0; t >>= 1) {
        if (tid < t) smu2[tid] += smu2[tid + t];
        __syncthreads();
    }
    float summu2 = smu2[0];
    float var = rq * invN - summu2;
    float norm = sqrtf(fmaxf(var, 0.f)) + 1e-6f;
    float inv = 1.0f / norm;
    int n = blockIdx.x * 2 + (tid >> 7);
    if (n < N) {
        float v = (Y[(size_t)n * DDIM + d] - mu) * inv;
        v = fmaxf(v, 0.f);
        Hout[(size_t)n * DDIM + d] = v;
        Hb[(size_t)n * DDIM + d] = f2bf(v);
    }
}

extern "C" void kernel_launch(void* const* d_in, const int* in_sizes, int n_in,
                              void* d_out, int out_size, void* d_ws, size_t ws_size,
                              hipStream_t stream)
{
    const float* X      = (const float*)d_in[0];
    const int*   rows   = (const int*)d_in[1];
    const int*   cols   = (const int*)d_in[2];
    const float* mask   = (const float*)d_in[3];
    const float* logdeg = (const float*)d_in[4];
    const float* W_in0  = (const float*)d_in[5];
    const float* b_in0  = (const float*)d_in[6];
    const float* W_in1  = (const float*)d_in[7];
    const float* b_in1  = (const float*)d_in[8];
    const float* W_in2  = (const float*)d_in[9];
    const float* b_in2  = (const float*)d_in[10];
    const float* Wmsg[2] = {(const float*)d_in[11], (const float*)d_in[16]};
    const float* Wg1[2]  = {(const float*)d_in[12], (const float*)d_in[17]};
    const float* bg1[2]  = {(const float*)d_in[13], (const float*)d_in[18]};
    const float* Wg2[2]  = {(const float*)d_in[14], (const float*)d_in[19]};
    const float* bg2[2]  = {(const float*)d_in[15], (const float*)d_in[20]};
    const float* Wh1 = (const float*)d_in[21];
    const float* bh1 = (const float*)d_in[22];
    const float* Wh2 = (const float*)d_in[23];
    const float* bh2 = (const float*)d_in[24];

    // workspace layout (float slots), ~85 MB.
    // LIFETIME MAP (race-audited):
    //   Xb      0        - 10240000   written prep, read gemm1. Dead after gemm1.
    //   Mb      0        -  5120000   written gather (block loop), read gate_fuse. (Xb dead)
    //   H0b     10240000 - 12800000   written gemm1, read gemm2
    //   H1b/Zb  12800000 - 15360000   gemm2->gemm3; zg->gather
    //   staging 15360000 - 18505728   written prep(binA2), read binB2 (inside gemm1 launch).
    //                                 (MUST NOT alias H0b: binB2 runs concurrently with gemm1!)
    //   H       15360000 - 17920000   written gemm3 (after staging dead)
    //   Hb      17920000 - 19200000   written gemm3
    float* ws = (float*)d_ws;
    unsigned short* Xb  = (unsigned short*)ws;
    unsigned short* Mb  = (unsigned short*)ws;
    float* Ybuf  = ws + 5120000;
    float* GH    = ws + 7680000;
    unsigned short* H0b = (unsigned short*)(ws + 10240000);
    unsigned short* H1b = (unsigned short*)(ws + 12800000);
    unsigned short* Zb  = (unsigned short*)(ws + 12800000);
    uint2* staging = (uint2*)(ws + 15360000);       // NCOARSE*ESTRIDE*2 = 3,145,728 slots
    float* H     = ws + 15360000;                   // 2.56M (after staging dead)
    unsigned short* Hb = (unsigned short*)(ws + 17920000);  // 1.28M slots
    int*   bcnt  = (int*)(ws + 19200000);           // 128
    float* red   = ws + 19200128;                   // 2 blocks x 8 stripes x 132
    int*   offs   = (int*)(ws + 19280000);          // 80000
    int*   ends   = (int*)(ws + 19360000);          // 80000
    int*   edst   = (int*)(ws + 19440000);          // NCOARSE*ESTRIDE = 1,572,864
    unsigned short* w0t  = (unsigned short*)(ws + 21013248);  // 131072 slots
    unsigned short* w1t  = (unsigned short*)(ws + 21144320);  // 32768
    unsigned short* w2t  = (unsigned short*)(ws + 21177088);  // 16384
    unsigned short* wzg[2]  = {(unsigned short*)(ws + 21193472), (unsigned short*)(ws + 21209856)};  // 256x128 each
    unsigned short* wgmt[2] = {(unsigned short*)(ws + 21226240), (unsigned short*)(ws + 21234432)};
    unsigned short* wh1t = (unsigned short*)(ws + 21242624);
    float* logits = (float*)d_out;
    float* alpha_out = (float*)d_out + N_NODES;

    dim3 blk(256);
    int gM32 = (N_NODES + 31) / 32;     // 625
    int gM64 = (N_NODES + 63) / 64;     // 313

    // ---- one memset: bcnt(128 ints) + red(2x8x132 floats) contiguous ----
    (void)hipMemsetAsync(bcnt, 0, (128 + 2 * 8 * 132) * sizeof(float), stream);

    // ---- prep: binA2 (first) + transposes + cast in ONE launch ----
    TD10 descs;
    descs.d[0] = {W_in0, w0t, IN_DIM_, H_IN_};
    descs.d[1] = {W_in1, w1t, H_IN_, H_IN_};
    descs.d[2] = {W_in2, w2t, H_IN_, DDIM};
    descs.d[3] = {Wmsg[0], wzg[0], DDIM, DDIM};                           // rows 0-127 of wzg0
    descs.d[4] = {Wg1[0], wzg[0] + DDIM * DDIM, DDIM, GATE_H_};           // rows 128-255 of wzg0
    descs.d[5] = {Wmsg[1], wzg[1], DDIM, DDIM};
    descs.d[6] = {Wg1[1], wzg[1] + DDIM * DDIM, DDIM, GATE_H_};
    descs.d[7] = {Wg1[0] + DDIM * GATE_H_, wgmt[0], DDIM, GATE_H_};
    descs.d[8] = {Wg1[1] + DDIM * GATE_H_, wgmt[1], DDIM, GATE_H_};
    descs.d[9] = {Wh1, wh1t, DDIM, DDIM};
    prep_kernel<<<BINA_NB + NB_TRANS + NB_CAST, blk, 0, stream>>>(
        X, Xb, descs, rows, cols, bcnt, staging);

    // ---- gemm1 (BM=64, 626 blocks) ++ binB2 (128 blocks), one launch ----
    gemm64_binb_kernel<<<2 * gM64 + NCOARSE, blk, 0, stream>>>(
        Xb, w0t, b_in0, H0b, N_NODES, H_IN_, IN_DIM_, 2 * gM64,
        staging, bcnt, offs, ends, edst);

    // ---- gemm2 (BM=64) ----
    gemm64_binb_kernel<<<2 * gM64, blk, 0, stream>>>(
        H0b, w1t, b_in1, H1b, N_NODES, H_IN_, H_IN_, 2 * gM64,
        nullptr, nullptr, nullptr, nullptr, nullptr);

    gemm_async_kernel<<<dim3(1, gM32), blk, 0, stream>>>(H1b, w2t, b_in2, H, Hb, N_NODES, DDIM, H_IN_, 1);

    for (int b = 0; b < 2; b++) {
        zg_gemm_kernel<<<dim3(2, gM32), blk, 0, stream>>>(Hb, wzg[b], bg1[b], Zb, GH, N_NODES);
        gather_kernel<<<CSR_TOTAL / 16, blk, 0, stream>>>(offs, ends, edst, Zb, Mb);  // 5000 blocks
        float* alph = alpha_out + (size_t)b * N_NODES * KADJ;
        gate_fuse_kernel<<<CSR_TOTAL / 32, blk, 0, stream>>>(
            Mb, wgmt[b], GH, logdeg, Wg1[b] + 256 * GATE_H_, Wg2[b], bg2[b],
            mask, H, Ybuf, alph, red + b * 8 * 132);
        pairnorm_kernel<<<(N_NODES + 1) / 2, blk, 0, stream>>>(Ybuf, red + b * 8 * 132, H, Hb, N_NODES);
    }

    // head (+ fused logits)
    head_gemm_kernel<<<gM32, blk, 0, stream>>>(Hb, wh1t, bh1, Wh2, bh2, logits, N_NODES);
}